// Round 5
// baseline (419.183 us; speedup 1.0000x reference)
//
#include <hip/hip_runtime.h>
#include <stdint.h>

// Problem constants
#define BB 256
#define NNODE 12
#define PP 66
#define DNF 1024
#define DEF 1024
#define DD 512
#define MROWS (BB*PP)        // 16896
#define MNODE (BB*NNODE)     // 3072
#define MTILES (MROWS/128)   // 132

typedef __attribute__((ext_vector_type(8))) short s16x8;
typedef __attribute__((ext_vector_type(4))) float f32x4;

__device__ __forceinline__ unsigned short f2bf(float f) {
  union { float f; unsigned u; } v; v.f = f;
  return (unsigned short)((v.u + 0x7FFFu + ((v.u >> 16) & 1u)) >> 16);
}
__device__ __forceinline__ float bf2f(unsigned short h) {
  union { unsigned u; float f; } v; v.u = ((unsigned)h) << 16;
  return v.f;
}

__device__ __forceinline__ void gll16(const void* g, void* l) {
  __builtin_amdgcn_global_load_lds(
      (const __attribute__((address_space(1))) void*)g,
      (__attribute__((address_space(3))) void*)l, 16, 0, 0);
}

// bijective XCD-chunk swizzle (m204)
__device__ __forceinline__ int swz_xcd(int orig, int nwg) {
  int q = nwg >> 3, r = nwg & 7, x = orig & 7;
  return (x < r ? x * (q + 1) : r * (q + 1) + (x - r) * q) + (orig >> 3);
}

// ---------------- fused prep kernel ----------------
__global__ __launch_bounds__(256) void k_prep(
    const float* __restrict__ node, unsigned short* __restrict__ node_bf,
    const float* __restrict__ W_node, unsigned short* __restrict__ WnT,
    const float* __restrict__ W_edge, unsigned short* __restrict__ WeT,
    const float* __restrict__ W0a, const float* __restrict__ W0b,
    const float* __restrict__ W0c, unsigned short* __restrict__ W0T,
    const float* __restrict__ W1a, const float* __restrict__ W1b,
    const float* __restrict__ W1c, unsigned short* __restrict__ W1T,
    const float* __restrict__ w2a, const float* __restrict__ w2b,
    const float* __restrict__ w2c,
    const float* __restrict__ b2a, const float* __restrict__ b2b,
    const float* __restrict__ b2c,
    unsigned short* __restrict__ W2T, float* __restrict__ b2pad,
    const float* __restrict__ b0a, const float* __restrict__ b0b,
    const float* __restrict__ b0c, float* __restrict__ b0cat,
    const float* __restrict__ b1a, const float* __restrict__ b1b,
    const float* __restrict__ b1c, float* __restrict__ b1cat) {
  __shared__ float tile[32][33];
  const int bid = blockIdx.x, t = threadIdx.x;
  if (bid < 3072) {
    int i = bid * 256 + t;
    float4 v = ((const float4*)node)[i];
    ushort4 o;
    o.x = f2bf(v.x); o.y = f2bf(v.y); o.z = f2bf(v.z); o.w = f2bf(v.w);
    ((ushort4*)node_bf)[i] = o;
  } else if (bid < 10240) {
    int tau = bid - 3072;
    const float* src; unsigned short* dst; int K, N;
    if (tau < 512)       { src = W_node; dst = WnT; K = 1024; N = 512; }
    else if (tau < 1024) { src = W_edge; dst = WeT; K = 1024; N = 512; tau -= 512; }
    else if (tau < 5632) {
      int hh = (tau - 1024) / 1536; tau = (tau - 1024) % 1536;
      src = hh == 0 ? W0a : (hh == 1 ? W0b : W0c);
      dst = W0T + (size_t)hh * 1024 * 1536; K = 1536; N = 1024;
    } else {
      int hh = (tau - 5632) / 512; tau = (tau - 5632) % 512;
      src = hh == 0 ? W1a : (hh == 1 ? W1b : W1c);
      dst = W1T + (size_t)hh * 512 * 1024; K = 1024; N = 512;
    }
    int ntiles = N >> 5;
    int kb = (tau / ntiles) * 32, nb = (tau % ntiles) * 32;
    int tx = t & 31, ty = t >> 5;
#pragma unroll
    for (int i = 0; i < 32; i += 8)
      tile[ty + i][tx] = src[(size_t)(kb + ty + i) * N + nb + tx];
    __syncthreads();
#pragma unroll
    for (int i = 0; i < 32; i += 8)
      dst[(size_t)(nb + ty + i) * K + kb + tx] = f2bf(tile[tx][ty + i]);
  } else if (bid < 11008) {
    int e = bid - 10240;
    int h = e >> 8, blk = e & 255;
    const int C = (h == 0) ? 9 : ((h == 1) ? 3 : 5);
    const float* W2 = (h == 0) ? w2a : ((h == 1) ? w2b : w2c);
    const float* b2 = (h == 0) ? b2a : ((h == 1) ? b2b : b2c);
    int idx = blk * 256 + t;
    int n = idx >> 9, k = idx & 511;
    W2T[(size_t)h * 65536 + idx] = (n < C) ? f2bf(W2[(size_t)k * C + n]) : (unsigned short)0;
    if (blk == 0 && t < 128)
      b2pad[h * 128 + t] = (t < C) ? b2[t] : 0.f;
  } else if (bid < 11020) {
    int j = bid - 11008;
    const float* b0 = (j < 4) ? b0a : (j < 8 ? b0b : b0c);
    b0cat[j * 256 + t] = b0[(j & 3) * 256 + t];
  } else {
    int j = bid - 11020;
    const float* b1 = (j < 2) ? b1a : (j < 4 ? b1b : b1c);
    b1cat[j * 256 + t] = b1[(j & 1) * 256 + t];
  }
}

// ---------------- gather: edge features/embeddings + node-pair table ----------------
__global__ __launch_bounds__(256) void k_gather_ef(const float* __restrict__ EF,
                                                   const float* __restrict__ EE,
                                                   const int* __restrict__ pairs,
                                                   const int* __restrict__ nrels,
                                                   unsigned short* __restrict__ efm,
                                                   unsigned short* __restrict__ emb,
                                                   int2* __restrict__ nodes) {
  int r = blockIdx.x;
  int b = r / PP;
  int i0 = pairs[r * 2 + 0], i1 = pairs[r * 2 + 1];
  int t = threadIdx.x;
  if (t == 0) {
    int p = r - b * PP;
    bool valid = p < nrels[b];
    nodes[r] = valid ? make_int2(b * NNODE + i0, b * NNODE + i1) : make_int2(-1, -1);
  }
  const float4* e01 = (const float4*)(EF + ((size_t)((b * NNODE + i0) * NNODE + i1)) * DEF);
  const float4* e10 = (const float4*)(EF + ((size_t)((b * NNODE + i1) * NNODE + i0)) * DEF);
  float4 a = e01[t], c = e10[t];
  ushort4 o;
  o.x = f2bf(0.5f * (a.x + c.x));
  o.y = f2bf(0.5f * (a.y + c.y));
  o.z = f2bf(0.5f * (a.z + c.z));
  o.w = f2bf(0.5f * (a.w + c.w));
  ((ushort4*)(efm + (size_t)r * DEF))[t] = o;
  const float2* g01 = (const float2*)(EE + ((size_t)((b * NNODE + i0) * NNODE + i1)) * DD);
  const float2* g10 = (const float2*)(EE + ((size_t)((b * NNODE + i1) * NNODE + i0)) * DD);
  float2 x = g01[t], y = g10[t];
  ushort2 eo;
  eo.x = f2bf(0.25f * (x.x + y.x));
  eo.y = f2bf(0.25f * (x.y + y.y));
  ((ushort2*)(emb + (size_t)r * DD))[t] = eo;
}

// ---------------- 128-tile MFMA GEMM (small/medium shapes) ----------------
// EPI: 0 = +bias -> bf16 ; 1 = e-assembly into ci_e (stride 512) with mask ;
//      2 = relu(+bias) -> bf16 ; 3 = layer-2 heads fp32 ; 4 = raw bf16 (no bias)
template <int EPI>
__global__ __launch_bounds__(256) void k_gemm(
    const unsigned short* __restrict__ A,
    const unsigned short* __restrict__ BT,
    int Ntiles, int K, int ldB,
    const float* __restrict__ bias,
    unsigned short* __restrict__ outb, int ldo,
    const unsigned short* __restrict__ em,
    const int* __restrict__ nrels,
    unsigned short* __restrict__ ci) {
  __shared__ __align__(16) unsigned short sm[16384];
  char* smc = (char*)sm;
  const int t = threadIdx.x;
  const int l = t & 63, w = t >> 6;
  const int wm = w >> 1, wn = w & 1;
  const int bid = blockIdx.x;
  int tn = bid % Ntiles, tm = bid / Ntiles;

  int head = 0;
  if constexpr (EPI == 3) {
    head = tm / MTILES;
    tm = tm - head * MTILES;
    A += (size_t)head * MROWS * DD;
    BT += (size_t)head * 128 * DD;
    bias += head * 128;
  }

  const int lrow = l >> 3;
  const int scol = (l & 7) ^ lrow;
  const unsigned short* Ap = A + (size_t)(tm * 128 + w * 8 + lrow) * K + scol * 8;
  const unsigned short* Bp = BT + (size_t)(tn * 128 + w * 8 + lrow) * ldB + scol * 8;

  f32x4 acc[4][4] = {};
  const int hi = l >> 4, l15 = l & 15, l7 = l & 7;
  const int nk = K >> 6;

  for (int kt = 0; kt < nk; ++kt) {
#pragma unroll
    for (int c = 0; c < 4; ++c) {
      gll16(Ap + (size_t)c * 32 * K, smc + c * 4096 + w * 1024);
      gll16(Bp + (size_t)c * 32 * ldB, smc + 16384 + c * 4096 + w * 1024);
    }
    __syncthreads();
#pragma unroll
    for (int kk = 0; kk < 2; ++kk) {
      const int cb = (((kk << 2) + hi) ^ l7) << 4;
      s16x8 af[4], bfr[4];
#pragma unroll
      for (int m = 0; m < 4; m++)
        af[m] = *(const s16x8*)(smc + (wm * 64 + m * 16 + l15) * 128 + cb);
#pragma unroll
      for (int n = 0; n < 4; n++)
        bfr[n] = *(const s16x8*)(smc + 16384 + (wn * 64 + n * 16 + l15) * 128 + cb);
#pragma unroll
      for (int m = 0; m < 4; m++)
#pragma unroll
        for (int n = 0; n < 4; n++)
          asm volatile("v_mfma_f32_16x16x32_bf16 %0, %1, %2, %0"
                       : "+v"(acc[m][n])
                       : "v"(af[m]), "v"(bfr[n]));
    }
    __syncthreads();
    Ap += 64;
    Bp += 64;
  }
  asm volatile("s_nop 7\n\ts_nop 7\n\ts_nop 7" :::);

  const int gr_base = tm * 128 + wm * 64 + (hi << 2);
  const int gc_base = tn * 128 + wn * 64 + l15;

  int Cc = 0; size_t obase = 0;
  if constexpr (EPI == 3) {
    Cc = (head == 0) ? 9 : ((head == 1) ? 3 : 5);
    obase = (head == 0) ? 0 : ((head == 1) ? (size_t)MROWS * 9 : (size_t)MROWS * 12);
  }

#pragma unroll
  for (int n = 0; n < 4; n++) {
    const int gc = gc_base + n * 16;
    const float bv = (EPI == 4) ? 0.f : bias[gc];
#pragma unroll
    for (int m = 0; m < 4; m++) {
#pragma unroll
      for (int i = 0; i < 4; i++) {
        const int gr = gr_base + m * 16 + i;
        float v = acc[m][n][i] + bv;
        if constexpr (EPI == 0 || EPI == 4) {
          outb[(size_t)gr * ldo + gc] = f2bf(v);
        } else if constexpr (EPI == 1) {
          int b = gr / PP, p = gr - b * PP;
          float e = bf2f(em[(size_t)gr * DD + gc]) + 0.5f * v;
          ci[(size_t)gr * DD + gc] =
              (p < nrels[b]) ? f2bf(e) : (unsigned short)0;
        } else if constexpr (EPI == 2) {
          outb[(size_t)gr * ldo + gc] = f2bf(v > 0.f ? v : 0.f);
        } else {
          if (gc < Cc)
            ((float*)outb)[obase + (size_t)gr * Cc + gc] = v;
        }
      }
    }
  }
}

// ---------------- 256x256 MFMA GEMM, wave tile 128x64, counted-vmcnt dbuf ----
// 8 waves (2M x 4N). BK=64. LDS = 2 bufs x (A 32K + B 32K) = 128 KiB.
// Per K-tile: {barrier(protect buf being overwritten); STAGE(kt+1 -> buf^1);
// vmcnt(8) (own tile-kt loads landed; kt+1's 8 stay in flight -> never drains
// mid-loop); barrier (=> ALL waves' tile-kt loads landed: vmcnt BEFORE barrier
// gives the cross-wave residency guarantee r4 lacked); free-run compute}.
// Last tile: no stage, vmcnt(0) (cheap: issued a full tile earlier).
// Chunk-XOR LDS swizzle via pre-swizzled global source; 0 bank conflicts.
// EPI: 2 = relu(+bias)->bf16 ; 5 = L0': relu(bias + acc + nfa[i0]+nfb[i1]).
template <int EPI>
__global__ __launch_bounds__(512, 2) void k_g256(
    const unsigned short* __restrict__ A, int ldA,
    const unsigned short* __restrict__ BT, int ldB, int K,
    int Ntiles, int blocksPerHead,
    long long aHeadOff, long long bHeadOff, long long oHeadOff, int biasHeadOff,
    const float* __restrict__ bias,
    unsigned short* __restrict__ outb, int ldo,
    const int2* __restrict__ nodes,
    const unsigned short* __restrict__ nfa,
    const unsigned short* __restrict__ nfb) {
  __shared__ __align__(16) unsigned short sm[65536];  // 128 KiB
  char* smc = (char*)sm;

  const int swz = swz_xcd(blockIdx.x, gridDim.x);
  const int head = swz / blocksPerHead;
  const int rb = swz - head * blocksPerHead;
  const int tm = rb / Ntiles, tn = rb - (rb / Ntiles) * Ntiles;

  A += (size_t)head * aHeadOff;
  BT += (size_t)head * bHeadOff;
  bias += head * biasHeadOff;
  unsigned short* outp = outb + (size_t)head * oHeadOff;

  const int t = threadIdx.x, l = t & 63, w = t >> 6;
  const int wm = w >> 2, wn = w & 3;        // 2M x 4N -> wave tile 128x64
  const int l15 = l & 15, hi = l >> 4, l7 = l & 7;
  const int srow = t >> 3;                  // 0..63
  const int schunk = (t & 7) ^ (srow & 7);  // pre-swizzled source chunk
  const unsigned short* Asrc = A + (size_t)(tm * 256 + srow) * ldA + schunk * 8;
  const unsigned short* Bsrc = BT + (size_t)(tn * 256 + srow) * ldB + schunk * 8;

#define STG(ktI, d)                                                          \
  do {                                                                       \
    _Pragma("unroll") for (int j_ = 0; j_ < 4; j_++)                         \
      gll16(Asrc + (size_t)(j_ * 64) * ldA + ((ktI) << 6),                   \
            smc + (d) * 65536 + j_ * 8192 + w * 1024);                       \
    _Pragma("unroll") for (int j_ = 0; j_ < 4; j_++)                         \
      gll16(Bsrc + (size_t)(j_ * 64) * ldB + ((ktI) << 6),                   \
            smc + (d) * 65536 + 32768 + j_ * 8192 + w * 1024);               \
  } while (0)

  f32x4 acc[8][4] = {};
  const int NT = K >> 6;

  STG(0, 0);  // prologue: tile 0 into buf 0
  for (int kt = 0; kt < NT; ++kt) {
    const int cb = kt & 1;
    __syncthreads();  // all waves done reading buf cb^1 (tile kt-1)
    if (kt + 1 < NT) {
      STG(kt + 1, cb ^ 1);
      asm volatile("s_waitcnt vmcnt(8)" ::: "memory");  // tile kt landed (own)
    } else {
      asm volatile("s_waitcnt vmcnt(0)" ::: "memory");
    }
    __syncthreads();  // cross-wave: ALL tile-kt loads landed

    const char* Ab = smc + cb * 65536;
    const char* Bb = smc + cb * 65536 + 32768;
#pragma unroll
    for (int kk = 0; kk < 2; ++kk) {
      const int cofs = (((kk << 2) + hi) ^ l7) << 4;
      s16x8 bfv[4], am[8];
#pragma unroll
      for (int n = 0; n < 4; n++)
        bfv[n] = *(const s16x8*)(Bb + (wn * 64 + n * 16 + l15) * 128 + cofs);
#pragma unroll
      for (int m = 0; m < 8; m++)
        am[m] = *(const s16x8*)(Ab + (wm * 128 + m * 16 + l15) * 128 + cofs);
      __builtin_amdgcn_s_setprio(1);
#pragma unroll
      for (int m = 0; m < 8; m++)
#pragma unroll
        for (int n = 0; n < 4; n++)
          asm volatile("v_mfma_f32_16x16x32_bf16 %0, %1, %2, %0"
                       : "+v"(acc[m][n]) : "v"(am[m]), "v"(bfv[n]));
      __builtin_amdgcn_s_setprio(0);
    }
  }
  asm volatile("s_nop 7\n\ts_nop 7\n\ts_nop 7" :::);  // MFMA->VALU hazard guard

  const int gr0 = tm * 256 + wm * 128 + (hi << 2);
  const int gc0 = tn * 256 + wn * 64 + l15;
  float bv[4];
#pragma unroll
  for (int n = 0; n < 4; n++) bv[n] = bias[gc0 + n * 16];

#pragma unroll
  for (int m = 0; m < 8; m++) {
#pragma unroll
    for (int i = 0; i < 4; i++) {
      const int gr = gr0 + m * 16 + i;
      if constexpr (EPI == 5) {
        int2 nn = nodes[gr];
#pragma unroll
        for (int n = 0; n < 4; n++) {
          const int gc = gc0 + n * 16;
          float v = acc[m][n][i] + bv[n];
          if (nn.x >= 0)
            v += bf2f(nfa[(size_t)nn.x * 3072 + gc]) +
                 bf2f(nfb[(size_t)nn.y * 3072 + gc]);
          outp[(size_t)gr * ldo + gc] = f2bf(v > 0.f ? v : 0.f);
        }
      } else {
#pragma unroll
        for (int n = 0; n < 4; n++) {
          const int gc = gc0 + n * 16;
          float v = acc[m][n][i] + bv[n];
          outp[(size_t)gr * ldo + gc] = f2bf(v > 0.f ? v : 0.f);
        }
      }
    }
  }
#undef STG
}

// ---------------- launcher ----------------
extern "C" void kernel_launch(void* const* d_in, const int* in_sizes, int n_in,
                              void* d_out, int out_size, void* d_ws, size_t ws_size,
                              hipStream_t stream) {
  const float* node   = (const float*)d_in[0];
  const float* EF     = (const float*)d_in[1];
  const float* EE     = (const float*)d_in[2];
  const int*   pairs  = (const int*)d_in[3];
  const int*   nrels  = (const int*)d_in[4];
  const float* W_node = (const float*)d_in[5];
  const float* b_node = (const float*)d_in[6];
  const float* W_edge = (const float*)d_in[7];
  const float* b_edge = (const float*)d_in[8];
  const float* hW0[3] = {(const float*)d_in[9],  (const float*)d_in[15], (const float*)d_in[21]};
  const float* hb0[3] = {(const float*)d_in[10], (const float*)d_in[16], (const float*)d_in[22]};
  const float* hW1[3] = {(const float*)d_in[11], (const float*)d_in[17], (const float*)d_in[23]};
  const float* hb1[3] = {(const float*)d_in[12], (const float*)d_in[18], (const float*)d_in[24]};
  const float* hW2[3] = {(const float*)d_in[13], (const float*)d_in[19], (const float*)d_in[25]};
  const float* hb2[3] = {(const float*)d_in[14], (const float*)d_in[20], (const float*)d_in[26]};

  char* ws = (char*)d_ws;
  size_t off = 0;
  auto alloc = [&](size_t bytes) {
    char* p = ws + off;
    off += (bytes + 255) & ~(size_t)255;
    return p;
  };
  // --- persistent front ---
  unsigned short* WnT   = (unsigned short*)alloc((size_t)512 * 1024 * 2);
  unsigned short* WeT   = (unsigned short*)alloc((size_t)512 * 1024 * 2);
  unsigned short* W0T   = (unsigned short*)alloc((size_t)3072 * 1536 * 2);
  unsigned short* W1T   = (unsigned short*)alloc((size_t)3 * 512 * 1024 * 2);
  unsigned short* W2T   = (unsigned short*)alloc((size_t)3 * 128 * 512 * 2);
  float*          b2pad = (float*)alloc((size_t)3 * 128 * 4);
  float*          b0cat = (float*)alloc((size_t)3072 * 4);
  float*          b1cat = (float*)alloc((size_t)1536 * 4);
  int2*           nodes = (int2*)alloc((size_t)MROWS * 8);
  // --- zone A: efm+EMb (dead after e-GEMM) -> reused as nfa/nfb, then h1 ---
  size_t zoneA = off;
  unsigned short* efm = (unsigned short*)alloc((size_t)MROWS * DEF * 2);  // 34.6M
  unsigned short* EMb = (unsigned short*)alloc((size_t)MROWS * DD * 2);   // 17.3M
  // --- zone B: ci_e (dead after L0') ---
  unsigned short* ci_e = (unsigned short*)alloc((size_t)MROWS * DD * 2);  // 17.3M
  // --- zone C: node_bf+nf (dead before L0') -> overlaid by h0big ---
  size_t zoneC = off;
  unsigned short* node_bf = (unsigned short*)alloc((size_t)MNODE * DNF * 2);
  unsigned short* nf      = (unsigned short*)alloc((size_t)MNODE * DD * 2);
  // overlays
  unsigned short* nfa   = (unsigned short*)(ws + zoneA);                 // 18.9M
  unsigned short* nfb   = nfa + (size_t)MNODE * 3072;                    // 18.9M
  unsigned short* h1    = (unsigned short*)(ws + zoneA);                 // 51.9M (after L0')
  unsigned short* h0big = (unsigned short*)(ws + zoneC);                 // 104M

  // 1. prep: conv + transposes + W2 pad + bias concats (1 launch)
  k_prep<<<11026, 256, 0, stream>>>(node, node_bf, W_node, WnT, W_edge, WeT,
      hW0[0], hW0[1], hW0[2], W0T, hW1[0], hW1[1], hW1[2], W1T,
      hW2[0], hW2[1], hW2[2], hb2[0], hb2[1], hb2[2], W2T, b2pad,
      hb0[0], hb0[1], hb0[2], b0cat, hb1[0], hb1[1], hb1[2], b1cat);
  // 2. edge gathers + node-pair table
  k_gather_ef<<<MROWS, 256, 0, stream>>>(EF, EE, pairs, nrels, efm, EMb, nodes);

  // 3. nf = node_bf @ WnT^T + b_node  (M=3072,N=512,K=1024)
  k_gemm<0><<<(MNODE / 128) * 4, 256, 0, stream>>>(
      node_bf, WnT, 4, 1024, 1024, b_node, nf, 512, nullptr, nullptr, nullptr);
  // 4. e -> ci_e: 0.25*(ee+ee') + 0.5*(efm@We + b_edge), masked
  k_gemm<1><<<MTILES * 4, 256, 0, stream>>>(
      efm, WeT, 4, 1024, 1024, b_edge, nullptr, 0, EMb, nrels, ci_e);
  // 5. node-side layer-0 partials: nfa = nf@W0[0:512,:]^T, nfb = nf@W0[512:1024,:]^T
  //    (N = 3 heads x 1024, K=512; W0T rows [h*1024+n], ldB=1536)
  k_gemm<4><<<(MNODE / 128) * 24, 256, 0, stream>>>(
      nf, W0T, 24, 512, 1536, b_node /*unused*/, nfa, 3072, nullptr, nullptr, nullptr);
  k_gemm<4><<<(MNODE / 128) * 24, 256, 0, stream>>>(
      nf, W0T + 512, 24, 512, 1536, b_node /*unused*/, nfb, 3072, nullptr, nullptr, nullptr);

  // 6. L0': h0 = relu(ci_e @ W0[1024:1536,:]^T + b0 + nfa[i0] + nfb[i1])
  //    M=16896, N=3072, K=512
  k_g256<5><<<(MROWS / 256) * 12, 512, 0, stream>>>(
      ci_e, 512, W0T + 1024, 1536, 512, 12, (MROWS / 256) * 12,
      0, 0, 0, 0, b0cat, h0big, 3072, nodes, nfa, nfb);

  // 7. L1: per head h1 = relu(h0[:,h*1024:] @ W1[h]^T + b1[h])  (K=1024,N=512)
  k_g256<2><<<3 * (MROWS / 256) * 2, 512, 0, stream>>>(
      h0big, 3072, W1T, 1024, 1024, 2, (MROWS / 256) * 2,
      1024, (long long)512 * 1024, (long long)MROWS * DD, 512, b1cat, h1, 512,
      nullptr, nullptr, nullptr);

  // 8. L2: merged padded GEMM -> d_out (fp32) lr | cr | mr
  k_gemm<3><<<3 * MTILES, 256, 0, stream>>>(
      h1, W2T, 1, 512, 512, b2pad, (unsigned short*)d_out, 0,
      nullptr, nullptr, nullptr);
}

// Round 6
// 398.639 us; speedup vs baseline: 1.0515x; 1.0515x over previous
//
#include <hip/hip_runtime.h>
#include <stdint.h>

// Problem constants
#define BB 256
#define NNODE 12
#define PP 66
#define DNF 1024
#define DEF 1024
#define DD 512
#define MROWS (BB*PP)        // 16896
#define MNODE (BB*NNODE)     // 3072
#define MTILES (MROWS/128)   // 132

typedef __attribute__((ext_vector_type(8))) short s16x8;
typedef __attribute__((ext_vector_type(4))) float f32x4;

__device__ __forceinline__ unsigned short f2bf(float f) {
  union { float f; unsigned u; } v; v.f = f;
  return (unsigned short)((v.u + 0x7FFFu + ((v.u >> 16) & 1u)) >> 16);
}
__device__ __forceinline__ float bf2f(unsigned short h) {
  union { unsigned u; float f; } v; v.u = ((unsigned)h) << 16;
  return v.f;
}

__device__ __forceinline__ void gll16(const void* g, void* l) {
  __builtin_amdgcn_global_load_lds(
      (const __attribute__((address_space(1))) void*)g,
      (__attribute__((address_space(3))) void*)l, 16, 0, 0);
}

// bijective XCD-chunk swizzle (m204)
__device__ __forceinline__ int swz_xcd(int orig, int nwg) {
  int q = nwg >> 3, r = nwg & 7, x = orig & 7;
  return (x < r ? x * (q + 1) : r * (q + 1) + (x - r) * q) + (orig >> 3);
}

// ---------------- fused prep kernel ----------------
__global__ __launch_bounds__(256) void k_prep(
    const float* __restrict__ node, unsigned short* __restrict__ node_bf,
    const float* __restrict__ W_node, unsigned short* __restrict__ WnT,
    const float* __restrict__ W_edge, unsigned short* __restrict__ WeT,
    const float* __restrict__ W0a, const float* __restrict__ W0b,
    const float* __restrict__ W0c, unsigned short* __restrict__ W0T,
    const float* __restrict__ W1a, const float* __restrict__ W1b,
    const float* __restrict__ W1c, unsigned short* __restrict__ W1T,
    const float* __restrict__ w2a, const float* __restrict__ w2b,
    const float* __restrict__ w2c,
    const float* __restrict__ b2a, const float* __restrict__ b2b,
    const float* __restrict__ b2c,
    unsigned short* __restrict__ W2T, float* __restrict__ b2pad,
    const float* __restrict__ b0a, const float* __restrict__ b0b,
    const float* __restrict__ b0c, float* __restrict__ b0cat,
    const float* __restrict__ b1a, const float* __restrict__ b1b,
    const float* __restrict__ b1c, float* __restrict__ b1cat) {
  __shared__ float tile[32][33];
  const int bid = blockIdx.x, t = threadIdx.x;
  if (bid < 3072) {
    int i = bid * 256 + t;
    float4 v = ((const float4*)node)[i];
    ushort4 o;
    o.x = f2bf(v.x); o.y = f2bf(v.y); o.z = f2bf(v.z); o.w = f2bf(v.w);
    ((ushort4*)node_bf)[i] = o;
  } else if (bid < 10240) {
    int tau = bid - 3072;
    const float* src; unsigned short* dst; int K, N;
    if (tau < 512)       { src = W_node; dst = WnT; K = 1024; N = 512; }
    else if (tau < 1024) { src = W_edge; dst = WeT; K = 1024; N = 512; tau -= 512; }
    else if (tau < 5632) {
      int hh = (tau - 1024) / 1536; tau = (tau - 1024) % 1536;
      src = hh == 0 ? W0a : (hh == 1 ? W0b : W0c);
      dst = W0T + (size_t)hh * 1024 * 1536; K = 1536; N = 1024;
    } else {
      int hh = (tau - 5632) / 512; tau = (tau - 5632) % 512;
      src = hh == 0 ? W1a : (hh == 1 ? W1b : W1c);
      dst = W1T + (size_t)hh * 512 * 1024; K = 1024; N = 512;
    }
    int ntiles = N >> 5;
    int kb = (tau / ntiles) * 32, nb = (tau % ntiles) * 32;
    int tx = t & 31, ty = t >> 5;
#pragma unroll
    for (int i = 0; i < 32; i += 8)
      tile[ty + i][tx] = src[(size_t)(kb + ty + i) * N + nb + tx];
    __syncthreads();
#pragma unroll
    for (int i = 0; i < 32; i += 8)
      dst[(size_t)(nb + ty + i) * K + kb + tx] = f2bf(tile[tx][ty + i]);
  } else if (bid < 11008) {
    int e = bid - 10240;
    int h = e >> 8, blk = e & 255;
    const int C = (h == 0) ? 9 : ((h == 1) ? 3 : 5);
    const float* W2 = (h == 0) ? w2a : ((h == 1) ? w2b : w2c);
    const float* b2 = (h == 0) ? b2a : ((h == 1) ? b2b : b2c);
    int idx = blk * 256 + t;
    int n = idx >> 9, k = idx & 511;
    W2T[(size_t)h * 65536 + idx] = (n < C) ? f2bf(W2[(size_t)k * C + n]) : (unsigned short)0;
    if (blk == 0 && t < 128)
      b2pad[h * 128 + t] = (t < C) ? b2[t] : 0.f;
  } else if (bid < 11020) {
    int j = bid - 11008;
    const float* b0 = (j < 4) ? b0a : (j < 8 ? b0b : b0c);
    b0cat[j * 256 + t] = b0[(j & 3) * 256 + t];
  } else {
    int j = bid - 11020;
    const float* b1 = (j < 2) ? b1a : (j < 4 ? b1b : b1c);
    b1cat[j * 256 + t] = b1[(j & 1) * 256 + t];
  }
}

// ---------------- gather: edge features/embeddings + node-pair table ----------------
__global__ __launch_bounds__(256) void k_gather_ef(const float* __restrict__ EF,
                                                   const float* __restrict__ EE,
                                                   const int* __restrict__ pairs,
                                                   const int* __restrict__ nrels,
                                                   unsigned short* __restrict__ efm,
                                                   unsigned short* __restrict__ emb,
                                                   int2* __restrict__ nodes) {
  int r = blockIdx.x;
  int b = r / PP;
  int i0 = pairs[r * 2 + 0], i1 = pairs[r * 2 + 1];
  int t = threadIdx.x;
  if (t == 0) {
    int p = r - b * PP;
    bool valid = p < nrels[b];
    nodes[r] = valid ? make_int2(b * NNODE + i0, b * NNODE + i1) : make_int2(-1, -1);
  }
  const float4* e01 = (const float4*)(EF + ((size_t)((b * NNODE + i0) * NNODE + i1)) * DEF);
  const float4* e10 = (const float4*)(EF + ((size_t)((b * NNODE + i1) * NNODE + i0)) * DEF);
  float4 a = e01[t], c = e10[t];
  ushort4 o;
  o.x = f2bf(0.5f * (a.x + c.x));
  o.y = f2bf(0.5f * (a.y + c.y));
  o.z = f2bf(0.5f * (a.z + c.z));
  o.w = f2bf(0.5f * (a.w + c.w));
  ((ushort4*)(efm + (size_t)r * DEF))[t] = o;
  const float2* g01 = (const float2*)(EE + ((size_t)((b * NNODE + i0) * NNODE + i1)) * DD);
  const float2* g10 = (const float2*)(EE + ((size_t)((b * NNODE + i1) * NNODE + i0)) * DD);
  float2 x = g01[t], y = g10[t];
  ushort2 eo;
  eo.x = f2bf(0.25f * (x.x + y.x));
  eo.y = f2bf(0.25f * (x.y + y.y));
  ((ushort2*)(emb + (size_t)r * DD))[t] = eo;
}

// ---------------- 128-tile MFMA GEMM (small/medium shapes) ----------------
// EPI: 0 = +bias -> bf16 ; 1 = e-assembly into ci_e (stride 512) with mask ;
//      2 = relu(+bias) -> bf16 ; 3 = layer-2 heads fp32 ; 4 = raw bf16 (no bias)
template <int EPI>
__global__ __launch_bounds__(256) void k_gemm(
    const unsigned short* __restrict__ A,
    const unsigned short* __restrict__ BT,
    int Ntiles, int K, int ldB,
    const float* __restrict__ bias,
    unsigned short* __restrict__ outb, int ldo,
    const unsigned short* __restrict__ em,
    const int* __restrict__ nrels,
    unsigned short* __restrict__ ci) {
  __shared__ __align__(16) unsigned short sm[16384];
  char* smc = (char*)sm;
  const int t = threadIdx.x;
  const int l = t & 63, w = t >> 6;
  const int wm = w >> 1, wn = w & 1;
  const int bid = blockIdx.x;
  int tn = bid % Ntiles, tm = bid / Ntiles;

  int head = 0;
  if constexpr (EPI == 3) {
    head = tm / MTILES;
    tm = tm - head * MTILES;
    A += (size_t)head * MROWS * DD;
    BT += (size_t)head * 128 * DD;
    bias += head * 128;
  }

  const int lrow = l >> 3;
  const int scol = (l & 7) ^ lrow;
  const unsigned short* Ap = A + (size_t)(tm * 128 + w * 8 + lrow) * K + scol * 8;
  const unsigned short* Bp = BT + (size_t)(tn * 128 + w * 8 + lrow) * ldB + scol * 8;

  f32x4 acc[4][4] = {};
  const int hi = l >> 4, l15 = l & 15, l7 = l & 7;
  const int nk = K >> 6;

  for (int kt = 0; kt < nk; ++kt) {
#pragma unroll
    for (int c = 0; c < 4; ++c) {
      gll16(Ap + (size_t)c * 32 * K, smc + c * 4096 + w * 1024);
      gll16(Bp + (size_t)c * 32 * ldB, smc + 16384 + c * 4096 + w * 1024);
    }
    __syncthreads();
#pragma unroll
    for (int kk = 0; kk < 2; ++kk) {
      const int cb = (((kk << 2) + hi) ^ l7) << 4;
      s16x8 af[4], bfr[4];
#pragma unroll
      for (int m = 0; m < 4; m++)
        af[m] = *(const s16x8*)(smc + (wm * 64 + m * 16 + l15) * 128 + cb);
#pragma unroll
      for (int n = 0; n < 4; n++)
        bfr[n] = *(const s16x8*)(smc + 16384 + (wn * 64 + n * 16 + l15) * 128 + cb);
#pragma unroll
      for (int m = 0; m < 4; m++)
#pragma unroll
        for (int n = 0; n < 4; n++)
          asm volatile("v_mfma_f32_16x16x32_bf16 %0, %1, %2, %0"
                       : "+v"(acc[m][n])
                       : "v"(af[m]), "v"(bfr[n]));
    }
    __syncthreads();
    Ap += 64;
    Bp += 64;
  }
  asm volatile("s_nop 7\n\ts_nop 7\n\ts_nop 7" :::);

  const int gr_base = tm * 128 + wm * 64 + (hi << 2);
  const int gc_base = tn * 128 + wn * 64 + l15;

  int Cc = 0; size_t obase = 0;
  if constexpr (EPI == 3) {
    Cc = (head == 0) ? 9 : ((head == 1) ? 3 : 5);
    obase = (head == 0) ? 0 : ((head == 1) ? (size_t)MROWS * 9 : (size_t)MROWS * 12);
  }

#pragma unroll
  for (int n = 0; n < 4; n++) {
    const int gc = gc_base + n * 16;
    const float bv = (EPI == 4) ? 0.f : bias[gc];
#pragma unroll
    for (int m = 0; m < 4; m++) {
#pragma unroll
      for (int i = 0; i < 4; i++) {
        const int gr = gr_base + m * 16 + i;
        float v = acc[m][n][i] + bv;
        if constexpr (EPI == 0 || EPI == 4) {
          outb[(size_t)gr * ldo + gc] = f2bf(v);
        } else if constexpr (EPI == 1) {
          int b = gr / PP, p = gr - b * PP;
          float e = bf2f(em[(size_t)gr * DD + gc]) + 0.5f * v;
          ci[(size_t)gr * DD + gc] =
              (p < nrels[b]) ? f2bf(e) : (unsigned short)0;
        } else if constexpr (EPI == 2) {
          outb[(size_t)gr * ldo + gc] = f2bf(v > 0.f ? v : 0.f);
        } else {
          if (gc < Cc)
            ((float*)outb)[obase + (size_t)gr * Cc + gc] = v;
        }
      }
    }
  }
}

// ------- 256x128 triple-buffer depth-2 MFMA GEMM, single barrier/K-tile -------
// 8 waves (4M x 2N), wave tile 64x64. BK=64. LDS = 3 bufs x (A 32K + B 16K) = 144K.
// Per K-tile: { STAGE(kt+2 -> buf[(kt+2)%3]); compute tile kt from buf[kt%3];
//               s_waitcnt vmcnt(6); __syncthreads(); }
// Invariants (airtight, no cross-wave race):
//  - stage target buf[(kt+2)%3] == buffer read at iter kt-1; the barrier at the
//    end of kt-1 separates all reads from these writes.
//  - vmcnt(6) BEFORE the barrier: each wave certifies its 6 tile-(kt+1) loads
//    landed (kt+2's 6 stay in flight; never drains). After the barrier, ALL
//    waves' tile-(kt+1) loads have landed -> next iter computes with no wait.
//  - tail: clamped dead re-stages keep 6 loads/iter so vmcnt(6) stays exact;
//    dead writes target barrier-retired buffers only.
// Chunk-XOR LDS swizzle via pre-swizzled global source (kg = l7 ^ (l>>3));
// same XOR on ds_read -> 0 bank conflicts (measured, r4 family).
// EPI: 2 = relu(+bias)->bf16 ; 5 = L0': relu(bias + acc + nfa[i0] + nfb[i1]).
template <int EPI>
__global__ __launch_bounds__(512, 1) void k_g3(
    const unsigned short* __restrict__ A, int ldA,
    const unsigned short* __restrict__ BT, int ldB, int K,
    int Ntiles, int blocksPerHead,
    long long aHeadOff, long long bHeadOff, long long oHeadOff, int biasHeadOff,
    const float* __restrict__ bias,
    unsigned short* __restrict__ outb, int ldo,
    const int2* __restrict__ nodes,
    const unsigned short* __restrict__ nfa,
    const unsigned short* __restrict__ nfb) {
  __shared__ __align__(16) unsigned short sm[73728];  // 144 KiB
  char* smc = (char*)sm;

  const int swz = swz_xcd(blockIdx.x, gridDim.x);
  const int head = swz / blocksPerHead;
  const int rb = swz - head * blocksPerHead;
  const int tm = rb / Ntiles, tn = rb - (rb / Ntiles) * Ntiles;

  A += (size_t)head * aHeadOff;
  BT += (size_t)head * bHeadOff;
  bias += head * biasHeadOff;
  unsigned short* outp = outb + (size_t)head * oHeadOff;

  const int t = threadIdx.x, l = t & 63, w = t >> 6;
  const int wm = w >> 1, wn = w & 1;
  const int l15 = l & 15, hi = l >> 4, l7 = l & 7, lr3 = l >> 3;
  const int kg = l7 ^ lr3;  // pre-swizzled source chunk

  // staging pointers: 4 A-rows + 2 B-rows per thread-slice (6 gll16/wave)
  const unsigned short* rAp[4];
  const unsigned short* rBp[2];
#pragma unroll
  for (int i = 0; i < 4; i++)
    rAp[i] = A + (size_t)(tm * 256 + i * 64 + w * 8 + lr3) * ldA + kg * 8;
#pragma unroll
  for (int i = 0; i < 2; i++)
    rBp[i] = BT + (size_t)(tn * 128 + i * 64 + w * 8 + lr3) * ldB + kg * 8;

#define STG3(ktI, sbOff)                                                     \
  do {                                                                       \
    _Pragma("unroll") for (int i_ = 0; i_ < 4; i_++)                         \
      gll16(rAp[i_] + (((size_t)(ktI)) << 6),                                \
            smc + (sbOff) + i_ * 8192 + w * 1024);                           \
    _Pragma("unroll") for (int i_ = 0; i_ < 2; i_++)                         \
      gll16(rBp[i_] + (((size_t)(ktI)) << 6),                                \
            smc + (sbOff) + 32768 + i_ * 8192 + w * 1024);                   \
  } while (0)

  f32x4 acc[4][4] = {};
  const int NT = K >> 6;

  // prologue: tiles 0,1 into bufs 0,1 ; certify tile 0 before the barrier
  STG3(0, 0);
  STG3(1, 49152);
  asm volatile("s_waitcnt vmcnt(6)" ::: "memory");
  __syncthreads();

  int cbuf = 0;            // compute-buffer byte offset (tile kt)
  int sb = 2 * 49152;      // stage-target byte offset  (tile kt+2)
  for (int kt = 0; kt < NT; ++kt) {
    const int ktof = (kt + 2 < NT) ? kt + 2 : NT - 1;  // clamped dead tail stage
    STG3(ktof, sb);        // issue early; hides under this tile's compute

#pragma unroll
    for (int kk = 0; kk < 2; ++kk) {
      const int cofs = (((kk << 2) + hi) ^ l7) << 4;
      s16x8 af[4], bfv[4];
#pragma unroll
      for (int m = 0; m < 4; m++)
        af[m] = *(const s16x8*)(smc + cbuf + (wm * 64 + m * 16 + l15) * 128 + cofs);
#pragma unroll
      for (int n = 0; n < 4; n++)
        bfv[n] = *(const s16x8*)(smc + cbuf + 32768 + (wn * 64 + n * 16 + l15) * 128 + cofs);
      __builtin_amdgcn_s_setprio(1);
#pragma unroll
      for (int m = 0; m < 4; m++)
#pragma unroll
        for (int n = 0; n < 4; n++)
          asm volatile("v_mfma_f32_16x16x32_bf16 %0, %1, %2, %0"
                       : "+v"(acc[m][n])
                       : "v"(af[m]), "v"(bfv[n]));
      __builtin_amdgcn_s_setprio(0);
    }

    asm volatile("s_waitcnt vmcnt(6)" ::: "memory");  // tile kt+1 landed (own 6)
    __syncthreads();                                   // => ALL waves' kt+1 landed
    sb = cbuf;                                         // freed: read this iter
    cbuf = (cbuf == 2 * 49152) ? 0 : cbuf + 49152;
  }
  asm volatile("s_nop 7\n\ts_nop 7\n\ts_nop 7" :::);  // MFMA->VALU hazard guard

  // epilogue
  const int gr0 = tm * 256 + wm * 64 + (hi << 2);
  const int gc0 = tn * 128 + wn * 64 + l15;
  float bv[4];
#pragma unroll
  for (int n = 0; n < 4; n++) bv[n] = bias[gc0 + n * 16];

#pragma unroll
  for (int m = 0; m < 4; m++) {
#pragma unroll
    for (int i = 0; i < 4; i++) {
      const int gr = gr0 + m * 16 + i;
      if constexpr (EPI == 5) {
        int2 nn = nodes[gr];
#pragma unroll
        for (int n = 0; n < 4; n++) {
          const int gc = gc0 + n * 16;
          float v = acc[m][n][i] + bv[n];
          if (nn.x >= 0)
            v += bf2f(nfa[(size_t)nn.x * 3072 + gc]) +
                 bf2f(nfb[(size_t)nn.y * 3072 + gc]);
          outp[(size_t)gr * ldo + gc] = f2bf(v > 0.f ? v : 0.f);
        }
      } else {
#pragma unroll
        for (int n = 0; n < 4; n++) {
          const int gc = gc0 + n * 16;
          float v = acc[m][n][i] + bv[n];
          outp[(size_t)gr * ldo + gc] = f2bf(v > 0.f ? v : 0.f);
        }
      }
    }
  }
#undef STG3
}

// ---------------- launcher ----------------
extern "C" void kernel_launch(void* const* d_in, const int* in_sizes, int n_in,
                              void* d_out, int out_size, void* d_ws, size_t ws_size,
                              hipStream_t stream) {
  const float* node   = (const float*)d_in[0];
  const float* EF     = (const float*)d_in[1];
  const float* EE     = (const float*)d_in[2];
  const int*   pairs  = (const int*)d_in[3];
  const int*   nrels  = (const int*)d_in[4];
  const float* W_node = (const float*)d_in[5];
  const float* b_node = (const float*)d_in[6];
  const float* W_edge = (const float*)d_in[7];
  const float* b_edge = (const float*)d_in[8];
  const float* hW0[3] = {(const float*)d_in[9],  (const float*)d_in[15], (const float*)d_in[21]};
  const float* hb0[3] = {(const float*)d_in[10], (const float*)d_in[16], (const float*)d_in[22]};
  const float* hW1[3] = {(const float*)d_in[11], (const float*)d_in[17], (const float*)d_in[23]};
  const float* hb1[3] = {(const float*)d_in[12], (const float*)d_in[18], (const float*)d_in[24]};
  const float* hW2[3] = {(const float*)d_in[13], (const float*)d_in[19], (const float*)d_in[25]};
  const float* hb2[3] = {(const float*)d_in[14], (const float*)d_in[20], (const float*)d_in[26]};

  char* ws = (char*)d_ws;
  size_t off = 0;
  auto alloc = [&](size_t bytes) {
    char* p = ws + off;
    off += (bytes + 255) & ~(size_t)255;
    return p;
  };
  // --- persistent front ---
  unsigned short* WnT   = (unsigned short*)alloc((size_t)512 * 1024 * 2);
  unsigned short* WeT   = (unsigned short*)alloc((size_t)512 * 1024 * 2);
  unsigned short* W0T   = (unsigned short*)alloc((size_t)3072 * 1536 * 2);
  unsigned short* W1T   = (unsigned short*)alloc((size_t)3 * 512 * 1024 * 2);
  unsigned short* W2T   = (unsigned short*)alloc((size_t)3 * 128 * 512 * 2);
  float*          b2pad = (float*)alloc((size_t)3 * 128 * 4);
  float*          b0cat = (float*)alloc((size_t)3072 * 4);
  float*          b1cat = (float*)alloc((size_t)1536 * 4);
  int2*           nodes = (int2*)alloc((size_t)MROWS * 8);
  // --- zone A: efm+EMb (dead after e-GEMM) -> reused as nfa/nfb, then h1 ---
  size_t zoneA = off;
  unsigned short* efm = (unsigned short*)alloc((size_t)MROWS * DEF * 2);  // 34.6M
  unsigned short* EMb = (unsigned short*)alloc((size_t)MROWS * DD * 2);   // 17.3M
  // --- zone B: ci_e (dead after L0') ---
  unsigned short* ci_e = (unsigned short*)alloc((size_t)MROWS * DD * 2);  // 17.3M
  // --- zone C: node_bf+nf (dead before L0') -> overlaid by h0big ---
  size_t zoneC = off;
  unsigned short* node_bf = (unsigned short*)alloc((size_t)MNODE * DNF * 2);
  unsigned short* nf      = (unsigned short*)alloc((size_t)MNODE * DD * 2);
  // overlays
  unsigned short* nfa   = (unsigned short*)(ws + zoneA);                 // 18.9M
  unsigned short* nfb   = nfa + (size_t)MNODE * 3072;                    // 18.9M
  unsigned short* h1    = (unsigned short*)(ws + zoneA);                 // 51.9M (after L0')
  unsigned short* h0big = (unsigned short*)(ws + zoneC);                 // 104M

  // 1. prep: conv + transposes + W2 pad + bias concats (1 launch)
  k_prep<<<11026, 256, 0, stream>>>(node, node_bf, W_node, WnT, W_edge, WeT,
      hW0[0], hW0[1], hW0[2], W0T, hW1[0], hW1[1], hW1[2], W1T,
      hW2[0], hW2[1], hW2[2], hb2[0], hb2[1], hb2[2], W2T, b2pad,
      hb0[0], hb0[1], hb0[2], b0cat, hb1[0], hb1[1], hb1[2], b1cat);
  // 2. edge gathers + node-pair table
  k_gather_ef<<<MROWS, 256, 0, stream>>>(EF, EE, pairs, nrels, efm, EMb, nodes);

  // 3. nf = node_bf @ WnT^T + b_node  (M=3072,N=512,K=1024)
  k_gemm<0><<<(MNODE / 128) * 4, 256, 0, stream>>>(
      node_bf, WnT, 4, 1024, 1024, b_node, nf, 512, nullptr, nullptr, nullptr);
  // 4. e -> ci_e: 0.25*(ee+ee') + 0.5*(efm@We + b_edge), masked
  k_gemm<1><<<MTILES * 4, 256, 0, stream>>>(
      efm, WeT, 4, 1024, 1024, b_edge, nullptr, 0, EMb, nrels, ci_e);
  // 5. node-side layer-0 partials: nfa = nf@W0[0:512,:]^T, nfb = nf@W0[512:1024,:]^T
  k_gemm<4><<<(MNODE / 128) * 24, 256, 0, stream>>>(
      nf, W0T, 24, 512, 1536, b_node /*unused*/, nfa, 3072, nullptr, nullptr, nullptr);
  k_gemm<4><<<(MNODE / 128) * 24, 256, 0, stream>>>(
      nf, W0T + 512, 24, 512, 1536, b_node /*unused*/, nfb, 3072, nullptr, nullptr, nullptr);

  // 6. L0': h0 = relu(ci_e @ W0[1024:1536,:]^T + b0 + nfa[i0] + nfb[i1])
  //    M=16896, N=3072, K=512 -> grid 66 x 24 = 1584 (x8 XCD-clean)
  k_g3<5><<<(MROWS / 256) * 24, 512, 0, stream>>>(
      ci_e, 512, W0T + 1024, 1536, 512, 24, (MROWS / 256) * 24,
      0, 0, 0, 0, b0cat, h0big, 3072, nodes, nfa, nfb);

  // 7. L1: per head h1 = relu(h0[:,h*1024:] @ W1[h]^T + b1[h])  (K=1024,N=512)
  //    grid 3 x 66 x 4 = 792
  k_g3<2><<<3 * (MROWS / 256) * 4, 512, 0, stream>>>(
      h0big, 3072, W1T, 1024, 1024, 4, (MROWS / 256) * 4,
      1024, (long long)512 * 1024, (long long)MROWS * DD, 512, b1cat, h1, 512,
      nullptr, nullptr, nullptr);

  // 8. L2: merged padded GEMM -> d_out (fp32) lr | cr | mr
  k_gemm<3><<<3 * MTILES, 256, 0, stream>>>(
      h1, W2T, 1, 512, 512, b2pad, (unsigned short*)d_out, 0,
      nullptr, nullptr, nullptr);
}

// Round 7
// 385.957 us; speedup vs baseline: 1.0861x; 1.0329x over previous
//
#include <hip/hip_runtime.h>
#include <stdint.h>

// Problem constants
#define BB 256
#define NNODE 12
#define PP 66
#define DNF 1024
#define DEF 1024
#define DD 512
#define MROWS (BB*PP)        // 16896
#define MNODE (BB*NNODE)     // 3072
#define MTILES (MROWS/128)   // 132

typedef __attribute__((ext_vector_type(8))) short s16x8;
typedef __attribute__((ext_vector_type(4))) float f32x4;

__device__ __forceinline__ unsigned short f2bf(float f) {
  union { float f; unsigned u; } v; v.f = f;
  return (unsigned short)((v.u + 0x7FFFu + ((v.u >> 16) & 1u)) >> 16);
}
__device__ __forceinline__ float bf2f(unsigned short h) {
  union { unsigned u; float f; } v; v.u = ((unsigned)h) << 16;
  return v.f;
}

__device__ __forceinline__ void gll16(const void* g, void* l) {
  __builtin_amdgcn_global_load_lds(
      (const __attribute__((address_space(1))) void*)g,
      (__attribute__((address_space(3))) void*)l, 16, 0, 0);
}

// ---------------- fused prep kernel ----------------
__global__ __launch_bounds__(256) void k_prep(
    const float* __restrict__ node, unsigned short* __restrict__ node_bf,
    const float* __restrict__ W_node, unsigned short* __restrict__ WnT,
    const float* __restrict__ W_edge, unsigned short* __restrict__ WeT,
    const float* __restrict__ W0a, const float* __restrict__ W0b,
    const float* __restrict__ W0c, unsigned short* __restrict__ W0T,
    const float* __restrict__ W1a, const float* __restrict__ W1b,
    const float* __restrict__ W1c, unsigned short* __restrict__ W1T,
    const float* __restrict__ w2a, const float* __restrict__ w2b,
    const float* __restrict__ w2c,
    const float* __restrict__ b2a, const float* __restrict__ b2b,
    const float* __restrict__ b2c,
    unsigned short* __restrict__ W2T, float* __restrict__ b2pad,
    const float* __restrict__ b0a, const float* __restrict__ b0b,
    const float* __restrict__ b0c, float* __restrict__ b0cat,
    const float* __restrict__ b1a, const float* __restrict__ b1b,
    const float* __restrict__ b1c, float* __restrict__ b1cat) {
  __shared__ float tile[32][33];
  const int bid = blockIdx.x, t = threadIdx.x;
  if (bid < 3072) {
    int i = bid * 256 + t;
    float4 v = ((const float4*)node)[i];
    ushort4 o;
    o.x = f2bf(v.x); o.y = f2bf(v.y); o.z = f2bf(v.z); o.w = f2bf(v.w);
    ((ushort4*)node_bf)[i] = o;
  } else if (bid < 10240) {
    int tau = bid - 3072;
    const float* src; unsigned short* dst; int K, N;
    if (tau < 512)       { src = W_node; dst = WnT; K = 1024; N = 512; }
    else if (tau < 1024) { src = W_edge; dst = WeT; K = 1024; N = 512; tau -= 512; }
    else if (tau < 5632) {
      int hh = (tau - 1024) / 1536; tau = (tau - 1024) % 1536;
      src = hh == 0 ? W0a : (hh == 1 ? W0b : W0c);
      dst = W0T + (size_t)hh * 1024 * 1536; K = 1536; N = 1024;
    } else {
      int hh = (tau - 5632) / 512; tau = (tau - 5632) % 512;
      src = hh == 0 ? W1a : (hh == 1 ? W1b : W1c);
      dst = W1T + (size_t)hh * 512 * 1024; K = 1024; N = 512;
    }
    int ntiles = N >> 5;
    int kb = (tau / ntiles) * 32, nb = (tau % ntiles) * 32;
    int tx = t & 31, ty = t >> 5;
#pragma unroll
    for (int i = 0; i < 32; i += 8)
      tile[ty + i][tx] = src[(size_t)(kb + ty + i) * N + nb + tx];
    __syncthreads();
#pragma unroll
    for (int i = 0; i < 32; i += 8)
      dst[(size_t)(nb + ty + i) * K + kb + tx] = f2bf(tile[tx][ty + i]);
  } else if (bid < 11008) {
    int e = bid - 10240;
    int h = e >> 8, blk = e & 255;
    const int C = (h == 0) ? 9 : ((h == 1) ? 3 : 5);
    const float* W2 = (h == 0) ? w2a : ((h == 1) ? w2b : w2c);
    const float* b2 = (h == 0) ? b2a : ((h == 1) ? b2b : b2c);
    int idx = blk * 256 + t;
    int n = idx >> 9, k = idx & 511;
    W2T[(size_t)h * 65536 + idx] = (n < C) ? f2bf(W2[(size_t)k * C + n]) : (unsigned short)0;
    if (blk == 0 && t < 128)
      b2pad[h * 128 + t] = (t < C) ? b2[t] : 0.f;
  } else if (bid < 11020) {
    int j = bid - 11008;
    const float* b0 = (j < 4) ? b0a : (j < 8 ? b0b : b0c);
    b0cat[j * 256 + t] = b0[(j & 3) * 256 + t];
  } else {
    int j = bid - 11020;
    const float* b1 = (j < 2) ? b1a : (j < 4 ? b1b : b1c);
    b1cat[j * 256 + t] = b1[(j & 1) * 256 + t];
  }
}

// ---------------- gather: edge features/embeddings + node-pair table ----------------
__global__ __launch_bounds__(256) void k_gather_ef(const float* __restrict__ EF,
                                                   const float* __restrict__ EE,
                                                   const int* __restrict__ pairs,
                                                   const int* __restrict__ nrels,
                                                   unsigned short* __restrict__ efm,
                                                   unsigned short* __restrict__ emb,
                                                   int2* __restrict__ nodes) {
  int r = blockIdx.x;
  int b = r / PP;
  int i0 = pairs[r * 2 + 0], i1 = pairs[r * 2 + 1];
  int t = threadIdx.x;
  if (t == 0) {
    int p = r - b * PP;
    bool valid = p < nrels[b];
    nodes[r] = valid ? make_int2(b * NNODE + i0, b * NNODE + i1) : make_int2(-1, -1);
  }
  const float4* e01 = (const float4*)(EF + ((size_t)((b * NNODE + i0) * NNODE + i1)) * DEF);
  const float4* e10 = (const float4*)(EF + ((size_t)((b * NNODE + i1) * NNODE + i0)) * DEF);
  float4 a = e01[t], c = e10[t];
  ushort4 o;
  o.x = f2bf(0.5f * (a.x + c.x));
  o.y = f2bf(0.5f * (a.y + c.y));
  o.z = f2bf(0.5f * (a.z + c.z));
  o.w = f2bf(0.5f * (a.w + c.w));
  ((ushort4*)(efm + (size_t)r * DEF))[t] = o;
  const float2* g01 = (const float2*)(EE + ((size_t)((b * NNODE + i0) * NNODE + i1)) * DD);
  const float2* g10 = (const float2*)(EE + ((size_t)((b * NNODE + i1) * NNODE + i0)) * DD);
  float2 x = g01[t], y = g10[t];
  ushort2 eo;
  eo.x = f2bf(0.25f * (x.x + y.x));
  eo.y = f2bf(0.25f * (x.y + y.y));
  ((ushort2*)(emb + (size_t)r * DD))[t] = eo;
}

// ---------------- 128-tile MFMA GEMM (m97-family: 32 KB LDS, multi-block/CU) --
// C = A[M][ldA] (cols [0,K)) x BT[N][ldB]^T. 4 waves (2x2), BK=64,
// global_load_lds w=16 staging, chunk-XOR swizzle via pre-swizzled source.
// Multi-head fusion via blocksPerHead (>0): head = bid / blocksPerHead,
// A += head*aHeadOff (element offset; works with ldA), BT += head*bHeadOff,
// out += head*oHeadOff, bias += head*biasHeadOff.
// EPI: 0 = +bias -> bf16 ; 1 = e-assembly into ci_e (stride 512, masked) ;
//      2 = relu(+bias) -> bf16 ; 3 = layer-2 heads fp32 (own head logic) ;
//      4 = raw bf16 (no bias) ; 5 = L0': relu(bias + acc + nfa[i0]+nfb[i1])
template <int EPI>
__global__ __launch_bounds__(256) void k_gemm(
    const unsigned short* __restrict__ A, int ldA,
    const unsigned short* __restrict__ BT, int ldB, int K,
    int Ntiles,
    const float* __restrict__ bias,
    unsigned short* __restrict__ outb, int ldo,
    const unsigned short* __restrict__ em,
    const int* __restrict__ nrels,
    unsigned short* __restrict__ ci,
    int blocksPerHead, long long aHeadOff, long long bHeadOff,
    long long oHeadOff, int biasHeadOff,
    const int2* __restrict__ nodes,
    const unsigned short* __restrict__ nfa,
    const unsigned short* __restrict__ nfb) {
  __shared__ __align__(16) unsigned short sm[16384];  // 32 KB: A 16K + B 16K
  char* smc = (char*)sm;
  const int t = threadIdx.x;
  const int l = t & 63, w = t >> 6;
  const int wm = w >> 1, wn = w & 1;
  int bid = blockIdx.x;

  int head = 0;
  unsigned short* outp = outb;
  if constexpr (EPI == 3) {
    // own head logic: grid = 3*MTILES, Ntiles==1
    head = bid / MTILES;
    bid -= head * MTILES;
    A += (size_t)head * MROWS * DD;
    BT += (size_t)head * 128 * DD;
    bias += head * 128;
  } else {
    if (blocksPerHead > 0) {
      head = bid / blocksPerHead;
      bid -= head * blocksPerHead;
      A += (size_t)head * aHeadOff;
      BT += (size_t)head * bHeadOff;
      bias += head * biasHeadOff;
      outp = outb + (size_t)head * oHeadOff;
    }
  }
  const int tn = bid % Ntiles, tm = bid / Ntiles;

  const int lrow = l >> 3;
  const int scol = (l & 7) ^ lrow;       // pre-swizzled source chunk
  const unsigned short* Ap = A + (size_t)(tm * 128 + w * 8 + lrow) * ldA + scol * 8;
  const unsigned short* Bp = BT + (size_t)(tn * 128 + w * 8 + lrow) * ldB + scol * 8;

  f32x4 acc[4][4] = {};
  const int hi = l >> 4, l15 = l & 15, l7 = l & 7;
  const int nk = K >> 6;

  for (int kt = 0; kt < nk; ++kt) {
#pragma unroll
    for (int c = 0; c < 4; ++c) {
      gll16(Ap + (size_t)c * 32 * ldA, smc + c * 4096 + w * 1024);
      gll16(Bp + (size_t)c * 32 * ldB, smc + 16384 + c * 4096 + w * 1024);
    }
    __syncthreads();
#pragma unroll
    for (int kk = 0; kk < 2; ++kk) {
      const int cb = (((kk << 2) + hi) ^ l7) << 4;
      s16x8 af[4], bfr[4];
#pragma unroll
      for (int m = 0; m < 4; m++)
        af[m] = *(const s16x8*)(smc + (wm * 64 + m * 16 + l15) * 128 + cb);
#pragma unroll
      for (int n = 0; n < 4; n++)
        bfr[n] = *(const s16x8*)(smc + 16384 + (wn * 64 + n * 16 + l15) * 128 + cb);
#pragma unroll
      for (int m = 0; m < 4; m++)
#pragma unroll
        for (int n = 0; n < 4; n++)
          asm volatile("v_mfma_f32_16x16x32_bf16 %0, %1, %2, %0"
                       : "+v"(acc[m][n])
                       : "v"(af[m]), "v"(bfr[n]));
    }
    __syncthreads();
    Ap += 64;
    Bp += 64;
  }
  asm volatile("s_nop 7\n\ts_nop 7\n\ts_nop 7" :::);  // MFMA->VALU hazard guard

  // C/D layout: col = lane&15, row = (lane>>4)*4 + reg
  const int gr_base = tm * 128 + wm * 64 + (hi << 2);
  const int gc_base = tn * 128 + wn * 64 + l15;

  int Cc = 0; size_t obase = 0;
  if constexpr (EPI == 3) {
    Cc = (head == 0) ? 9 : ((head == 1) ? 3 : 5);
    obase = (head == 0) ? 0 : ((head == 1) ? (size_t)MROWS * 9 : (size_t)MROWS * 12);
  }

#pragma unroll
  for (int n = 0; n < 4; n++) {
    const int gc = gc_base + n * 16;
    const float bv = (EPI == 4) ? 0.f : bias[gc];
#pragma unroll
    for (int m = 0; m < 4; m++) {
#pragma unroll
      for (int i = 0; i < 4; i++) {
        const int gr = gr_base + m * 16 + i;
        float v = acc[m][n][i] + bv;
        if constexpr (EPI == 0 || EPI == 4) {
          outp[(size_t)gr * ldo + gc] = f2bf(v);
        } else if constexpr (EPI == 1) {
          int b = gr / PP, p = gr - b * PP;
          float e = bf2f(em[(size_t)gr * DD + gc]) + 0.5f * v;
          ci[(size_t)gr * DD + gc] =
              (p < nrels[b]) ? f2bf(e) : (unsigned short)0;
        } else if constexpr (EPI == 2) {
          outp[(size_t)gr * ldo + gc] = f2bf(v > 0.f ? v : 0.f);
        } else if constexpr (EPI == 5) {
          int2 nn = nodes[gr];
          if (nn.x >= 0)
            v += bf2f(nfa[(size_t)nn.x * 3072 + gc]) +
                 bf2f(nfb[(size_t)nn.y * 3072 + gc]);
          outp[(size_t)gr * ldo + gc] = f2bf(v > 0.f ? v : 0.f);
        } else {
          if (gc < Cc)
            ((float*)outb)[obase + (size_t)gr * Cc + gc] = v;
        }
      }
    }
  }
}

// ---------------- launcher ----------------
extern "C" void kernel_launch(void* const* d_in, const int* in_sizes, int n_in,
                              void* d_out, int out_size, void* d_ws, size_t ws_size,
                              hipStream_t stream) {
  const float* node   = (const float*)d_in[0];
  const float* EF     = (const float*)d_in[1];
  const float* EE     = (const float*)d_in[2];
  const int*   pairs  = (const int*)d_in[3];
  const int*   nrels  = (const int*)d_in[4];
  const float* W_node = (const float*)d_in[5];
  const float* b_node = (const float*)d_in[6];
  const float* W_edge = (const float*)d_in[7];
  const float* b_edge = (const float*)d_in[8];
  const float* hW0[3] = {(const float*)d_in[9],  (const float*)d_in[15], (const float*)d_in[21]};
  const float* hb0[3] = {(const float*)d_in[10], (const float*)d_in[16], (const float*)d_in[22]};
  const float* hW1[3] = {(const float*)d_in[11], (const float*)d_in[17], (const float*)d_in[23]};
  const float* hb1[3] = {(const float*)d_in[12], (const float*)d_in[18], (const float*)d_in[24]};
  const float* hW2[3] = {(const float*)d_in[13], (const float*)d_in[19], (const float*)d_in[25]};
  const float* hb2[3] = {(const float*)d_in[14], (const float*)d_in[20], (const float*)d_in[26]};

  char* ws = (char*)d_ws;
  size_t off = 0;
  auto alloc = [&](size_t bytes) {
    char* p = ws + off;
    off += (bytes + 255) & ~(size_t)255;
    return p;
  };
  // --- persistent front ---
  unsigned short* WnT   = (unsigned short*)alloc((size_t)512 * 1024 * 2);
  unsigned short* WeT   = (unsigned short*)alloc((size_t)512 * 1024 * 2);
  unsigned short* W0T   = (unsigned short*)alloc((size_t)3072 * 1536 * 2);
  unsigned short* W1T   = (unsigned short*)alloc((size_t)3 * 512 * 1024 * 2);
  unsigned short* W2T   = (unsigned short*)alloc((size_t)3 * 128 * 512 * 2);
  float*          b2pad = (float*)alloc((size_t)3 * 128 * 4);
  float*          b0cat = (float*)alloc((size_t)3072 * 4);
  float*          b1cat = (float*)alloc((size_t)1536 * 4);
  int2*           nodes = (int2*)alloc((size_t)MROWS * 8);
  // --- zone A: efm+EMb (dead after e-GEMM) -> reused as nfa/nfb, then h1 ---
  size_t zoneA = off;
  unsigned short* efm = (unsigned short*)alloc((size_t)MROWS * DEF * 2);  // 34.6M
  unsigned short* EMb = (unsigned short*)alloc((size_t)MROWS * DD * 2);   // 17.3M
  // --- zone B: ci_e (dead after L0') ---
  unsigned short* ci_e = (unsigned short*)alloc((size_t)MROWS * DD * 2);  // 17.3M
  // --- zone C: node_bf+nf (dead before L0') -> overlaid by h0big ---
  size_t zoneC = off;
  unsigned short* node_bf = (unsigned short*)alloc((size_t)MNODE * DNF * 2);
  unsigned short* nf      = (unsigned short*)alloc((size_t)MNODE * DD * 2);
  // overlays
  unsigned short* nfa   = (unsigned short*)(ws + zoneA);                 // 18.9M
  unsigned short* nfb   = nfa + (size_t)MNODE * 3072;                    // 18.9M
  unsigned short* h1    = (unsigned short*)(ws + zoneA);                 // 51.9M (after L0')
  unsigned short* h0big = (unsigned short*)(ws + zoneC);                 // 104M

  // 1. prep: conv + transposes + W2 pad + bias concats (1 launch)
  k_prep<<<11026, 256, 0, stream>>>(node, node_bf, W_node, WnT, W_edge, WeT,
      hW0[0], hW0[1], hW0[2], W0T, hW1[0], hW1[1], hW1[2], W1T,
      hW2[0], hW2[1], hW2[2], hb2[0], hb2[1], hb2[2], W2T, b2pad,
      hb0[0], hb0[1], hb0[2], b0cat, hb1[0], hb1[1], hb1[2], b1cat);
  // 2. edge gathers + node-pair table
  k_gather_ef<<<MROWS, 256, 0, stream>>>(EF, EE, pairs, nrels, efm, EMb, nodes);

  // 3. nf = node_bf @ WnT^T + b_node  (M=3072,N=512,K=1024)
  k_gemm<0><<<(MNODE / 128) * 4, 256, 0, stream>>>(
      node_bf, 1024, WnT, 1024, 1024, 4, b_node, nf, 512,
      nullptr, nullptr, nullptr, 0, 0, 0, 0, 0, nullptr, nullptr, nullptr);
  // 4. e -> ci_e: 0.25*(ee+ee') + 0.5*(efm@We + b_edge), masked  (M=16896,N=512,K=1024)
  k_gemm<1><<<MTILES * 4, 256, 0, stream>>>(
      efm, 1024, WeT, 1024, 1024, 4, b_edge, nullptr, 0,
      EMb, nrels, ci_e, 0, 0, 0, 0, 0, nullptr, nullptr, nullptr);
  // 5. node-side layer-0 partials (M=3072, N=3072, K=512):
  //    nfa = nf@W0[0:512,:]^T ; nfb = nf@W0[512:1024,:]^T
  k_gemm<4><<<(MNODE / 128) * 24, 256, 0, stream>>>(
      nf, 512, W0T, 1536, 512, 24, nullptr, nfa, 3072,
      nullptr, nullptr, nullptr, 0, 0, 0, 0, 0, nullptr, nullptr, nullptr);
  k_gemm<4><<<(MNODE / 128) * 24, 256, 0, stream>>>(
      nf, 512, W0T + 512, 1536, 512, 24, nullptr, nfb, 3072,
      nullptr, nullptr, nullptr, 0, 0, 0, 0, 0, nullptr, nullptr, nullptr);

  // 6. L0': h0 = relu(ci_e @ W0[1024:1536,:]^T + b0 + nfa[i0] + nfb[i1])
  //    M=16896, N=3072, K=512 -> grid 132 x 24 = 3168
  k_gemm<5><<<MTILES * 24, 256, 0, stream>>>(
      ci_e, 512, W0T + 1024, 1536, 512, 24, b0cat, h0big, 3072,
      nullptr, nullptr, nullptr, 0, 0, 0, 0, 0, nodes, nfa, nfb);

  // 7. L1 fused over heads: h1[h] = relu(h0[:,h*1024:] @ W1[h]^T + b1[h])
  //    per head M=16896, N=512, K=1024 -> grid 3 x 132 x 4 = 1584
  k_gemm<2><<<3 * MTILES * 4, 256, 0, stream>>>(
      h0big, 3072, W1T, 1024, 1024, 4, b1cat, h1, 512,
      nullptr, nullptr, nullptr, MTILES * 4,
      1024, (long long)512 * 1024, (long long)MROWS * DD, 512,
      nullptr, nullptr, nullptr);

  // 8. L2: merged padded GEMM -> d_out (fp32) lr | cr | mr  (grid 3 x 132)
  k_gemm<3><<<3 * MTILES, 256, 0, stream>>>(
      h1, 512, W2T, 512, 512, 1, b2pad, (unsigned short*)d_out, 0,
      nullptr, nullptr, nullptr, 0, 0, 0, 0, 0, nullptr, nullptr, nullptr);
}

// Round 8
// 316.653 us; speedup vs baseline: 1.3238x; 1.2189x over previous
//
#include <hip/hip_runtime.h>
#include <stdint.h>

// Problem constants
#define BB 256
#define NNODE 12
#define PP 66
#define DNF 1024
#define DEF 1024
#define DD 512
#define MROWS (BB*PP)        // 16896
#define MNODE (BB*NNODE)     // 3072
#define MTILES (MROWS/128)   // 132

typedef __attribute__((ext_vector_type(8))) short s16x8;
typedef __attribute__((ext_vector_type(4))) float f32x4;
typedef __attribute__((ext_vector_type(8))) unsigned short u16x8;

__device__ __forceinline__ unsigned short f2bf(float f) {
  union { float f; unsigned u; } v; v.f = f;
  return (unsigned short)((v.u + 0x7FFFu + ((v.u >> 16) & 1u)) >> 16);
}
__device__ __forceinline__ float bf2f(unsigned short h) {
  union { unsigned u; float f; } v; v.u = ((unsigned)h) << 16;
  return v.f;
}

__device__ __forceinline__ void gll16(const void* g, void* l) {
  __builtin_amdgcn_global_load_lds(
      (const __attribute__((address_space(1))) void*)g,
      (__attribute__((address_space(3))) void*)l, 16, 0, 0);
}

// ---------------- fused prep kernel ----------------
__global__ __launch_bounds__(256) void k_prep(
    const float* __restrict__ node, unsigned short* __restrict__ node_bf,
    const float* __restrict__ W_node, unsigned short* __restrict__ WnT,
    const float* __restrict__ W_edge, unsigned short* __restrict__ WeT,
    const float* __restrict__ W0a, const float* __restrict__ W0b,
    const float* __restrict__ W0c, unsigned short* __restrict__ W0T,
    const float* __restrict__ W1a, const float* __restrict__ W1b,
    const float* __restrict__ W1c, unsigned short* __restrict__ W1T,
    const float* __restrict__ w2a, const float* __restrict__ w2b,
    const float* __restrict__ w2c,
    const float* __restrict__ b2a, const float* __restrict__ b2b,
    const float* __restrict__ b2c,
    unsigned short* __restrict__ W2T, float* __restrict__ b2pad,
    const float* __restrict__ b0a, const float* __restrict__ b0b,
    const float* __restrict__ b0c, float* __restrict__ b0cat,
    const float* __restrict__ b1a, const float* __restrict__ b1b,
    const float* __restrict__ b1c, float* __restrict__ b1cat) {
  __shared__ float tile[32][33];
  const int bid = blockIdx.x, t = threadIdx.x;
  if (bid < 3072) {
    int i = bid * 256 + t;
    float4 v = ((const float4*)node)[i];
    ushort4 o;
    o.x = f2bf(v.x); o.y = f2bf(v.y); o.z = f2bf(v.z); o.w = f2bf(v.w);
    ((ushort4*)node_bf)[i] = o;
  } else if (bid < 10240) {
    int tau = bid - 3072;
    const float* src; unsigned short* dst; int K, N;
    if (tau < 512)       { src = W_node; dst = WnT; K = 1024; N = 512; }
    else if (tau < 1024) { src = W_edge; dst = WeT; K = 1024; N = 512; tau -= 512; }
    else if (tau < 5632) {
      int hh = (tau - 1024) / 1536; tau = (tau - 1024) % 1536;
      src = hh == 0 ? W0a : (hh == 1 ? W0b : W0c);
      dst = W0T + (size_t)hh * 1024 * 1536; K = 1536; N = 1024;
    } else {
      int hh = (tau - 5632) / 512; tau = (tau - 5632) % 512;
      src = hh == 0 ? W1a : (hh == 1 ? W1b : W1c);
      dst = W1T + (size_t)hh * 512 * 1024; K = 1024; N = 512;
    }
    int ntiles = N >> 5;
    int kb = (tau / ntiles) * 32, nb = (tau % ntiles) * 32;
    int tx = t & 31, ty = t >> 5;
#pragma unroll
    for (int i = 0; i < 32; i += 8)
      tile[ty + i][tx] = src[(size_t)(kb + ty + i) * N + nb + tx];
    __syncthreads();
#pragma unroll
    for (int i = 0; i < 32; i += 8)
      dst[(size_t)(nb + ty + i) * K + kb + tx] = f2bf(tile[tx][ty + i]);
  } else if (bid < 11008) {
    int e = bid - 10240;
    int h = e >> 8, blk = e & 255;
    const int C = (h == 0) ? 9 : ((h == 1) ? 3 : 5);
    const float* W2 = (h == 0) ? w2a : ((h == 1) ? w2b : w2c);
    const float* b2 = (h == 0) ? b2a : ((h == 1) ? b2b : b2c);
    int idx = blk * 256 + t;
    int n = idx >> 9, k = idx & 511;
    W2T[(size_t)h * 65536 + idx] = (n < C) ? f2bf(W2[(size_t)k * C + n]) : (unsigned short)0;
    if (blk == 0 && t < 128)
      b2pad[h * 128 + t] = (t < C) ? b2[t] : 0.f;
  } else if (bid < 11020) {
    int j = bid - 11008;
    const float* b0 = (j < 4) ? b0a : (j < 8 ? b0b : b0c);
    b0cat[j * 256 + t] = b0[(j & 3) * 256 + t];
  } else {
    int j = bid - 11020;
    const float* b1 = (j < 2) ? b1a : (j < 4 ? b1b : b1c);
    b1cat[j * 256 + t] = b1[(j & 1) * 256 + t];
  }
}

// ---------------- gather: edge features/embeddings + node-pair table ----------------
__global__ __launch_bounds__(256) void k_gather_ef(const float* __restrict__ EF,
                                                   const float* __restrict__ EE,
                                                   const int* __restrict__ pairs,
                                                   const int* __restrict__ nrels,
                                                   unsigned short* __restrict__ efm,
                                                   unsigned short* __restrict__ emb,
                                                   int2* __restrict__ nodes) {
  int r = blockIdx.x;
  int b = r / PP;
  int i0 = pairs[r * 2 + 0], i1 = pairs[r * 2 + 1];
  int t = threadIdx.x;
  if (t == 0) {
    int p = r - b * PP;
    bool valid = p < nrels[b];
    nodes[r] = valid ? make_int2(b * NNODE + i0, b * NNODE + i1) : make_int2(-1, -1);
  }
  const float4* e01 = (const float4*)(EF + ((size_t)((b * NNODE + i0) * NNODE + i1)) * DEF);
  const float4* e10 = (const float4*)(EF + ((size_t)((b * NNODE + i1) * NNODE + i0)) * DEF);
  float4 a = e01[t], c = e10[t];
  ushort4 o;
  o.x = f2bf(0.5f * (a.x + c.x));
  o.y = f2bf(0.5f * (a.y + c.y));
  o.z = f2bf(0.5f * (a.z + c.z));
  o.w = f2bf(0.5f * (a.w + c.w));
  ((ushort4*)(efm + (size_t)r * DEF))[t] = o;
  const float2* g01 = (const float2*)(EE + ((size_t)((b * NNODE + i0) * NNODE + i1)) * DD);
  const float2* g10 = (const float2*)(EE + ((size_t)((b * NNODE + i1) * NNODE + i0)) * DD);
  float2 x = g01[t], y = g10[t];
  ushort2 eo;
  eo.x = f2bf(0.25f * (x.x + y.x));
  eo.y = f2bf(0.25f * (x.y + y.y));
  ((ushort2*)(emb + (size_t)r * DD))[t] = eo;
}

// ---------------- 128-tile MFMA GEMM (m97-family: 32 KB LDS, multi-block/CU) --
// C = A[M][ldA] (cols [0,K)) x BT[N][ldB]^T. 4 waves (2x2), BK=64,
// global_load_lds w=16 staging, chunk-XOR swizzle via pre-swizzled source.
// Multi-head fusion via blocksPerHead (>0).
// EPI: 0 = +bias -> bf16 ; 1 = e-assembly into ci_e (stride 512, masked) ;
//      2 = relu(+bias) -> bf16 ; 3 = layer-2 heads fp32 (own head logic) ;
//      4 = raw bf16 (no bias) ; 5 = L0': relu(bias + acc + npair) where
//      npair = nfa[i0]+nfb[i1] is LDS-staged per tile with COALESCED loads
//      (fixed r7's 128-scattered-2B-loads/thread epilogue).
template <int EPI>
__global__ __launch_bounds__(256) void k_gemm(
    const unsigned short* __restrict__ A, int ldA,
    const unsigned short* __restrict__ BT, int ldB, int K,
    int Ntiles,
    const float* __restrict__ bias,
    unsigned short* __restrict__ outb, int ldo,
    const unsigned short* __restrict__ em,
    const int* __restrict__ nrels,
    unsigned short* __restrict__ ci,
    int blocksPerHead, long long aHeadOff, long long bHeadOff,
    long long oHeadOff, int biasHeadOff,
    const int2* __restrict__ nodes,
    const unsigned short* __restrict__ nfa,
    const unsigned short* __restrict__ nfb) {
  // 33792 B: K-loop uses [0,32768) (A 16K | B 16K); EPI=5 epilogue reuses
  // [0,33792) as npair tile, ld=264 B (bank-shift 8/4-rows -> conflict-free).
  __shared__ __align__(16) unsigned short sm[16896];
  char* smc = (char*)sm;
  const int t = threadIdx.x;
  const int l = t & 63, w = t >> 6;
  const int wm = w >> 1, wn = w & 1;
  int bid = blockIdx.x;

  int head = 0;
  unsigned short* outp = outb;
  if constexpr (EPI == 3) {
    head = bid / MTILES;
    bid -= head * MTILES;
    A += (size_t)head * MROWS * DD;
    BT += (size_t)head * 128 * DD;
    bias += head * 128;
  } else {
    if (blocksPerHead > 0) {
      head = bid / blocksPerHead;
      bid -= head * blocksPerHead;
      A += (size_t)head * aHeadOff;
      BT += (size_t)head * bHeadOff;
      bias += head * biasHeadOff;
      outp = outb + (size_t)head * oHeadOff;
    }
  }
  const int tn = bid % Ntiles, tm = bid / Ntiles;

  const int lrow = l >> 3;
  const int scol = (l & 7) ^ lrow;       // pre-swizzled source chunk
  const unsigned short* Ap = A + (size_t)(tm * 128 + w * 8 + lrow) * ldA + scol * 8;
  const unsigned short* Bp = BT + (size_t)(tn * 128 + w * 8 + lrow) * ldB + scol * 8;

  f32x4 acc[4][4] = {};
  const int hi = l >> 4, l15 = l & 15, l7 = l & 7;
  const int nk = K >> 6;

  for (int kt = 0; kt < nk; ++kt) {
#pragma unroll
    for (int c = 0; c < 4; ++c) {
      gll16(Ap + (size_t)c * 32 * ldA, smc + c * 4096 + w * 1024);
      gll16(Bp + (size_t)c * 32 * ldB, smc + 16384 + c * 4096 + w * 1024);
    }
    __syncthreads();
#pragma unroll
    for (int kk = 0; kk < 2; ++kk) {
      const int cb = (((kk << 2) + hi) ^ l7) << 4;
      s16x8 af[4], bfr[4];
#pragma unroll
      for (int m = 0; m < 4; m++)
        af[m] = *(const s16x8*)(smc + (wm * 64 + m * 16 + l15) * 128 + cb);
#pragma unroll
      for (int n = 0; n < 4; n++)
        bfr[n] = *(const s16x8*)(smc + 16384 + (wn * 64 + n * 16 + l15) * 128 + cb);
#pragma unroll
      for (int m = 0; m < 4; m++)
#pragma unroll
        for (int n = 0; n < 4; n++)
          asm volatile("v_mfma_f32_16x16x32_bf16 %0, %1, %2, %0"
                       : "+v"(acc[m][n])
                       : "v"(af[m]), "v"(bfr[n]));
    }
    __syncthreads();
    Ap += 64;
    Bp += 64;
  }
  asm volatile("s_nop 7\n\ts_nop 7\n\ts_nop 7" :::);  // MFMA->VALU hazard guard

  if constexpr (EPI == 5) {
    // Stage npair = nfa[i0]+nfb[i1] (bf16 sum) for the whole 128x128 tile.
    // Coalesced: 16 lanes x 16B cover one 256B row segment. 8 rows/thread.
    // K-loop LDS is dead (final barrier passed); safe to overwrite.
    const int se_r = t >> 4;          // 0..15
    const int se_c = (t & 15) * 8;    // 0..120 (ushort col)
#pragma unroll
    for (int it = 0; it < 8; ++it) {
      const int rr = se_r + (it << 4);
      const int2 nn = nodes[tm * 128 + rr];
      union { unsigned short s[8]; unsigned long long q[2]; } ov;
      if (nn.x >= 0) {
        u16x8 va = *(const u16x8*)&nfa[(size_t)nn.x * 3072 + tn * 128 + se_c];
        u16x8 vb = *(const u16x8*)&nfb[(size_t)nn.y * 3072 + tn * 128 + se_c];
#pragma unroll
        for (int j = 0; j < 8; ++j)
          ov.s[j] = f2bf(bf2f(va[j]) + bf2f(vb[j]));
      } else {
        ov.q[0] = 0; ov.q[1] = 0;
      }
      *(unsigned long long*)(smc + rr * 264 + se_c * 2) = ov.q[0];
      *(unsigned long long*)(smc + rr * 264 + se_c * 2 + 8) = ov.q[1];
    }
    __syncthreads();
  }

  // C/D layout: col = lane&15, row = (lane>>4)*4 + reg
  const int gr_base = tm * 128 + wm * 64 + (hi << 2);
  const int gc_base = tn * 128 + wn * 64 + l15;
  const int lr_base = wm * 64 + (hi << 2);      // local row within tile
  const int lc_base = wn * 64 + l15;            // local col within tile

  int Cc = 0; size_t obase = 0;
  if constexpr (EPI == 3) {
    Cc = (head == 0) ? 9 : ((head == 1) ? 3 : 5);
    obase = (head == 0) ? 0 : ((head == 1) ? (size_t)MROWS * 9 : (size_t)MROWS * 12);
  }

#pragma unroll
  for (int n = 0; n < 4; n++) {
    const int gc = gc_base + n * 16;
    const float bv = (EPI == 4) ? 0.f : bias[gc];
#pragma unroll
    for (int m = 0; m < 4; m++) {
#pragma unroll
      for (int i = 0; i < 4; i++) {
        const int gr = gr_base + m * 16 + i;
        float v = acc[m][n][i] + bv;
        if constexpr (EPI == 0 || EPI == 4) {
          outp[(size_t)gr * ldo + gc] = f2bf(v);
        } else if constexpr (EPI == 1) {
          int b = gr / PP, p = gr - b * PP;
          float e = bf2f(em[(size_t)gr * DD + gc]) + 0.5f * v;
          ci[(size_t)gr * DD + gc] =
              (p < nrels[b]) ? f2bf(e) : (unsigned short)0;
        } else if constexpr (EPI == 2) {
          outp[(size_t)gr * ldo + gc] = f2bf(v > 0.f ? v : 0.f);
        } else if constexpr (EPI == 5) {
          const int lr = lr_base + m * 16 + i;
          const int lc = lc_base + n * 16;
          v += bf2f(*(const unsigned short*)(smc + lr * 264 + lc * 2));
          outp[(size_t)gr * ldo + gc] = f2bf(v > 0.f ? v : 0.f);
        } else {
          if (gc < Cc)
            ((float*)outb)[obase + (size_t)gr * Cc + gc] = v;
        }
      }
    }
  }
}

// ---------------- launcher ----------------
extern "C" void kernel_launch(void* const* d_in, const int* in_sizes, int n_in,
                              void* d_out, int out_size, void* d_ws, size_t ws_size,
                              hipStream_t stream) {
  const float* node   = (const float*)d_in[0];
  const float* EF     = (const float*)d_in[1];
  const float* EE     = (const float*)d_in[2];
  const int*   pairs  = (const int*)d_in[3];
  const int*   nrels  = (const int*)d_in[4];
  const float* W_node = (const float*)d_in[5];
  const float* b_node = (const float*)d_in[6];
  const float* W_edge = (const float*)d_in[7];
  const float* b_edge = (const float*)d_in[8];
  const float* hW0[3] = {(const float*)d_in[9],  (const float*)d_in[15], (const float*)d_in[21]};
  const float* hb0[3] = {(const float*)d_in[10], (const float*)d_in[16], (const float*)d_in[22]};
  const float* hW1[3] = {(const float*)d_in[11], (const float*)d_in[17], (const float*)d_in[23]};
  const float* hb1[3] = {(const float*)d_in[12], (const float*)d_in[18], (const float*)d_in[24]};
  const float* hW2[3] = {(const float*)d_in[13], (const float*)d_in[19], (const float*)d_in[25]};
  const float* hb2[3] = {(const float*)d_in[14], (const float*)d_in[20], (const float*)d_in[26]};

  char* ws = (char*)d_ws;
  size_t off = 0;
  auto alloc = [&](size_t bytes) {
    char* p = ws + off;
    off += (bytes + 255) & ~(size_t)255;
    return p;
  };
  // --- persistent front ---
  unsigned short* WnT   = (unsigned short*)alloc((size_t)512 * 1024 * 2);
  unsigned short* WeT   = (unsigned short*)alloc((size_t)512 * 1024 * 2);
  unsigned short* W0T   = (unsigned short*)alloc((size_t)3072 * 1536 * 2);
  unsigned short* W1T   = (unsigned short*)alloc((size_t)3 * 512 * 1024 * 2);
  unsigned short* W2T   = (unsigned short*)alloc((size_t)3 * 128 * 512 * 2);
  float*          b2pad = (float*)alloc((size_t)3 * 128 * 4);
  float*          b0cat = (float*)alloc((size_t)3072 * 4);
  float*          b1cat = (float*)alloc((size_t)1536 * 4);
  int2*           nodes = (int2*)alloc((size_t)MROWS * 8);
  // --- zone A: efm+EMb (dead after e-GEMM) -> reused as nfa/nfb, then h1 ---
  size_t zoneA = off;
  unsigned short* efm = (unsigned short*)alloc((size_t)MROWS * DEF * 2);  // 34.6M
  unsigned short* EMb = (unsigned short*)alloc((size_t)MROWS * DD * 2);   // 17.3M
  // --- zone B: ci_e (dead after L0') ---
  unsigned short* ci_e = (unsigned short*)alloc((size_t)MROWS * DD * 2);  // 17.3M
  // --- zone C: node_bf+nf (dead before L0') -> overlaid by h0big ---
  size_t zoneC = off;
  unsigned short* node_bf = (unsigned short*)alloc((size_t)MNODE * DNF * 2);
  unsigned short* nf      = (unsigned short*)alloc((size_t)MNODE * DD * 2);
  // overlays
  unsigned short* nfa   = (unsigned short*)(ws + zoneA);                 // 18.9M
  unsigned short* nfb   = nfa + (size_t)MNODE * 3072;                    // 18.9M
  unsigned short* h1    = (unsigned short*)(ws + zoneA);                 // 51.9M (after L0')
  unsigned short* h0big = (unsigned short*)(ws + zoneC);                 // 104M

  // 1. prep: conv + transposes + W2 pad + bias concats (1 launch)
  k_prep<<<11026, 256, 0, stream>>>(node, node_bf, W_node, WnT, W_edge, WeT,
      hW0[0], hW0[1], hW0[2], W0T, hW1[0], hW1[1], hW1[2], W1T,
      hW2[0], hW2[1], hW2[2], hb2[0], hb2[1], hb2[2], W2T, b2pad,
      hb0[0], hb0[1], hb0[2], b0cat, hb1[0], hb1[1], hb1[2], b1cat);
  // 2. edge gathers + node-pair table
  k_gather_ef<<<MROWS, 256, 0, stream>>>(EF, EE, pairs, nrels, efm, EMb, nodes);

  // 3. nf = node_bf @ WnT^T + b_node  (M=3072,N=512,K=1024)
  k_gemm<0><<<(MNODE / 128) * 4, 256, 0, stream>>>(
      node_bf, 1024, WnT, 1024, 1024, 4, b_node, nf, 512,
      nullptr, nullptr, nullptr, 0, 0, 0, 0, 0, nullptr, nullptr, nullptr);
  // 4. e -> ci_e: 0.25*(ee+ee') + 0.5*(efm@We + b_edge), masked  (M=16896,N=512,K=1024)
  k_gemm<1><<<MTILES * 4, 256, 0, stream>>>(
      efm, 1024, WeT, 1024, 1024, 4, b_edge, nullptr, 0,
      EMb, nrels, ci_e, 0, 0, 0, 0, 0, nullptr, nullptr, nullptr);
  // 5. node-side layer-0 partials, ONE fused dispatch (2 "heads" = a/b halves):
  //    nfa = nf@W0[0:512,:]^T ; nfb = nf@W0[512:1024,:]^T  (each M=3072,N=3072,K=512)
  k_gemm<4><<<2 * (MNODE / 128) * 24, 256, 0, stream>>>(
      nf, 512, W0T, 1536, 512, 24, nullptr, nfa, 3072,
      nullptr, nullptr, nullptr, (MNODE / 128) * 24,
      0, 512, (long long)MNODE * 3072, 0, nullptr, nullptr, nullptr);

  // 6. L0': h0 = relu(ci_e @ W0[1024:1536,:]^T + b0 + npair)  (LDS-staged gather)
  //    M=16896, N=3072, K=512 -> grid 132 x 24 = 3168
  k_gemm<5><<<MTILES * 24, 256, 0, stream>>>(
      ci_e, 512, W0T + 1024, 1536, 512, 24, b0cat, h0big, 3072,
      nullptr, nullptr, nullptr, 0, 0, 0, 0, 0, nodes, nfa, nfb);

  // 7. L1 fused over heads: h1[h] = relu(h0[:,h*1024:] @ W1[h]^T + b1[h])
  //    per head M=16896, N=512, K=1024 -> grid 3 x 132 x 4 = 1584
  k_gemm<2><<<3 * MTILES * 4, 256, 0, stream>>>(
      h0big, 3072, W1T, 1024, 1024, 4, b1cat, h1, 512,
      nullptr, nullptr, nullptr, MTILES * 4,
      1024, (long long)512 * 1024, (long long)MROWS * DD, 512,
      nullptr, nullptr, nullptr);

  // 8. L2: merged padded GEMM -> d_out (fp32) lr | cr | mr  (grid 3 x 132)
  k_gemm<3><<<3 * MTILES, 256, 0, stream>>>(
      h1, 512, W2T, 512, 512, 1, b2pad, (unsigned short*)d_out, 0,
      nullptr, nullptr, nullptr, 0, 0, 0, 0, 0, nullptr, nullptr, nullptr);
}

// Round 9
// 294.024 us; speedup vs baseline: 1.4257x; 1.0770x over previous
//
#include <hip/hip_runtime.h>
#include <stdint.h>

// Problem constants
#define BB 256
#define NNODE 12
#define PP 66
#define DNF 1024
#define DEF 1024
#define DD 512
#define MROWS (BB*PP)        // 16896
#define MNODE (BB*NNODE)     // 3072
#define MTILES (MROWS/128)   // 132

typedef __attribute__((ext_vector_type(8))) short s16x8;
typedef __attribute__((ext_vector_type(4))) float f32x4;
typedef __attribute__((ext_vector_type(8))) unsigned short u16x8;

__device__ __forceinline__ unsigned short f2bf(float f) {
  union { float f; unsigned u; } v; v.f = f;
  return (unsigned short)((v.u + 0x7FFFu + ((v.u >> 16) & 1u)) >> 16);
}
__device__ __forceinline__ float bf2f(unsigned short h) {
  union { unsigned u; float f; } v; v.u = ((unsigned)h) << 16;
  return v.f;
}

__device__ __forceinline__ void gll16(const void* g, void* l) {
  __builtin_amdgcn_global_load_lds(
      (const __attribute__((address_space(1))) void*)g,
      (__attribute__((address_space(3))) void*)l, 16, 0, 0);
}

// ---------------- scan: exclusive prefix of num_rels + pad-init ----------------
__global__ __launch_bounds__(256) void k_scan(const int* __restrict__ nrels,
                                              int* __restrict__ offs,
                                              int* __restrict__ Mv,
                                              int2* __restrict__ nodes) {
  __shared__ int s[256];
  const int t = threadIdx.x;
  const int val = nrels[t];
  s[t] = val;
  __syncthreads();
  for (int d = 1; d < 256; d <<= 1) {
    int x = (t >= d) ? s[t - d] : 0;
    __syncthreads();
    s[t] += x;
    __syncthreads();
  }
  offs[t] = s[t] - val;              // exclusive
  __syncthreads();
  const int total = s[255];
  if (t == 0) *Mv = total;
  // zero-init up to 128 pad rows of the compact nodes table (bounds OOB gathers)
  if (t < 128) {
    int cr = total + t;
    if (cr < MROWS) nodes[cr] = make_int2(0, 0);
  }
}

// ---------------- invalid-row constants ----------------
// h1c[h][n] = relu(b1[h][n] + sum_k relu(b0[h][k]) * W1[h][k][n])   (fp32 exact)
__global__ __launch_bounds__(128) void k_h1c(
    const float* __restrict__ b0a, const float* __restrict__ b0b,
    const float* __restrict__ b0c,
    const float* __restrict__ W1a, const float* __restrict__ W1b,
    const float* __restrict__ W1c,
    const float* __restrict__ b1a, const float* __restrict__ b1b,
    const float* __restrict__ b1c, float* __restrict__ h1c) {
  const int blk = blockIdx.x;            // 0..11
  const int h = blk >> 2, s = blk & 3;
  const float* b0 = h == 0 ? b0a : (h == 1 ? b0b : b0c);
  const float* W1 = h == 0 ? W1a : (h == 1 ? W1b : W1c);
  const float* b1 = h == 0 ? b1a : (h == 1 ? b1b : b1c);
  const int n = s * 128 + threadIdx.x;
  float acc = b1[n];
  for (int k = 0; k < 1024; ++k)
    acc += fmaxf(b0[k], 0.f) * W1[(size_t)k * 512 + n];
  h1c[h * 512 + n] = fmaxf(acc, 0.f);
}

// outc[c] = b2 + h1c @ W2   (17 values: 9 lr | 3 cr | 5 mr)
__global__ __launch_bounds__(64) void k_outc(
    const float* __restrict__ h1c,
    const float* __restrict__ w2a, const float* __restrict__ w2b,
    const float* __restrict__ w2c,
    const float* __restrict__ b2a, const float* __restrict__ b2b,
    const float* __restrict__ b2c, float* __restrict__ outc) {
  const int c = threadIdx.x;
  if (c >= 17) return;
  const int h = c < 9 ? 0 : (c < 12 ? 1 : 2);
  const int cc = c < 9 ? c : (c < 12 ? c - 9 : c - 12);
  const int C = h == 0 ? 9 : (h == 1 ? 3 : 5);
  const float* W2 = h == 0 ? w2a : (h == 1 ? w2b : w2c);
  const float* b2 = h == 0 ? b2a : (h == 1 ? b2b : b2c);
  const float* hv = h1c + h * 512;
  float acc = b2[cc];
  for (int k = 0; k < 512; ++k) acc += hv[k] * W2[(size_t)k * C + cc];
  outc[c] = acc;
}

// fill d_out with constant rows (valid rows overwritten later by L2 scatter)
__global__ __launch_bounds__(256) void k_fillout(const float* __restrict__ outc,
                                                 float* __restrict__ out) {
  const int e = blockIdx.x * 256 + threadIdx.x;
  if (e >= MROWS * 17) return;
  int c;
  if (e < MROWS * 9) c = e % 9;
  else if (e < MROWS * 12) c = 9 + (e - MROWS * 9) % 3;
  else c = 12 + (e - MROWS * 12) % 5;
  out[e] = outc[c];
}

// ---------------- fused prep kernel ----------------
__global__ __launch_bounds__(256) void k_prep(
    const float* __restrict__ node, unsigned short* __restrict__ node_bf,
    const float* __restrict__ W_node, unsigned short* __restrict__ WnT,
    const float* __restrict__ W_edge, unsigned short* __restrict__ WeT,
    const float* __restrict__ W0a, const float* __restrict__ W0b,
    const float* __restrict__ W0c, unsigned short* __restrict__ W0T,
    const float* __restrict__ W1a, const float* __restrict__ W1b,
    const float* __restrict__ W1c, unsigned short* __restrict__ W1T,
    const float* __restrict__ w2a, const float* __restrict__ w2b,
    const float* __restrict__ w2c,
    const float* __restrict__ b2a, const float* __restrict__ b2b,
    const float* __restrict__ b2c,
    unsigned short* __restrict__ W2T, float* __restrict__ b2pad,
    const float* __restrict__ b0a, const float* __restrict__ b0b,
    const float* __restrict__ b0c, float* __restrict__ b0cat,
    const float* __restrict__ b1a, const float* __restrict__ b1b,
    const float* __restrict__ b1c, float* __restrict__ b1cat) {
  __shared__ float tile[32][33];
  const int bid = blockIdx.x, t = threadIdx.x;
  if (bid < 3072) {
    int i = bid * 256 + t;
    float4 v = ((const float4*)node)[i];
    ushort4 o;
    o.x = f2bf(v.x); o.y = f2bf(v.y); o.z = f2bf(v.z); o.w = f2bf(v.w);
    ((ushort4*)node_bf)[i] = o;
  } else if (bid < 10240) {
    int tau = bid - 3072;
    const float* src; unsigned short* dst; int K, N;
    if (tau < 512)       { src = W_node; dst = WnT; K = 1024; N = 512; }
    else if (tau < 1024) { src = W_edge; dst = WeT; K = 1024; N = 512; tau -= 512; }
    else if (tau < 5632) {
      int hh = (tau - 1024) / 1536; tau = (tau - 1024) % 1536;
      src = hh == 0 ? W0a : (hh == 1 ? W0b : W0c);
      dst = W0T + (size_t)hh * 1024 * 1536; K = 1536; N = 1024;
    } else {
      int hh = (tau - 5632) / 512; tau = (tau - 5632) % 512;
      src = hh == 0 ? W1a : (hh == 1 ? W1b : W1c);
      dst = W1T + (size_t)hh * 512 * 1024; K = 1024; N = 512;
    }
    int ntiles = N >> 5;
    int kb = (tau / ntiles) * 32, nb = (tau % ntiles) * 32;
    int tx = t & 31, ty = t >> 5;
#pragma unroll
    for (int i = 0; i < 32; i += 8)
      tile[ty + i][tx] = src[(size_t)(kb + ty + i) * N + nb + tx];
    __syncthreads();
#pragma unroll
    for (int i = 0; i < 32; i += 8)
      dst[(size_t)(nb + ty + i) * K + kb + tx] = f2bf(tile[tx][ty + i]);
  } else if (bid < 11008) {
    int e = bid - 10240;
    int h = e >> 8, blk = e & 255;
    const int C = (h == 0) ? 9 : ((h == 1) ? 3 : 5);
    const float* W2 = (h == 0) ? w2a : ((h == 1) ? w2b : w2c);
    const float* b2 = (h == 0) ? b2a : ((h == 1) ? b2b : b2c);
    int idx = blk * 256 + t;
    int n = idx >> 9, k = idx & 511;
    W2T[(size_t)h * 65536 + idx] = (n < C) ? f2bf(W2[(size_t)k * C + n]) : (unsigned short)0;
    if (blk == 0 && t < 128)
      b2pad[h * 128 + t] = (t < C) ? b2[t] : 0.f;
  } else if (bid < 11020) {
    int j = bid - 11008;
    const float* b0 = (j < 4) ? b0a : (j < 8 ? b0b : b0c);
    b0cat[j * 256 + t] = b0[(j & 3) * 256 + t];
  } else {
    int j = bid - 11020;
    const float* b1 = (j < 2) ? b1a : (j < 4 ? b1b : b1c);
    b1cat[j * 256 + t] = b1[(j & 1) * 256 + t];
  }
}

// ------- gather (COMPACT): edge features/embeddings + node-pair + row map ------
__global__ __launch_bounds__(256) void k_gather_ef(const float* __restrict__ EF,
                                                   const float* __restrict__ EE,
                                                   const int* __restrict__ pairs,
                                                   const int* __restrict__ nrels,
                                                   const int* __restrict__ offs,
                                                   unsigned short* __restrict__ efm,
                                                   unsigned short* __restrict__ emb,
                                                   int2* __restrict__ nodes,
                                                   int* __restrict__ rmap) {
  int r = blockIdx.x;
  int b = r / PP, p = r - b * PP;
  if (p >= nrels[b]) return;          // invalid row: no compact slot
  const int cr = offs[b] + p;         // compact row
  int i0 = pairs[r * 2 + 0], i1 = pairs[r * 2 + 1];
  int t = threadIdx.x;
  if (t == 0) {
    nodes[cr] = make_int2(b * NNODE + i0, b * NNODE + i1);
    rmap[cr] = r;
  }
  const float4* e01 = (const float4*)(EF + ((size_t)((b * NNODE + i0) * NNODE + i1)) * DEF);
  const float4* e10 = (const float4*)(EF + ((size_t)((b * NNODE + i1) * NNODE + i0)) * DEF);
  float4 a = e01[t], c = e10[t];
  ushort4 o;
  o.x = f2bf(0.5f * (a.x + c.x));
  o.y = f2bf(0.5f * (a.y + c.y));
  o.z = f2bf(0.5f * (a.z + c.z));
  o.w = f2bf(0.5f * (a.w + c.w));
  ((ushort4*)(efm + (size_t)cr * DEF))[t] = o;
  const float2* g01 = (const float2*)(EE + ((size_t)((b * NNODE + i0) * NNODE + i1)) * DD);
  const float2* g10 = (const float2*)(EE + ((size_t)((b * NNODE + i1) * NNODE + i0)) * DD);
  float2 x = g01[t], y = g10[t];
  ushort2 eo;
  eo.x = f2bf(0.25f * (x.x + y.x));
  eo.y = f2bf(0.25f * (x.y + y.y));
  ((ushort2*)(emb + (size_t)cr * DD))[t] = eo;
}

// ---------------- 128-tile MFMA GEMM (m97-family: 32 KB LDS, multi-block/CU) --
// EPI: 0 = +bias -> bf16 ; 1 = e-assembly into ci_e (compact, no mask) ;
//      2 = relu(+bias) -> bf16 ; 3 = layer-2 heads fp32, scatter via rmap ;
//      4 = raw bf16 (no bias) ; 5 = L0': relu(bias + acc + npair), LDS-staged.
// Mvp != nullptr -> per-block early exit when tm*128 >= *Mvp (compact M).
template <int EPI>
__global__ __launch_bounds__(256) void k_gemm(
    const unsigned short* __restrict__ A, int ldA,
    const unsigned short* __restrict__ BT, int ldB, int K,
    int Ntiles,
    const float* __restrict__ bias,
    unsigned short* __restrict__ outb, int ldo,
    const unsigned short* __restrict__ em,
    const int* __restrict__ Mvp,
    unsigned short* __restrict__ ci,
    int blocksPerHead, long long aHeadOff, long long bHeadOff,
    long long oHeadOff, int biasHeadOff,
    const int2* __restrict__ nodes,
    const unsigned short* __restrict__ nfa,
    const unsigned short* __restrict__ nfb,
    const int* __restrict__ rmap) {
  __shared__ __align__(16) unsigned short sm[16896];
  char* smc = (char*)sm;
  const int t = threadIdx.x;
  const int l = t & 63, w = t >> 6;
  const int wm = w >> 1, wn = w & 1;
  int bid = blockIdx.x;

  int head = 0;
  unsigned short* outp = outb;
  if constexpr (EPI == 3) {
    head = bid / MTILES;
    bid -= head * MTILES;
    A += (size_t)head * MROWS * DD;
    BT += (size_t)head * 128 * DD;
    bias += head * 128;
  } else {
    if (blocksPerHead > 0) {
      head = bid / blocksPerHead;
      bid -= head * blocksPerHead;
      A += (size_t)head * aHeadOff;
      BT += (size_t)head * bHeadOff;
      bias += head * biasHeadOff;
      outp = outb + (size_t)head * oHeadOff;
    }
  }
  const int tn = bid % Ntiles, tm = bid / Ntiles;

  int Mv = MROWS;
  if (Mvp) {
    Mv = *Mvp;
    if (tm * 128 >= Mv) return;   // compact early-exit (uniform branch)
  }

  const int lrow = l >> 3;
  const int scol = (l & 7) ^ lrow;       // pre-swizzled source chunk
  const unsigned short* Ap = A + (size_t)(tm * 128 + w * 8 + lrow) * ldA + scol * 8;
  const unsigned short* Bp = BT + (size_t)(tn * 128 + w * 8 + lrow) * ldB + scol * 8;

  f32x4 acc[4][4] = {};
  const int hi = l >> 4, l15 = l & 15, l7 = l & 7;
  const int nk = K >> 6;

  for (int kt = 0; kt < nk; ++kt) {
#pragma unroll
    for (int c = 0; c < 4; ++c) {
      gll16(Ap + (size_t)c * 32 * ldA, smc + c * 4096 + w * 1024);
      gll16(Bp + (size_t)c * 32 * ldB, smc + 16384 + c * 4096 + w * 1024);
    }
    __syncthreads();
#pragma unroll
    for (int kk = 0; kk < 2; ++kk) {
      const int cb = (((kk << 2) + hi) ^ l7) << 4;
      s16x8 af[4], bfr[4];
#pragma unroll
      for (int m = 0; m < 4; m++)
        af[m] = *(const s16x8*)(smc + (wm * 64 + m * 16 + l15) * 128 + cb);
#pragma unroll
      for (int n = 0; n < 4; n++)
        bfr[n] = *(const s16x8*)(smc + 16384 + (wn * 64 + n * 16 + l15) * 128 + cb);
#pragma unroll
      for (int m = 0; m < 4; m++)
#pragma unroll
        for (int n = 0; n < 4; n++)
          asm volatile("v_mfma_f32_16x16x32_bf16 %0, %1, %2, %0"
                       : "+v"(acc[m][n])
                       : "v"(af[m]), "v"(bfr[n]));
    }
    __syncthreads();
    Ap += 64;
    Bp += 64;
  }
  asm volatile("s_nop 7\n\ts_nop 7\n\ts_nop 7" :::);  // MFMA->VALU hazard guard

  if constexpr (EPI == 5) {
    // Stage npair = nfa[i0]+nfb[i1] for the 128x128 tile, coalesced 16B/lane.
    const int se_r = t >> 4;
    const int se_c = (t & 15) * 8;
#pragma unroll
    for (int it = 0; it < 8; ++it) {
      const int rr = se_r + (it << 4);
      const int2 nn = nodes[tm * 128 + rr];   // pad rows zero-initialized
      union { unsigned short s[8]; unsigned long long q[2]; } ov;
      u16x8 va = *(const u16x8*)&nfa[(size_t)nn.x * 3072 + tn * 128 + se_c];
      u16x8 vb = *(const u16x8*)&nfb[(size_t)nn.y * 3072 + tn * 128 + se_c];
#pragma unroll
      for (int j = 0; j < 8; ++j)
        ov.s[j] = f2bf(bf2f(va[j]) + bf2f(vb[j]));
      *(unsigned long long*)(smc + rr * 264 + se_c * 2) = ov.q[0];
      *(unsigned long long*)(smc + rr * 264 + se_c * 2 + 8) = ov.q[1];
    }
    __syncthreads();
  }

  // C/D layout: col = lane&15, row = (lane>>4)*4 + reg
  const int gr_base = tm * 128 + wm * 64 + (hi << 2);
  const int gc_base = tn * 128 + wn * 64 + l15;
  const int lr_base = wm * 64 + (hi << 2);
  const int lc_base = wn * 64 + l15;

  int Cc = 0; size_t obase = 0;
  if constexpr (EPI == 3) {
    Cc = (head == 0) ? 9 : ((head == 1) ? 3 : 5);
    obase = (head == 0) ? 0 : ((head == 1) ? (size_t)MROWS * 9 : (size_t)MROWS * 12);
  }

#pragma unroll
  for (int n = 0; n < 4; n++) {
    const int gc = gc_base + n * 16;
    const float bv = (EPI == 4) ? 0.f : bias[gc];
#pragma unroll
    for (int m = 0; m < 4; m++) {
#pragma unroll
      for (int i = 0; i < 4; i++) {
        const int gr = gr_base + m * 16 + i;
        float v = acc[m][n][i] + bv;
        if constexpr (EPI == 0 || EPI == 4) {
          outp[(size_t)gr * ldo + gc] = f2bf(v);
        } else if constexpr (EPI == 1) {
          // compact rows are all valid: no mask
          float e = bf2f(em[(size_t)gr * DD + gc]) + 0.5f * v;
          ci[(size_t)gr * DD + gc] = f2bf(e);
        } else if constexpr (EPI == 2) {
          outp[(size_t)gr * ldo + gc] = f2bf(v > 0.f ? v : 0.f);
        } else if constexpr (EPI == 5) {
          const int lr = lr_base + m * 16 + i;
          const int lc = lc_base + n * 16;
          v += bf2f(*(const unsigned short*)(smc + lr * 264 + lc * 2));
          outp[(size_t)gr * ldo + gc] = f2bf(v > 0.f ? v : 0.f);
        } else {
          if (gc < Cc && gr < Mv)
            ((float*)outb)[obase + (size_t)rmap[gr] * Cc + gc] = v;
        }
      }
    }
  }
}

// ---------------- launcher ----------------
extern "C" void kernel_launch(void* const* d_in, const int* in_sizes, int n_in,
                              void* d_out, int out_size, void* d_ws, size_t ws_size,
                              hipStream_t stream) {
  const float* node   = (const float*)d_in[0];
  const float* EF     = (const float*)d_in[1];
  const float* EE     = (const float*)d_in[2];
  const int*   pairs  = (const int*)d_in[3];
  const int*   nrels  = (const int*)d_in[4];
  const float* W_node = (const float*)d_in[5];
  const float* b_node = (const float*)d_in[6];
  const float* W_edge = (const float*)d_in[7];
  const float* b_edge = (const float*)d_in[8];
  const float* hW0[3] = {(const float*)d_in[9],  (const float*)d_in[15], (const float*)d_in[21]};
  const float* hb0[3] = {(const float*)d_in[10], (const float*)d_in[16], (const float*)d_in[22]};
  const float* hW1[3] = {(const float*)d_in[11], (const float*)d_in[17], (const float*)d_in[23]};
  const float* hb1[3] = {(const float*)d_in[12], (const float*)d_in[18], (const float*)d_in[24]};
  const float* hW2[3] = {(const float*)d_in[13], (const float*)d_in[19], (const float*)d_in[25]};
  const float* hb2[3] = {(const float*)d_in[14], (const float*)d_in[20], (const float*)d_in[26]};

  char* ws = (char*)d_ws;
  size_t off = 0;
  auto alloc = [&](size_t bytes) {
    char* p = ws + off;
    off += (bytes + 255) & ~(size_t)255;
    return p;
  };
  // --- persistent front ---
  unsigned short* WnT   = (unsigned short*)alloc((size_t)512 * 1024 * 2);
  unsigned short* WeT   = (unsigned short*)alloc((size_t)512 * 1024 * 2);
  unsigned short* W0T   = (unsigned short*)alloc((size_t)3072 * 1536 * 2);
  unsigned short* W1T   = (unsigned short*)alloc((size_t)3 * 512 * 1024 * 2);
  unsigned short* W2T   = (unsigned short*)alloc((size_t)3 * 128 * 512 * 2);
  float*          b2pad = (float*)alloc((size_t)3 * 128 * 4);
  float*          b0cat = (float*)alloc((size_t)3072 * 4);
  float*          b1cat = (float*)alloc((size_t)1536 * 4);
  int2*           nodes = (int2*)alloc((size_t)MROWS * 8);
  int*            offs  = (int*)alloc((size_t)256 * 4);
  int*            Mv    = (int*)alloc(256);
  int*            rmap  = (int*)alloc((size_t)MROWS * 4);
  float*          h1c   = (float*)alloc((size_t)1536 * 4);
  float*          outc  = (float*)alloc((size_t)32 * 4);
  // --- zone A: efm+EMb (dead after e-GEMM) -> reused as nfa/nfb, then h1 ---
  size_t zoneA = off;
  unsigned short* efm = (unsigned short*)alloc((size_t)MROWS * DEF * 2);  // 34.6M
  unsigned short* EMb = (unsigned short*)alloc((size_t)MROWS * DD * 2);   // 17.3M
  // --- zone B: ci_e (dead after L0') ---
  unsigned short* ci_e = (unsigned short*)alloc((size_t)MROWS * DD * 2);  // 17.3M
  // --- zone C: node_bf+nf (dead before L0') -> overlaid by h0big ---
  size_t zoneC = off;
  unsigned short* node_bf = (unsigned short*)alloc((size_t)MNODE * DNF * 2);
  unsigned short* nf      = (unsigned short*)alloc((size_t)MNODE * DD * 2);
  // overlays
  unsigned short* nfa   = (unsigned short*)(ws + zoneA);                 // 18.9M
  unsigned short* nfb   = nfa + (size_t)MNODE * 3072;                    // 18.9M
  unsigned short* h1    = (unsigned short*)(ws + zoneA);                 // 51.9M (after L0')
  unsigned short* h0big = (unsigned short*)(ws + zoneC);                 // 104M

  // 0. prefix scan of num_rels + nodes pad init ; invalid-row constants
  k_scan<<<1, 256, 0, stream>>>(nrels, offs, Mv, nodes);
  k_h1c<<<12, 128, 0, stream>>>(hb0[0], hb0[1], hb0[2], hW1[0], hW1[1], hW1[2],
                                hb1[0], hb1[1], hb1[2], h1c);
  k_outc<<<1, 64, 0, stream>>>(h1c, hW2[0], hW2[1], hW2[2],
                               hb2[0], hb2[1], hb2[2], outc);
  k_fillout<<<(MROWS * 17 + 255) / 256, 256, 0, stream>>>(outc, (float*)d_out);

  // 1. prep: conv + transposes + W2 pad + bias concats (1 launch)
  k_prep<<<11026, 256, 0, stream>>>(node, node_bf, W_node, WnT, W_edge, WeT,
      hW0[0], hW0[1], hW0[2], W0T, hW1[0], hW1[1], hW1[2], W1T,
      hW2[0], hW2[1], hW2[2], hb2[0], hb2[1], hb2[2], W2T, b2pad,
      hb0[0], hb0[1], hb0[2], b0cat, hb1[0], hb1[1], hb1[2], b1cat);
  // 2. compact edge gathers + node-pair table + row map
  k_gather_ef<<<MROWS, 256, 0, stream>>>(EF, EE, pairs, nrels, offs,
                                         efm, EMb, nodes, rmap);

  // 3. nf = node_bf @ WnT^T + b_node  (M=3072,N=512,K=1024; node space, full)
  k_gemm<0><<<(MNODE / 128) * 4, 256, 0, stream>>>(
      node_bf, 1024, WnT, 1024, 1024, 4, b_node, nf, 512,
      nullptr, nullptr, nullptr, 0, 0, 0, 0, 0, nullptr, nullptr, nullptr, nullptr);
  // 4. e -> ci_e (compact): 0.25*(ee+ee') + 0.5*(efm@We + b_edge)
  k_gemm<1><<<MTILES * 4, 256, 0, stream>>>(
      efm, 1024, WeT, 1024, 1024, 4, b_edge, nullptr, 0,
      EMb, Mv, ci_e, 0, 0, 0, 0, 0, nullptr, nullptr, nullptr, nullptr);
  // 5. node-side layer-0 partials, ONE fused dispatch (a/b halves):
  k_gemm<4><<<2 * (MNODE / 128) * 24, 256, 0, stream>>>(
      nf, 512, W0T, 1536, 512, 24, nullptr, nfa, 3072,
      nullptr, nullptr, nullptr, (MNODE / 128) * 24,
      0, 512, (long long)MNODE * 3072, 0, nullptr, nullptr, nullptr, nullptr);

  // 6. L0' (compact): h0 = relu(ci_e @ W0[1024:1536,:]^T + b0 + npair)
  k_gemm<5><<<MTILES * 24, 256, 0, stream>>>(
      ci_e, 512, W0T + 1024, 1536, 512, 24, b0cat, h0big, 3072,
      nullptr, Mv, nullptr, 0, 0, 0, 0, 0, nodes, nfa, nfb, nullptr);

  // 7. L1 (compact, fused over heads): h1[h] = relu(h0[:,h*1024:] @ W1[h]^T + b1[h])
  k_gemm<2><<<3 * MTILES * 4, 256, 0, stream>>>(
      h0big, 3072, W1T, 1024, 1024, 4, b1cat, h1, 512,
      nullptr, Mv, nullptr, MTILES * 4,
      1024, (long long)512 * 1024, (long long)MROWS * DD, 512,
      nullptr, nullptr, nullptr, nullptr);

  // 8. L2 (compact): padded GEMM, scatter valid rows into pre-filled d_out
  k_gemm<3><<<3 * MTILES, 256, 0, stream>>>(
      h1, 512, W2T, 512, 512, 1, b2pad, (unsigned short*)d_out, 0,
      nullptr, Mv, nullptr, 0, 0, 0, 0, 0, nullptr, nullptr, nullptr, rmap);
}

// Round 10
// 275.482 us; speedup vs baseline: 1.5216x; 1.0673x over previous
//
#include <hip/hip_runtime.h>
#include <stdint.h>

// Problem constants
#define BB 256
#define NNODE 12
#define PP 66
#define DNF 1024
#define DEF 1024
#define DD 512
#define MROWS (BB*PP)        // 16896
#define MNODE (BB*NNODE)     // 3072
#define MTILES (MROWS/128)   // 132

typedef __attribute__((ext_vector_type(8))) short s16x8;
typedef __attribute__((ext_vector_type(4))) float f32x4;
typedef __attribute__((ext_vector_type(8))) unsigned short u16x8;

__device__ __forceinline__ unsigned short f2bf(float f) {
  union { float f; unsigned u; } v; v.f = f;
  return (unsigned short)((v.u + 0x7FFFu + ((v.u >> 16) & 1u)) >> 16);
}
__device__ __forceinline__ float bf2f(unsigned short h) {
  union { unsigned u; float f; } v; v.u = ((unsigned)h) << 16;
  return v.f;
}

__device__ __forceinline__ void gll16(const void* g, void* l) {
  __builtin_amdgcn_global_load_lds(
      (const __attribute__((address_space(1))) void*)g,
      (__attribute__((address_space(3))) void*)l, 16, 0, 0);
}

// ------------- k_const: scan + invalid-row constants (1 launch, 4 blocks) ----
// blocks 0-2: head h -> h1c (512-wide parallel) then outc via shfl+LDS-atomic.
// block 3: exclusive prefix scan of num_rels + compact-nodes pad zero-init.
__global__ __launch_bounds__(512) void k_const(
    const int* __restrict__ nrels, int* __restrict__ offs,
    int* __restrict__ Mv, int2* __restrict__ nodes,
    const float* __restrict__ b0a, const float* __restrict__ b0b,
    const float* __restrict__ b0c,
    const float* __restrict__ W1a, const float* __restrict__ W1b,
    const float* __restrict__ W1c,
    const float* __restrict__ b1a, const float* __restrict__ b1b,
    const float* __restrict__ b1c,
    const float* __restrict__ w2a, const float* __restrict__ w2b,
    const float* __restrict__ w2c,
    const float* __restrict__ b2a, const float* __restrict__ b2b,
    const float* __restrict__ b2c, float* __restrict__ outc) {
  const int bid = blockIdx.x, t = threadIdx.x;
  if (bid == 3) {
    __shared__ int s[256];
    int val = 0;
    if (t < 256) { val = nrels[t]; s[t] = val; }
    __syncthreads();
    for (int d = 1; d < 256; d <<= 1) {
      int x = (t >= d && t < 256) ? s[t - d] : 0;
      __syncthreads();
      if (t < 256) s[t] += x;
      __syncthreads();
    }
    if (t < 256) offs[t] = s[t] - val;
    __syncthreads();
    const int total = s[255];
    if (t == 0) *Mv = total;
    if (t < 128) {
      int cr = total + t;
      if (cr < MROWS) nodes[cr] = make_int2(0, 0);
    }
    return;
  }
  const int h = bid;
  const float* b0 = h == 0 ? b0a : (h == 1 ? b0b : b0c);
  const float* W1 = h == 0 ? W1a : (h == 1 ? W1b : W1c);
  const float* b1 = h == 0 ? b1a : (h == 1 ? b1b : b1c);
  const float* W2 = h == 0 ? w2a : (h == 1 ? w2b : w2c);
  const float* b2 = h == 0 ? b2a : (h == 1 ? b2b : b2c);
  const int C = h == 0 ? 9 : (h == 1 ? 3 : 5);
  const int obase = h == 0 ? 0 : (h == 1 ? 9 : 12);
  __shared__ float red[9];
  if (t < 9) red[t] = 0.f;
  float acc = b1[t];
#pragma unroll 4
  for (int k = 0; k < 1024; ++k)
    acc += fmaxf(b0[k], 0.f) * W1[(size_t)k * 512 + t];
  const float hv = fmaxf(acc, 0.f);   // h1c[k=t]
  __syncthreads();                    // red[] initialized
  float p[9] = {0.f, 0.f, 0.f, 0.f, 0.f, 0.f, 0.f, 0.f, 0.f};
#pragma unroll
  for (int c = 0; c < 9; ++c)
    if (c < C) p[c] = hv * W2[(size_t)t * C + c];
#pragma unroll
  for (int c = 0; c < 9; ++c)
#pragma unroll
    for (int off = 32; off; off >>= 1) p[c] += __shfl_xor(p[c], off);
  if ((t & 63) == 0)
    for (int c = 0; c < C; ++c) atomicAdd(&red[c], p[c]);
  __syncthreads();
  if (t < C) outc[obase + t] = red[t] + b2[t];
}

// fill d_out with constant rows (valid rows overwritten later by L2 scatter)
__global__ __launch_bounds__(256) void k_fillout(const float* __restrict__ outc,
                                                 float* __restrict__ out) {
  const int e = blockIdx.x * 256 + threadIdx.x;
  if (e >= MROWS * 17) return;
  int c;
  if (e < MROWS * 9) c = e % 9;
  else if (e < MROWS * 12) c = 9 + (e - MROWS * 9) % 3;
  else c = 12 + (e - MROWS * 12) % 5;
  out[e] = outc[c];
}

// ---------------- fused prep kernel ----------------
// [0,3072) conv node->bf16 ; [3072,4864) 64x64 transposes ;
// [4864,5632) W2 pad ; [5632,5644) b0cat ; [5644,5650) b1cat ; [5650,5654) b_ne
__global__ __launch_bounds__(256) void k_prep(
    const float* __restrict__ node, unsigned short* __restrict__ node_bf,
    const float* __restrict__ W_node, unsigned short* __restrict__ WnT,
    const float* __restrict__ W_edge, unsigned short* __restrict__ WeT,
    const float* __restrict__ W0a, const float* __restrict__ W0b,
    const float* __restrict__ W0c, unsigned short* __restrict__ W0T,
    const float* __restrict__ W1a, const float* __restrict__ W1b,
    const float* __restrict__ W1c, unsigned short* __restrict__ W1T,
    const float* __restrict__ w2a, const float* __restrict__ w2b,
    const float* __restrict__ w2c,
    const float* __restrict__ b2a, const float* __restrict__ b2b,
    const float* __restrict__ b2c,
    unsigned short* __restrict__ W2T, float* __restrict__ b2pad,
    const float* __restrict__ b0a, const float* __restrict__ b0b,
    const float* __restrict__ b0c, float* __restrict__ b0cat,
    const float* __restrict__ b1a, const float* __restrict__ b1b,
    const float* __restrict__ b1c, float* __restrict__ b1cat,
    const float* __restrict__ b_node, const float* __restrict__ b_edge,
    float* __restrict__ b_ne) {
  __shared__ float tile[64][65];
  const int bid = blockIdx.x, t = threadIdx.x;
  if (bid < 3072) {
    int i = bid * 256 + t;
    float4 v = ((const float4*)node)[i];
    ushort4 o;
    o.x = f2bf(v.x); o.y = f2bf(v.y); o.z = f2bf(v.z); o.w = f2bf(v.w);
    ((ushort4*)node_bf)[i] = o;
  } else if (bid < 4864) {
    int tau = bid - 3072;
    const float* src; unsigned short* dst; int K, N;
    if (tau < 128)       { src = W_node; dst = WnT; K = 1024; N = 512; }
    else if (tau < 256)  { src = W_edge; dst = WeT; K = 1024; N = 512; tau -= 128; }
    else if (tau < 1408) {
      int hh = (tau - 256) / 384; tau = (tau - 256) % 384;
      src = hh == 0 ? W0a : (hh == 1 ? W0b : W0c);
      dst = W0T + (size_t)hh * 1024 * 1536; K = 1536; N = 1024;
    } else {
      int hh = (tau - 1408) / 128; tau = (tau - 1408) % 128;
      src = hh == 0 ? W1a : (hh == 1 ? W1b : W1c);
      dst = W1T + (size_t)hh * 512 * 1024; K = 1024; N = 512;
    }
    const int ntn = N >> 6;
    const int kb = (tau / ntn) * 64, nb = (tau % ntn) * 64;
    const int tx = t & 15, ty = t >> 4;
#pragma unroll
    for (int i = 0; i < 4; i++) {
      float4 v = *(const float4*)&src[(size_t)(kb + ty + 16 * i) * N + nb + tx * 4];
      tile[ty + 16 * i][tx * 4 + 0] = v.x;
      tile[ty + 16 * i][tx * 4 + 1] = v.y;
      tile[ty + 16 * i][tx * 4 + 2] = v.z;
      tile[ty + 16 * i][tx * 4 + 3] = v.w;
    }
    __syncthreads();
    const int wx = t & 7, wy = t >> 3;
#pragma unroll
    for (int i = 0; i < 2; i++) {
      const int n = wy + 32 * i;
      u16x8 o;
#pragma unroll
      for (int j = 0; j < 8; j++) o[j] = f2bf(tile[wx * 8 + j][n]);
      *(u16x8*)&dst[(size_t)(nb + n) * K + kb + wx * 8] = o;
    }
  } else if (bid < 5632) {
    int e = bid - 4864;
    int h = e >> 8, blk = e & 255;
    const int C = (h == 0) ? 9 : ((h == 1) ? 3 : 5);
    const float* W2 = (h == 0) ? w2a : ((h == 1) ? w2b : w2c);
    const float* b2 = (h == 0) ? b2a : ((h == 1) ? b2b : b2c);
    int idx = blk * 256 + t;
    int n = idx >> 9, k = idx & 511;
    W2T[(size_t)h * 65536 + idx] = (n < C) ? f2bf(W2[(size_t)k * C + n]) : (unsigned short)0;
    if (blk == 0 && t < 128)
      b2pad[h * 128 + t] = (t < C) ? b2[t] : 0.f;
  } else if (bid < 5644) {
    int j = bid - 5632;
    const float* b0 = (j < 4) ? b0a : (j < 8 ? b0b : b0c);
    b0cat[j * 256 + t] = b0[(j & 3) * 256 + t];
  } else if (bid < 5650) {
    int j = bid - 5644;
    const float* b1 = (j < 2) ? b1a : (j < 4 ? b1b : b1c);
    b1cat[j * 256 + t] = b1[(j & 1) * 256 + t];
  } else {
    int idx = (bid - 5650) * 256 + t;     // 0..1023
    b_ne[idx] = (idx < 512) ? b_node[idx] : b_edge[idx - 512];
  }
}

// ------- gather (COMPACT): edge features/embeddings + node-pair + row map ------
__global__ __launch_bounds__(256) void k_gather_ef(const float* __restrict__ EF,
                                                   const float* __restrict__ EE,
                                                   const int* __restrict__ pairs,
                                                   const int* __restrict__ nrels,
                                                   const int* __restrict__ offs,
                                                   unsigned short* __restrict__ efm,
                                                   unsigned short* __restrict__ emb,
                                                   int2* __restrict__ nodes,
                                                   int* __restrict__ rmap) {
  int r = blockIdx.x;
  int b = r / PP, p = r - b * PP;
  if (p >= nrels[b]) return;          // invalid row: no compact slot
  const int cr = offs[b] + p;         // compact row
  int i0 = pairs[r * 2 + 0], i1 = pairs[r * 2 + 1];
  int t = threadIdx.x;
  if (t == 0) {
    nodes[cr] = make_int2(b * NNODE + i0, b * NNODE + i1);
    rmap[cr] = r;
  }
  const float4* e01 = (const float4*)(EF + ((size_t)((b * NNODE + i0) * NNODE + i1)) * DEF);
  const float4* e10 = (const float4*)(EF + ((size_t)((b * NNODE + i1) * NNODE + i0)) * DEF);
  float4 a = e01[t], c = e10[t];
  ushort4 o;
  o.x = f2bf(0.5f * (a.x + c.x));
  o.y = f2bf(0.5f * (a.y + c.y));
  o.z = f2bf(0.5f * (a.z + c.z));
  o.w = f2bf(0.5f * (a.w + c.w));
  ((ushort4*)(efm + (size_t)cr * DEF))[t] = o;
  const float2* g01 = (const float2*)(EE + ((size_t)((b * NNODE + i0) * NNODE + i1)) * DD);
  const float2* g10 = (const float2*)(EE + ((size_t)((b * NNODE + i1) * NNODE + i0)) * DD);
  float2 x = g01[t], y = g10[t];
  ushort2 eo;
  eo.x = f2bf(0.25f * (x.x + y.x));
  eo.y = f2bf(0.25f * (x.y + y.y));
  ((ushort2*)(emb + (size_t)cr * DD))[t] = eo;
}

// ---------------- 128-tile MFMA GEMM (m97-family: 32 KB LDS, multi-block/CU) --
// EPI: 0 = +bias -> bf16 ; 2 = relu(+bias) -> bf16 ;
//      3 = layer-2 heads fp32, scatter via rmap ; 4 = raw bf16 (no bias) ;
//      5 = L0': relu(bias + acc + npair), npair LDS-staged coalesced ;
//      6 = merged nf|e: head0 +bias->bf16(nf), head1 e-assembly into ci_e.
// Mvp != nullptr -> per-block early exit (compact M); EPI6 head0 uses MNODE.
template <int EPI>
__global__ __launch_bounds__(256) void k_gemm(
    const unsigned short* __restrict__ A, int ldA,
    const unsigned short* __restrict__ BT, int ldB, int K,
    int Ntiles,
    const float* __restrict__ bias,
    unsigned short* __restrict__ outb, int ldo,
    const unsigned short* __restrict__ em,
    const int* __restrict__ Mvp,
    unsigned short* __restrict__ ci,
    int blocksPerHead, long long aHeadOff, long long bHeadOff,
    long long oHeadOff, int biasHeadOff,
    const int2* __restrict__ nodes,
    const unsigned short* __restrict__ nfa,
    const unsigned short* __restrict__ nfb,
    const int* __restrict__ rmap) {
  __shared__ __align__(16) unsigned short sm[16896];
  char* smc = (char*)sm;
  const int t = threadIdx.x;
  const int l = t & 63, w = t >> 6;
  const int wm = w >> 1, wn = w & 1;
  int bid = blockIdx.x;

  int head = 0;
  unsigned short* outp = outb;
  if constexpr (EPI == 3) {
    head = bid / MTILES;
    bid -= head * MTILES;
    A += (size_t)head * MROWS * DD;
    BT += (size_t)head * 128 * DD;
    bias += head * 128;
  } else {
    if (blocksPerHead > 0) {
      head = bid / blocksPerHead;
      bid -= head * blocksPerHead;
      A += (long long)head * aHeadOff;
      BT += (long long)head * bHeadOff;
      bias += head * biasHeadOff;
      outp = outb + (long long)head * oHeadOff;
    }
  }
  const int tn = bid % Ntiles, tm = bid / Ntiles;

  int Mv = MROWS;
  if (Mvp) Mv = *Mvp;
  if constexpr (EPI == 6) { if (head == 0) Mv = MNODE; }
  if (Mvp) {
    if (tm * 128 >= Mv) return;   // compact early-exit (uniform branch)
  }

  const int lrow = l >> 3;
  const int scol = (l & 7) ^ lrow;       // pre-swizzled source chunk
  const unsigned short* Ap = A + (size_t)(tm * 128 + w * 8 + lrow) * ldA + scol * 8;
  const unsigned short* Bp = BT + (size_t)(tn * 128 + w * 8 + lrow) * ldB + scol * 8;

  f32x4 acc[4][4] = {};
  const int hi = l >> 4, l15 = l & 15, l7 = l & 7;
  const int nk = K >> 6;

  for (int kt = 0; kt < nk; ++kt) {
#pragma unroll
    for (int c = 0; c < 4; ++c) {
      gll16(Ap + (size_t)c * 32 * ldA, smc + c * 4096 + w * 1024);
      gll16(Bp + (size_t)c * 32 * ldB, smc + 16384 + c * 4096 + w * 1024);
    }
    __syncthreads();
#pragma unroll
    for (int kk = 0; kk < 2; ++kk) {
      const int cb = (((kk << 2) + hi) ^ l7) << 4;
      s16x8 af[4], bfr[4];
#pragma unroll
      for (int m = 0; m < 4; m++)
        af[m] = *(const s16x8*)(smc + (wm * 64 + m * 16 + l15) * 128 + cb);
#pragma unroll
      for (int n = 0; n < 4; n++)
        bfr[n] = *(const s16x8*)(smc + 16384 + (wn * 64 + n * 16 + l15) * 128 + cb);
#pragma unroll
      for (int m = 0; m < 4; m++)
#pragma unroll
        for (int n = 0; n < 4; n++)
          asm volatile("v_mfma_f32_16x16x32_bf16 %0, %1, %2, %0"
                       : "+v"(acc[m][n])
                       : "v"(af[m]), "v"(bfr[n]));
    }
    __syncthreads();
    Ap += 64;
    Bp += 64;
  }
  asm volatile("s_nop 7\n\ts_nop 7\n\ts_nop 7" :::);  // MFMA->VALU hazard guard

  if constexpr (EPI == 5) {
    // Stage npair = nfa[i0]+nfb[i1] for the 128x128 tile, coalesced 16B/lane.
    const int se_r = t >> 4;
    const int se_c = (t & 15) * 8;
#pragma unroll
    for (int it = 0; it < 8; ++it) {
      const int rr = se_r + (it << 4);
      const int2 nn = nodes[tm * 128 + rr];   // pad rows zero-initialized
      union { unsigned short s[8]; unsigned long long q[2]; } ov;
      u16x8 va = *(const u16x8*)&nfa[(size_t)nn.x * 3072 + tn * 128 + se_c];
      u16x8 vb = *(const u16x8*)&nfb[(size_t)nn.y * 3072 + tn * 128 + se_c];
#pragma unroll
      for (int j = 0; j < 8; ++j)
        ov.s[j] = f2bf(bf2f(va[j]) + bf2f(vb[j]));
      *(unsigned long long*)(smc + rr * 264 + se_c * 2) = ov.q[0];
      *(unsigned long long*)(smc + rr * 264 + se_c * 2 + 8) = ov.q[1];
    }
    __syncthreads();
  }

  // C/D layout: col = lane&15, row = (lane>>4)*4 + reg
  const int gr_base = tm * 128 + wm * 64 + (hi << 2);
  const int gc_base = tn * 128 + wn * 64 + l15;
  const int lr_base = wm * 64 + (hi << 2);
  const int lc_base = wn * 64 + l15;

  int Cc = 0; size_t obase = 0;
  if constexpr (EPI == 3) {
    Cc = (head == 0) ? 9 : ((head == 1) ? 3 : 5);
    obase = (head == 0) ? 0 : ((head == 1) ? (size_t)MROWS * 9 : (size_t)MROWS * 12);
  }

#pragma unroll
  for (int n = 0; n < 4; n++) {
    const int gc = gc_base + n * 16;
    const float bv = (EPI == 4) ? 0.f : bias[gc];
#pragma unroll
    for (int m = 0; m < 4; m++) {
#pragma unroll
      for (int i = 0; i < 4; i++) {
        const int gr = gr_base + m * 16 + i;
        float v = acc[m][n][i] + bv;
        if constexpr (EPI == 0 || EPI == 4) {
          outp[(size_t)gr * ldo + gc] = f2bf(v);
        } else if constexpr (EPI == 2) {
          outp[(size_t)gr * ldo + gc] = f2bf(v > 0.f ? v : 0.f);
        } else if constexpr (EPI == 5) {
          const int lr = lr_base + m * 16 + i;
          const int lc = lc_base + n * 16;
          v += bf2f(*(const unsigned short*)(smc + lr * 264 + lc * 2));
          outp[(size_t)gr * ldo + gc] = f2bf(v > 0.f ? v : 0.f);
        } else if constexpr (EPI == 6) {
          if (head == 0) {
            outp[(size_t)gr * ldo + gc] = f2bf(v);
          } else {
            float e = bf2f(em[(size_t)gr * DD + gc]) + 0.5f * v;
            ci[(size_t)gr * DD + gc] = f2bf(e);
          }
        } else {
          if (gc < Cc && gr < Mv)
            ((float*)outb)[obase + (size_t)rmap[gr] * Cc + gc] = v;
        }
      }
    }
  }
}

// ---------------- launcher ----------------
extern "C" void kernel_launch(void* const* d_in, const int* in_sizes, int n_in,
                              void* d_out, int out_size, void* d_ws, size_t ws_size,
                              hipStream_t stream) {
  const float* node   = (const float*)d_in[0];
  const float* EF     = (const float*)d_in[1];
  const float* EE     = (const float*)d_in[2];
  const int*   pairs  = (const int*)d_in[3];
  const int*   nrels  = (const int*)d_in[4];
  const float* W_node = (const float*)d_in[5];
  const float* b_node = (const float*)d_in[6];
  const float* W_edge = (const float*)d_in[7];
  const float* b_edge = (const float*)d_in[8];
  const float* hW0[3] = {(const float*)d_in[9],  (const float*)d_in[15], (const float*)d_in[21]};
  const float* hb0[3] = {(const float*)d_in[10], (const float*)d_in[16], (const float*)d_in[22]};
  const float* hW1[3] = {(const float*)d_in[11], (const float*)d_in[17], (const float*)d_in[23]};
  const float* hb1[3] = {(const float*)d_in[12], (const float*)d_in[18], (const float*)d_in[24]};
  const float* hW2[3] = {(const float*)d_in[13], (const float*)d_in[19], (const float*)d_in[25]};
  const float* hb2[3] = {(const float*)d_in[14], (const float*)d_in[20], (const float*)d_in[26]};

  char* ws = (char*)d_ws;
  size_t off = 0;
  auto alloc = [&](size_t bytes) {
    char* p = ws + off;
    off += (bytes + 255) & ~(size_t)255;
    return p;
  };
  // --- persistent front ---
  unsigned short* WnT   = (unsigned short*)alloc((size_t)512 * 1024 * 2);
  unsigned short* WeT   = (unsigned short*)alloc((size_t)512 * 1024 * 2);
  unsigned short* W0T   = (unsigned short*)alloc((size_t)3072 * 1536 * 2);
  unsigned short* W1T   = (unsigned short*)alloc((size_t)3 * 512 * 1024 * 2);
  unsigned short* W2T   = (unsigned short*)alloc((size_t)3 * 128 * 512 * 2);
  float*          b2pad = (float*)alloc((size_t)3 * 128 * 4);
  float*          b0cat = (float*)alloc((size_t)3072 * 4);
  float*          b1cat = (float*)alloc((size_t)1536 * 4);
  float*          b_ne  = (float*)alloc((size_t)1024 * 4);
  int2*           nodes = (int2*)alloc((size_t)MROWS * 8);
  int*            offs  = (int*)alloc((size_t)256 * 4);
  int*            Mv    = (int*)alloc(256);
  int*            rmap  = (int*)alloc((size_t)MROWS * 4);
  float*          outc  = (float*)alloc((size_t)32 * 4);
  // --- zone A: efm+EMb (dead after e-GEMM) -> reused as nfa/nfb, then h1 ---
  size_t zoneA = off;
  unsigned short* efm = (unsigned short*)alloc((size_t)MROWS * DEF * 2);  // 34.6M
  unsigned short* EMb = (unsigned short*)alloc((size_t)MROWS * DD * 2);   // 17.3M
  // --- zone B: ci_e (dead after L0') ---
  unsigned short* ci_e = (unsigned short*)alloc((size_t)MROWS * DD * 2);  // 17.3M
  // --- zone C: node_bf+nf (dead before L0') -> overlaid by h0big ---
  size_t zoneC = off;
  unsigned short* node_bf = (unsigned short*)alloc((size_t)MNODE * DNF * 2);
  unsigned short* nf      = (unsigned short*)alloc((size_t)MNODE * DD * 2);
  // overlays
  unsigned short* nfa   = (unsigned short*)(ws + zoneA);                 // 18.9M
  unsigned short* nfb   = nfa + (size_t)MNODE * 3072;                    // 18.9M
  unsigned short* h1    = (unsigned short*)(ws + zoneA);                 // 51.9M (after L0')
  unsigned short* h0big = (unsigned short*)(ws + zoneC);                 // 104M

  // 0. scan + invalid-row constants (1 launch)
  k_const<<<4, 512, 0, stream>>>(nrels, offs, Mv, nodes,
      hb0[0], hb0[1], hb0[2], hW1[0], hW1[1], hW1[2], hb1[0], hb1[1], hb1[2],
      hW2[0], hW2[1], hW2[2], hb2[0], hb2[1], hb2[2], outc);
  // 1. prep: conv + 64x64 transposes + W2 pad + bias concats (1 launch)
  k_prep<<<5654, 256, 0, stream>>>(node, node_bf, W_node, WnT, W_edge, WeT,
      hW0[0], hW0[1], hW0[2], W0T, hW1[0], hW1[1], hW1[2], W1T,
      hW2[0], hW2[1], hW2[2], hb2[0], hb2[1], hb2[2], W2T, b2pad,
      hb0[0], hb0[1], hb0[2], b0cat, hb1[0], hb1[1], hb1[2], b1cat,
      b_node, b_edge, b_ne);
  // 2. constant-row fill of d_out
  k_fillout<<<(MROWS * 17 + 255) / 256, 256, 0, stream>>>(outc, (float*)d_out);
  // 3. compact edge gathers + node-pair table + row map
  k_gather_ef<<<MROWS, 256, 0, stream>>>(EF, EE, pairs, nrels, offs,
                                         efm, EMb, nodes, rmap);

  // 4. merged nf|e GEMM (EPI 6): head0 nf = node_bf@WnT^T+b_node (M=3072);
  //    head1 ci_e = 0.25(ee+ee') + 0.5(efm@WeT^T + b_edge)  (M=Mv compact)
  k_gemm<6><<<2 * MTILES * 4, 256, 0, stream>>>(
      node_bf, 1024, WnT, 1024, 1024, 4, b_ne, nf, 512,
      EMb, Mv, ci_e, MTILES * 4,
      (long long)(efm - node_bf), (long long)512 * 1024,
      (long long)(ci_e - nf), 512,
      nullptr, nullptr, nullptr, nullptr);

  // 5. node-side layer-0 partials, ONE fused dispatch (a/b halves):
  //    nfa = nf@W0[0:512,:]^T ; nfb = nf@W0[512:1024,:]^T  (each M=3072,N=3072,K=512)
  k_gemm<4><<<2 * (MNODE / 128) * 24, 256, 0, stream>>>(
      nf, 512, W0T, 1536, 512, 24, nullptr, nfa, 3072,
      nullptr, nullptr, nullptr, (MNODE / 128) * 24,
      0, 512, (long long)MNODE * 3072, 0, nullptr, nullptr, nullptr, nullptr);

  // 6. L0' (compact): h0 = relu(ci_e @ W0[1024:1536,:]^T + b0 + npair)
  k_gemm<5><<<MTILES * 24, 256, 0, stream>>>(
      ci_e, 512, W0T + 1024, 1536, 512, 24, b0cat, h0big, 3072,
      nullptr, Mv, nullptr, 0, 0, 0, 0, 0, nodes, nfa, nfb, nullptr);

  // 7. L1 (compact, fused over heads): h1[h] = relu(h0[:,h*1024:] @ W1[h]^T + b1[h])
  k_gemm<2><<<3 * MTILES * 4, 256, 0, stream>>>(
      h0big, 3072, W1T, 1024, 1024, 4, b1cat, h1, 512,
      nullptr, Mv, nullptr, MTILES * 4,
      1024, (long long)512 * 1024, (long long)MROWS * DD, 512,
      nullptr, nullptr, nullptr, nullptr);

  // 8. L2 (compact): padded GEMM, scatter valid rows into pre-filled d_out
  k_gemm<3><<<3 * MTILES, 256, 0, stream>>>(
      h1, 512, W2T, 512, 512, 1, b2pad, (unsigned short*)d_out, 0,
      nullptr, Mv, nullptr, 0, 0, 0, 0, 0, nullptr, nullptr, nullptr, rmap);
}

// Round 11
// 212.971 us; speedup vs baseline: 1.9683x; 1.2935x over previous
//
#include <hip/hip_runtime.h>
#include <stdint.h>

// Problem constants
#define BB 256
#define NNODE 12
#define PP 66
#define DNF 1024
#define DEF 1024
#define DD 512
#define MROWS (BB*PP)        // 16896
#define MNODE (BB*NNODE)     // 3072
#define MTILES (MROWS/128)   // 132

typedef __attribute__((ext_vector_type(8))) short s16x8;
typedef __attribute__((ext_vector_type(4))) float f32x4;
typedef __attribute__((ext_vector_type(8))) unsigned short u16x8;

__device__ __forceinline__ unsigned short f2bf(float f) {
  union { float f; unsigned u; } v; v.f = f;
  return (unsigned short)((v.u + 0x7FFFu + ((v.u >> 16) & 1u)) >> 16);
}
__device__ __forceinline__ float bf2f(unsigned short h) {
  union { unsigned u; float f; } v; v.u = ((unsigned)h) << 16;
  return v.f;
}

__device__ __forceinline__ void gll16(const void* g, void* l) {
  __builtin_amdgcn_global_load_lds(
      (const __attribute__((address_space(1))) void*)g,
      (__attribute__((address_space(3))) void*)l, 16, 0, 0);
}

// ------- k_scan_h1c: prefix scan + PARALLEL h1c partials (25 blocks x 256) ----
// blocks 0..23: (head h = bid/8, k-chunk c = bid%8 of 128 rows). Each thread
// accumulates 2 columns (t, t+256) over its 128-k chunk with coalesced loads
// (unroll 8 -> ~16 latency rounds, vs r10's 256 -> this was the 130us stall).
// block 24: exclusive prefix scan of num_rels + compact-nodes pad zero-init.
__global__ __launch_bounds__(256) void k_scan_h1c(
    const int* __restrict__ nrels, int* __restrict__ offs,
    int* __restrict__ Mv, int2* __restrict__ nodes,
    const float* __restrict__ b0a, const float* __restrict__ b0b,
    const float* __restrict__ b0c,
    const float* __restrict__ W1a, const float* __restrict__ W1b,
    const float* __restrict__ W1c,
    float* __restrict__ h1part) {
  const int bid = blockIdx.x, t = threadIdx.x;
  if (bid == 24) {
    __shared__ int s[256];
    const int val = nrels[t];
    s[t] = val;
    __syncthreads();
    for (int d = 1; d < 256; d <<= 1) {
      int x = (t >= d) ? s[t - d] : 0;
      __syncthreads();
      s[t] += x;
      __syncthreads();
    }
    offs[t] = s[t] - val;
    __syncthreads();
    const int total = s[255];
    if (t == 0) *Mv = total;
    if (t < 128) {
      int cr = total + t;
      if (cr < MROWS) nodes[cr] = make_int2(0, 0);
    }
    return;
  }
  const int h = bid >> 3, c = bid & 7;
  const float* b0 = h == 0 ? b0a : (h == 1 ? b0b : b0c);
  const float* W1 = h == 0 ? W1a : (h == 1 ? W1b : W1c);
  const int k0 = c * 128;
  float acc0 = 0.f, acc1 = 0.f;
#pragma unroll 8
  for (int kk = 0; kk < 128; ++kk) {
    const int k = k0 + kk;
    const float bv = fmaxf(b0[k], 0.f);
    acc0 += bv * W1[(size_t)k * 512 + t];
    acc1 += bv * W1[(size_t)k * 512 + t + 256];
  }
  h1part[(size_t)bid * 512 + t] = acc0;
  h1part[(size_t)bid * 512 + t + 256] = acc1;
}

// ------- k_finish: h1c = relu(b1 + sum partials) ; outc = b2 + h1c@W2 --------
__global__ __launch_bounds__(512) void k_finish(
    const float* __restrict__ h1part,
    const float* __restrict__ b1a, const float* __restrict__ b1b,
    const float* __restrict__ b1c,
    const float* __restrict__ w2a, const float* __restrict__ w2b,
    const float* __restrict__ w2c,
    const float* __restrict__ b2a, const float* __restrict__ b2b,
    const float* __restrict__ b2c, float* __restrict__ outc) {
  const int t = threadIdx.x;
  __shared__ float red[9];
  for (int h = 0; h < 3; ++h) {
    const float* b1 = h == 0 ? b1a : (h == 1 ? b1b : b1c);
    const float* W2 = h == 0 ? w2a : (h == 1 ? w2b : w2c);
    const float* b2 = h == 0 ? b2a : (h == 1 ? b2b : b2c);
    const int C = h == 0 ? 9 : (h == 1 ? 3 : 5);
    const int obase = h == 0 ? 0 : (h == 1 ? 9 : 12);
    if (t < 9) red[t] = 0.f;
    float s = b1[t];
#pragma unroll
    for (int cc = 0; cc < 8; ++cc)
      s += h1part[(size_t)(h * 8 + cc) * 512 + t];
    const float hv = fmaxf(s, 0.f);
    __syncthreads();                     // red[] initialized
    float p[9] = {0.f, 0.f, 0.f, 0.f, 0.f, 0.f, 0.f, 0.f, 0.f};
#pragma unroll
    for (int c = 0; c < 9; ++c)
      if (c < C) p[c] = hv * W2[(size_t)t * C + c];
#pragma unroll
    for (int c = 0; c < 9; ++c)
#pragma unroll
      for (int off = 32; off; off >>= 1) p[c] += __shfl_xor(p[c], off);
    if ((t & 63) == 0)
      for (int c = 0; c < C; ++c) atomicAdd(&red[c], p[c]);
    __syncthreads();
    if (t < C) outc[obase + t] = red[t] + b2[t];
    __syncthreads();                     // writes done before next-head reset
  }
}

// fill d_out with constant rows (valid rows overwritten later by L2 scatter)
__global__ __launch_bounds__(256) void k_fillout(const float* __restrict__ outc,
                                                 float* __restrict__ out) {
  const int e = blockIdx.x * 256 + threadIdx.x;
  if (e >= MROWS * 17) return;
  int c;
  if (e < MROWS * 9) c = e % 9;
  else if (e < MROWS * 12) c = 9 + (e - MROWS * 9) % 3;
  else c = 12 + (e - MROWS * 12) % 5;
  out[e] = outc[c];
}

// ---------------- fused prep kernel ----------------
// [0,3072) conv node->bf16 ; [3072,4864) 64x64 transposes ;
// [4864,5632) W2 pad ; [5632,5644) b0cat ; [5644,5650) b1cat ; [5650,5654) b_ne
__global__ __launch_bounds__(256) void k_prep(
    const float* __restrict__ node, unsigned short* __restrict__ node_bf,
    const float* __restrict__ W_node, unsigned short* __restrict__ WnT,
    const float* __restrict__ W_edge, unsigned short* __restrict__ WeT,
    const float* __restrict__ W0a, const float* __restrict__ W0b,
    const float* __restrict__ W0c, unsigned short* __restrict__ W0T,
    const float* __restrict__ W1a, const float* __restrict__ W1b,
    const float* __restrict__ W1c, unsigned short* __restrict__ W1T,
    const float* __restrict__ w2a, const float* __restrict__ w2b,
    const float* __restrict__ w2c,
    const float* __restrict__ b2a, const float* __restrict__ b2b,
    const float* __restrict__ b2c,
    unsigned short* __restrict__ W2T, float* __restrict__ b2pad,
    const float* __restrict__ b0a, const float* __restrict__ b0b,
    const float* __restrict__ b0c, float* __restrict__ b0cat,
    const float* __restrict__ b1a, const float* __restrict__ b1b,
    const float* __restrict__ b1c, float* __restrict__ b1cat,
    const float* __restrict__ b_node, const float* __restrict__ b_edge,
    float* __restrict__ b_ne) {
  __shared__ float tile[64][65];
  const int bid = blockIdx.x, t = threadIdx.x;
  if (bid < 3072) {
    int i = bid * 256 + t;
    float4 v = ((const float4*)node)[i];
    ushort4 o;
    o.x = f2bf(v.x); o.y = f2bf(v.y); o.z = f2bf(v.z); o.w = f2bf(v.w);
    ((ushort4*)node_bf)[i] = o;
  } else if (bid < 4864) {
    int tau = bid - 3072;
    const float* src; unsigned short* dst; int K, N;
    if (tau < 128)       { src = W_node; dst = WnT; K = 1024; N = 512; }
    else if (tau < 256)  { src = W_edge; dst = WeT; K = 1024; N = 512; tau -= 128; }
    else if (tau < 1408) {
      int hh = (tau - 256) / 384; tau = (tau - 256) % 384;
      src = hh == 0 ? W0a : (hh == 1 ? W0b : W0c);
      dst = W0T + (size_t)hh * 1024 * 1536; K = 1536; N = 1024;
    } else {
      int hh = (tau - 1408) / 128; tau = (tau - 1408) % 128;
      src = hh == 0 ? W1a : (hh == 1 ? W1b : W1c);
      dst = W1T + (size_t)hh * 512 * 1024; K = 1024; N = 512;
    }
    const int ntn = N >> 6;
    const int kb = (tau / ntn) * 64, nb = (tau % ntn) * 64;
    const int tx = t & 15, ty = t >> 4;
#pragma unroll
    for (int i = 0; i < 4; i++) {
      float4 v = *(const float4*)&src[(size_t)(kb + ty + 16 * i) * N + nb + tx * 4];
      tile[ty + 16 * i][tx * 4 + 0] = v.x;
      tile[ty + 16 * i][tx * 4 + 1] = v.y;
      tile[ty + 16 * i][tx * 4 + 2] = v.z;
      tile[ty + 16 * i][tx * 4 + 3] = v.w;
    }
    __syncthreads();
    const int wx = t & 7, wy = t >> 3;
#pragma unroll
    for (int i = 0; i < 2; i++) {
      const int n = wy + 32 * i;
      u16x8 o;
#pragma unroll
      for (int j = 0; j < 8; j++) o[j] = f2bf(tile[wx * 8 + j][n]);
      *(u16x8*)&dst[(size_t)(nb + n) * K + kb + wx * 8] = o;
    }
  } else if (bid < 5632) {
    int e = bid - 4864;
    int h = e >> 8, blk = e & 255;
    const int C = (h == 0) ? 9 : ((h == 1) ? 3 : 5);
    const float* W2 = (h == 0) ? w2a : ((h == 1) ? w2b : w2c);
    const float* b2 = (h == 0) ? b2a : ((h == 1) ? b2b : b2c);
    int idx = blk * 256 + t;
    int n = idx >> 9, k = idx & 511;
    W2T[(size_t)h * 65536 + idx] = (n < C) ? f2bf(W2[(size_t)k * C + n]) : (unsigned short)0;
    if (blk == 0 && t < 128)
      b2pad[h * 128 + t] = (t < C) ? b2[t] : 0.f;
  } else if (bid < 5644) {
    int j = bid - 5632;
    const float* b0 = (j < 4) ? b0a : (j < 8 ? b0b : b0c);
    b0cat[j * 256 + t] = b0[(j & 3) * 256 + t];
  } else if (bid < 5650) {
    int j = bid - 5644;
    const float* b1 = (j < 2) ? b1a : (j < 4 ? b1b : b1c);
    b1cat[j * 256 + t] = b1[(j & 1) * 256 + t];
  } else {
    int idx = (bid - 5650) * 256 + t;     // 0..1023
    b_ne[idx] = (idx < 512) ? b_node[idx] : b_edge[idx - 512];
  }
}

// ------- gather (COMPACT): edge features/embeddings + node-pair + row map ------
__global__ __launch_bounds__(256) void k_gather_ef(const float* __restrict__ EF,
                                                   const float* __restrict__ EE,
                                                   const int* __restrict__ pairs,
                                                   const int* __restrict__ nrels,
                                                   const int* __restrict__ offs,
                                                   unsigned short* __restrict__ efm,
                                                   unsigned short* __restrict__ emb,
                                                   int2* __restrict__ nodes,
                                                   int* __restrict__ rmap) {
  int r = blockIdx.x;
  int b = r / PP, p = r - b * PP;
  if (p >= nrels[b]) return;          // invalid row: no compact slot
  const int cr = offs[b] + p;         // compact row
  int i0 = pairs[r * 2 + 0], i1 = pairs[r * 2 + 1];
  int t = threadIdx.x;
  if (t == 0) {
    nodes[cr] = make_int2(b * NNODE + i0, b * NNODE + i1);
    rmap[cr] = r;
  }
  const float4* e01 = (const float4*)(EF + ((size_t)((b * NNODE + i0) * NNODE + i1)) * DEF);
  const float4* e10 = (const float4*)(EF + ((size_t)((b * NNODE + i1) * NNODE + i0)) * DEF);
  float4 a = e01[t], c = e10[t];
  ushort4 o;
  o.x = f2bf(0.5f * (a.x + c.x));
  o.y = f2bf(0.5f * (a.y + c.y));
  o.z = f2bf(0.5f * (a.z + c.z));
  o.w = f2bf(0.5f * (a.w + c.w));
  ((ushort4*)(efm + (size_t)cr * DEF))[t] = o;
  const float2* g01 = (const float2*)(EE + ((size_t)((b * NNODE + i0) * NNODE + i1)) * DD);
  const float2* g10 = (const float2*)(EE + ((size_t)((b * NNODE + i1) * NNODE + i0)) * DD);
  float2 x = g01[t], y = g10[t];
  ushort2 eo;
  eo.x = f2bf(0.25f * (x.x + y.x));
  eo.y = f2bf(0.25f * (x.y + y.y));
  ((ushort2*)(emb + (size_t)cr * DD))[t] = eo;
}

// ---------------- 128-tile MFMA GEMM (m97-family: 32 KB LDS, multi-block/CU) --
// EPI: 0 = +bias -> bf16 ; 2 = relu(+bias) -> bf16 ;
//      3 = layer-2 heads fp32, scatter via rmap ; 4 = raw bf16 (no bias) ;
//      5 = L0': relu(bias + acc + npair), npair LDS-staged coalesced ;
//      6 = merged nf|e: head0 +bias->bf16(nf), head1 e-assembly into ci_e.
// Mvp != nullptr -> per-block early exit (compact M); EPI6 head0 uses MNODE.
template <int EPI>
__global__ __launch_bounds__(256) void k_gemm(
    const unsigned short* __restrict__ A, int ldA,
    const unsigned short* __restrict__ BT, int ldB, int K,
    int Ntiles,
    const float* __restrict__ bias,
    unsigned short* __restrict__ outb, int ldo,
    const unsigned short* __restrict__ em,
    const int* __restrict__ Mvp,
    unsigned short* __restrict__ ci,
    int blocksPerHead, long long aHeadOff, long long bHeadOff,
    long long oHeadOff, int biasHeadOff,
    const int2* __restrict__ nodes,
    const unsigned short* __restrict__ nfa,
    const unsigned short* __restrict__ nfb,
    const int* __restrict__ rmap) {
  __shared__ __align__(16) unsigned short sm[16896];
  char* smc = (char*)sm;
  const int t = threadIdx.x;
  const int l = t & 63, w = t >> 6;
  const int wm = w >> 1, wn = w & 1;
  int bid = blockIdx.x;

  int head = 0;
  unsigned short* outp = outb;
  if constexpr (EPI == 3) {
    head = bid / MTILES;
    bid -= head * MTILES;
    A += (size_t)head * MROWS * DD;
    BT += (size_t)head * 128 * DD;
    bias += head * 128;
  } else {
    if (blocksPerHead > 0) {
      head = bid / blocksPerHead;
      bid -= head * blocksPerHead;
      A += (long long)head * aHeadOff;
      BT += (long long)head * bHeadOff;
      bias += head * biasHeadOff;
      outp = outb + (long long)head * oHeadOff;
    }
  }
  const int tn = bid % Ntiles, tm = bid / Ntiles;

  int Mv = MROWS;
  if (Mvp) Mv = *Mvp;
  if constexpr (EPI == 6) { if (head == 0) Mv = MNODE; }
  if (Mvp) {
    if (tm * 128 >= Mv) return;   // compact early-exit (uniform branch)
  }

  const int lrow = l >> 3;
  const int scol = (l & 7) ^ lrow;       // pre-swizzled source chunk
  const unsigned short* Ap = A + (size_t)(tm * 128 + w * 8 + lrow) * ldA + scol * 8;
  const unsigned short* Bp = BT + (size_t)(tn * 128 + w * 8 + lrow) * ldB + scol * 8;

  f32x4 acc[4][4] = {};
  const int hi = l >> 4, l15 = l & 15, l7 = l & 7;
  const int nk = K >> 6;

  for (int kt = 0; kt < nk; ++kt) {
#pragma unroll
    for (int c = 0; c < 4; ++c) {
      gll16(Ap + (size_t)c * 32 * ldA, smc + c * 4096 + w * 1024);
      gll16(Bp + (size_t)c * 32 * ldB, smc + 16384 + c * 4096 + w * 1024);
    }
    __syncthreads();
#pragma unroll
    for (int kk = 0; kk < 2; ++kk) {
      const int cb = (((kk << 2) + hi) ^ l7) << 4;
      s16x8 af[4], bfr[4];
#pragma unroll
      for (int m = 0; m < 4; m++)
        af[m] = *(const s16x8*)(smc + (wm * 64 + m * 16 + l15) * 128 + cb);
#pragma unroll
      for (int n = 0; n < 4; n++)
        bfr[n] = *(const s16x8*)(smc + 16384 + (wn * 64 + n * 16 + l15) * 128 + cb);
#pragma unroll
      for (int m = 0; m < 4; m++)
#pragma unroll
        for (int n = 0; n < 4; n++)
          asm volatile("v_mfma_f32_16x16x32_bf16 %0, %1, %2, %0"
                       : "+v"(acc[m][n])
                       : "v"(af[m]), "v"(bfr[n]));
    }
    __syncthreads();
    Ap += 64;
    Bp += 64;
  }
  asm volatile("s_nop 7\n\ts_nop 7\n\ts_nop 7" :::);  // MFMA->VALU hazard guard

  if constexpr (EPI == 5) {
    // Stage npair = nfa[i0]+nfb[i1] for the 128x128 tile, coalesced 16B/lane.
    const int se_r = t >> 4;
    const int se_c = (t & 15) * 8;
#pragma unroll
    for (int it = 0; it < 8; ++it) {
      const int rr = se_r + (it << 4);
      const int2 nn = nodes[tm * 128 + rr];   // pad rows zero-initialized
      union { unsigned short s[8]; unsigned long long q[2]; } ov;
      u16x8 va = *(const u16x8*)&nfa[(size_t)nn.x * 3072 + tn * 128 + se_c];
      u16x8 vb = *(const u16x8*)&nfb[(size_t)nn.y * 3072 + tn * 128 + se_c];
#pragma unroll
      for (int j = 0; j < 8; ++j)
        ov.s[j] = f2bf(bf2f(va[j]) + bf2f(vb[j]));
      *(unsigned long long*)(smc + rr * 264 + se_c * 2) = ov.q[0];
      *(unsigned long long*)(smc + rr * 264 + se_c * 2 + 8) = ov.q[1];
    }
    __syncthreads();
  }

  // C/D layout: col = lane&15, row = (lane>>4)*4 + reg
  const int gr_base = tm * 128 + wm * 64 + (hi << 2);
  const int gc_base = tn * 128 + wn * 64 + l15;
  const int lr_base = wm * 64 + (hi << 2);
  const int lc_base = wn * 64 + l15;

  int Cc = 0; size_t obase = 0;
  if constexpr (EPI == 3) {
    Cc = (head == 0) ? 9 : ((head == 1) ? 3 : 5);
    obase = (head == 0) ? 0 : ((head == 1) ? (size_t)MROWS * 9 : (size_t)MROWS * 12);
  }

#pragma unroll
  for (int n = 0; n < 4; n++) {
    const int gc = gc_base + n * 16;
    const float bv = (EPI == 4) ? 0.f : bias[gc];
#pragma unroll
    for (int m = 0; m < 4; m++) {
#pragma unroll
      for (int i = 0; i < 4; i++) {
        const int gr = gr_base + m * 16 + i;
        float v = acc[m][n][i] + bv;
        if constexpr (EPI == 0 || EPI == 4) {
          outp[(size_t)gr * ldo + gc] = f2bf(v);
        } else if constexpr (EPI == 2) {
          outp[(size_t)gr * ldo + gc] = f2bf(v > 0.f ? v : 0.f);
        } else if constexpr (EPI == 5) {
          const int lr = lr_base + m * 16 + i;
          const int lc = lc_base + n * 16;
          v += bf2f(*(const unsigned short*)(smc + lr * 264 + lc * 2));
          outp[(size_t)gr * ldo + gc] = f2bf(v > 0.f ? v : 0.f);
        } else if constexpr (EPI == 6) {
          if (head == 0) {
            outp[(size_t)gr * ldo + gc] = f2bf(v);
          } else {
            float e = bf2f(em[(size_t)gr * DD + gc]) + 0.5f * v;
            ci[(size_t)gr * DD + gc] = f2bf(e);
          }
        } else {
          if (gc < Cc && gr < Mv)
            ((float*)outb)[obase + (size_t)rmap[gr] * Cc + gc] = v;
        }
      }
    }
  }
}

// ---------------- launcher ----------------
extern "C" void kernel_launch(void* const* d_in, const int* in_sizes, int n_in,
                              void* d_out, int out_size, void* d_ws, size_t ws_size,
                              hipStream_t stream) {
  const float* node   = (const float*)d_in[0];
  const float* EF     = (const float*)d_in[1];
  const float* EE     = (const float*)d_in[2];
  const int*   pairs  = (const int*)d_in[3];
  const int*   nrels  = (const int*)d_in[4];
  const float* W_node = (const float*)d_in[5];
  const float* b_node = (const float*)d_in[6];
  const float* W_edge = (const float*)d_in[7];
  const float* b_edge = (const float*)d_in[8];
  const float* hW0[3] = {(const float*)d_in[9],  (const float*)d_in[15], (const float*)d_in[21]};
  const float* hb0[3] = {(const float*)d_in[10], (const float*)d_in[16], (const float*)d_in[22]};
  const float* hW1[3] = {(const float*)d_in[11], (const float*)d_in[17], (const float*)d_in[23]};
  const float* hb1[3] = {(const float*)d_in[12], (const float*)d_in[18], (const float*)d_in[24]};
  const float* hW2[3] = {(const float*)d_in[13], (const float*)d_in[19], (const float*)d_in[25]};
  const float* hb2[3] = {(const float*)d_in[14], (const float*)d_in[20], (const float*)d_in[26]};

  char* ws = (char*)d_ws;
  size_t off = 0;
  auto alloc = [&](size_t bytes) {
    char* p = ws + off;
    off += (bytes + 255) & ~(size_t)255;
    return p;
  };
  // --- persistent front ---
  unsigned short* WnT    = (unsigned short*)alloc((size_t)512 * 1024 * 2);
  unsigned short* WeT    = (unsigned short*)alloc((size_t)512 * 1024 * 2);
  unsigned short* W0T    = (unsigned short*)alloc((size_t)3072 * 1536 * 2);
  unsigned short* W1T    = (unsigned short*)alloc((size_t)3 * 512 * 1024 * 2);
  unsigned short* W2T    = (unsigned short*)alloc((size_t)3 * 128 * 512 * 2);
  float*          b2pad  = (float*)alloc((size_t)3 * 128 * 4);
  float*          b0cat  = (float*)alloc((size_t)3072 * 4);
  float*          b1cat  = (float*)alloc((size_t)1536 * 4);
  float*          b_ne   = (float*)alloc((size_t)1024 * 4);
  int2*           nodes  = (int2*)alloc((size_t)MROWS * 8);
  int*            offs   = (int*)alloc((size_t)256 * 4);
  int*            Mv     = (int*)alloc(256);
  int*            rmap   = (int*)alloc((size_t)MROWS * 4);
  float*          outc   = (float*)alloc((size_t)32 * 4);
  float*          h1part = (float*)alloc((size_t)24 * 512 * 4);
  // --- zone A: efm+EMb (dead after e-GEMM) -> reused as nfa/nfb, then h1 ---
  size_t zoneA = off;
  unsigned short* efm = (unsigned short*)alloc((size_t)MROWS * DEF * 2);  // 34.6M
  unsigned short* EMb = (unsigned short*)alloc((size_t)MROWS * DD * 2);   // 17.3M
  // --- zone B: ci_e (dead after L0') ---
  unsigned short* ci_e = (unsigned short*)alloc((size_t)MROWS * DD * 2);  // 17.3M
  // --- zone C: node_bf+nf (dead before L0') -> overlaid by h0big ---
  size_t zoneC = off;
  unsigned short* node_bf = (unsigned short*)alloc((size_t)MNODE * DNF * 2);
  unsigned short* nf      = (unsigned short*)alloc((size_t)MNODE * DD * 2);
  // overlays
  unsigned short* nfa   = (unsigned short*)(ws + zoneA);                 // 18.9M
  unsigned short* nfb   = nfa + (size_t)MNODE * 3072;                    // 18.9M
  unsigned short* h1    = (unsigned short*)(ws + zoneA);                 // 51.9M (after L0')
  unsigned short* h0big = (unsigned short*)(ws + zoneC);                 // 104M

  // 0. scan + PARALLEL h1c partials (1 launch, 25 blocks) ; finish ; fill
  k_scan_h1c<<<25, 256, 0, stream>>>(nrels, offs, Mv, nodes,
      hb0[0], hb0[1], hb0[2], hW1[0], hW1[1], hW1[2], h1part);
  k_finish<<<1, 512, 0, stream>>>(h1part, hb1[0], hb1[1], hb1[2],
      hW2[0], hW2[1], hW2[2], hb2[0], hb2[1], hb2[2], outc);
  // 1. prep: conv + 64x64 transposes + W2 pad + bias concats (1 launch)
  k_prep<<<5654, 256, 0, stream>>>(node, node_bf, W_node, WnT, W_edge, WeT,
      hW0[0], hW0[1], hW0[2], W0T, hW1[0], hW1[1], hW1[2], W1T,
      hW2[0], hW2[1], hW2[2], hb2[0], hb2[1], hb2[2], W2T, b2pad,
      hb0[0], hb0[1], hb0[2], b0cat, hb1[0], hb1[1], hb1[2], b1cat,
      b_node, b_edge, b_ne);
  // 2. constant-row fill of d_out
  k_fillout<<<(MROWS * 17 + 255) / 256, 256, 0, stream>>>(outc, (float*)d_out);
  // 3. compact edge gathers + node-pair table + row map
  k_gather_ef<<<MROWS, 256, 0, stream>>>(EF, EE, pairs, nrels, offs,
                                         efm, EMb, nodes, rmap);

  // 4. merged nf|e GEMM (EPI 6): head0 nf = node_bf@WnT^T+b_node (M=3072);
  //    head1 ci_e = 0.25(ee+ee') + 0.5(efm@WeT^T + b_edge)  (M=Mv compact)
  k_gemm<6><<<2 * MTILES * 4, 256, 0, stream>>>(
      node_bf, 1024, WnT, 1024, 1024, 4, b_ne, nf, 512,
      EMb, Mv, ci_e, MTILES * 4,
      (long long)(efm - node_bf), (long long)512 * 1024,
      (long long)(ci_e - nf), 512,
      nullptr, nullptr, nullptr, nullptr);

  // 5. node-side layer-0 partials, ONE fused dispatch (a/b halves):
  //    nfa = nf@W0[0:512,:]^T ; nfb = nf@W0[512:1024,:]^T  (each M=3072,N=3072,K=512)
  k_gemm<4><<<2 * (MNODE / 128) * 24, 256, 0, stream>>>(
      nf, 512, W0T, 1536, 512, 24, nullptr, nfa, 3072,
      nullptr, nullptr, nullptr, (MNODE / 128) * 24,
      0, 512, (long long)MNODE * 3072, 0, nullptr, nullptr, nullptr, nullptr);

  // 6. L0' (compact): h0 = relu(ci_e @ W0[1024:1536,:]^T + b0 + npair)
  k_gemm<5><<<MTILES * 24, 256, 0, stream>>>(
      ci_e, 512, W0T + 1024, 1536, 512, 24, b0cat, h0big, 3072,
      nullptr, Mv, nullptr, 0, 0, 0, 0, 0, nodes, nfa, nfb, nullptr);

  // 7. L1 (compact, fused over heads): h1[h] = relu(h0[:,h*1024:] @ W1[h]^T + b1[h])
  k_gemm<2><<<3 * MTILES * 4, 256, 0, stream>>>(
      h0big, 3072, W1T, 1024, 1024, 4, b1cat, h1, 512,
      nullptr, Mv, nullptr, MTILES * 4,
      1024, (long long)512 * 1024, (long long)MROWS * DD, 512,
      nullptr, nullptr, nullptr, nullptr);

  // 8. L2 (compact): padded GEMM, scatter valid rows into pre-filled d_out
  k_gemm<3><<<3 * MTILES, 256, 0, stream>>>(
      h1, 512, W2T, 512, 512, 1, b2pad, (unsigned short*)d_out, 0,
      nullptr, Mv, nullptr, 0, 0, 0, 0, 0, nullptr, nullptr, nullptr, rmap);
}

// Round 12
// 208.559 us; speedup vs baseline: 2.0099x; 1.0212x over previous
//
#include <hip/hip_runtime.h>
#include <stdint.h>

// Problem constants
#define BB 256
#define NNODE 12
#define PP 66
#define DNF 1024
#define DEF 1024
#define DD 512
#define MROWS (BB*PP)        // 16896
#define MNODE (BB*NNODE)     // 3072
#define MTILES (MROWS/128)   // 132

typedef __attribute__((ext_vector_type(8))) short s16x8;
typedef __attribute__((ext_vector_type(4))) float f32x4;
typedef __attribute__((ext_vector_type(8))) unsigned short u16x8;

__device__ __forceinline__ unsigned short f2bf(float f) {
  union { float f; unsigned u; } v; v.f = f;
  return (unsigned short)((v.u + 0x7FFFu + ((v.u >> 16) & 1u)) >> 16);
}
__device__ __forceinline__ float bf2f(unsigned short h) {
  union { unsigned u; float f; } v; v.u = ((unsigned)h) << 16;
  return v.f;
}

__device__ __forceinline__ void gll16(const void* g, void* l) {
  __builtin_amdgcn_global_load_lds(
      (const __attribute__((address_space(1))) void*)g,
      (__attribute__((address_space(3))) void*)l, 16, 0, 0);
}

// ------- k_scan_h1c: prefix scan + PARALLEL h1c partials (25 blocks x 256) ----
__global__ __launch_bounds__(256) void k_scan_h1c(
    const int* __restrict__ nrels, int* __restrict__ offs,
    int* __restrict__ Mv, int2* __restrict__ nodes,
    const float* __restrict__ b0a, const float* __restrict__ b0b,
    const float* __restrict__ b0c,
    const float* __restrict__ W1a, const float* __restrict__ W1b,
    const float* __restrict__ W1c,
    float* __restrict__ h1part) {
  const int bid = blockIdx.x, t = threadIdx.x;
  if (bid == 24) {
    __shared__ int s[256];
    const int val = nrels[t];
    s[t] = val;
    __syncthreads();
    for (int d = 1; d < 256; d <<= 1) {
      int x = (t >= d) ? s[t - d] : 0;
      __syncthreads();
      s[t] += x;
      __syncthreads();
    }
    offs[t] = s[t] - val;
    __syncthreads();
    const int total = s[255];
    if (t == 0) *Mv = total;
    if (t < 128) {
      int cr = total + t;
      if (cr < MROWS) nodes[cr] = make_int2(0, 0);
    }
    return;
  }
  const int h = bid >> 3, c = bid & 7;
  const float* b0 = h == 0 ? b0a : (h == 1 ? b0b : b0c);
  const float* W1 = h == 0 ? W1a : (h == 1 ? W1b : W1c);
  const int k0 = c * 128;
  float acc0 = 0.f, acc1 = 0.f;
#pragma unroll 8
  for (int kk = 0; kk < 128; ++kk) {
    const int k = k0 + kk;
    const float bv = fmaxf(b0[k], 0.f);
    acc0 += bv * W1[(size_t)k * 512 + t];
    acc1 += bv * W1[(size_t)k * 512 + t + 256];
  }
  h1part[(size_t)bid * 512 + t] = acc0;
  h1part[(size_t)bid * 512 + t + 256] = acc1;
}

// ------- k_finish: h1c = relu(b1 + sum partials) ; outc = b2 + h1c@W2 --------
__global__ __launch_bounds__(512) void k_finish(
    const float* __restrict__ h1part,
    const float* __restrict__ b1a, const float* __restrict__ b1b,
    const float* __restrict__ b1c,
    const float* __restrict__ w2a, const float* __restrict__ w2b,
    const float* __restrict__ w2c,
    const float* __restrict__ b2a, const float* __restrict__ b2b,
    const float* __restrict__ b2c, float* __restrict__ outc) {
  const int t = threadIdx.x;
  __shared__ float red[9];
  for (int h = 0; h < 3; ++h) {
    const float* b1 = h == 0 ? b1a : (h == 1 ? b1b : b1c);
    const float* W2 = h == 0 ? w2a : (h == 1 ? w2b : w2c);
    const float* b2 = h == 0 ? b2a : (h == 1 ? b2b : b2c);
    const int C = h == 0 ? 9 : (h == 1 ? 3 : 5);
    const int obase = h == 0 ? 0 : (h == 1 ? 9 : 12);
    if (t < 9) red[t] = 0.f;
    float s = b1[t];
#pragma unroll
    for (int cc = 0; cc < 8; ++cc)
      s += h1part[(size_t)(h * 8 + cc) * 512 + t];
    const float hv = fmaxf(s, 0.f);
    __syncthreads();
    float p[9] = {0.f, 0.f, 0.f, 0.f, 0.f, 0.f, 0.f, 0.f, 0.f};
#pragma unroll
    for (int c = 0; c < 9; ++c)
      if (c < C) p[c] = hv * W2[(size_t)t * C + c];
#pragma unroll
    for (int c = 0; c < 9; ++c)
#pragma unroll
      for (int off = 32; off; off >>= 1) p[c] += __shfl_xor(p[c], off);
    if ((t & 63) == 0)
      for (int c = 0; c < C; ++c) atomicAdd(&red[c], p[c]);
    __syncthreads();
    if (t < C) outc[obase + t] = red[t] + b2[t];
    __syncthreads();
  }
}

// ---------------- k_prep_all: prep + compact gather + constant fill ----------
// [0,3072) conv node->bf16 ; [3072,4864) 64x64 transposes ; [4864,5632) W2 pad
// [5632,5644) b0cat ; [5644,5650) b1cat ; [5650,5654) b_ne ;
// [5654,22550) compact gather_ef ; [22550,23672) fillout of d_out.
// All segments independent; needs offs (scan) + outc (finish) done.
__global__ __launch_bounds__(256) void k_prep_all(
    const float* __restrict__ node, unsigned short* __restrict__ node_bf,
    const float* __restrict__ W_node, unsigned short* __restrict__ WnT,
    const float* __restrict__ W_edge, unsigned short* __restrict__ WeT,
    const float* __restrict__ W0a, const float* __restrict__ W0b,
    const float* __restrict__ W0c, unsigned short* __restrict__ W0T,
    const float* __restrict__ W1a, const float* __restrict__ W1b,
    const float* __restrict__ W1c, unsigned short* __restrict__ W1T,
    const float* __restrict__ w2a, const float* __restrict__ w2b,
    const float* __restrict__ w2c,
    const float* __restrict__ b2a, const float* __restrict__ b2b,
    const float* __restrict__ b2c,
    unsigned short* __restrict__ W2T, float* __restrict__ b2pad,
    const float* __restrict__ b0a, const float* __restrict__ b0b,
    const float* __restrict__ b0c, float* __restrict__ b0cat,
    const float* __restrict__ b1a, const float* __restrict__ b1b,
    const float* __restrict__ b1c, float* __restrict__ b1cat,
    const float* __restrict__ b_node, const float* __restrict__ b_edge,
    float* __restrict__ b_ne,
    const float* __restrict__ EF, const float* __restrict__ EE,
    const int* __restrict__ pairs, const int* __restrict__ nrels,
    const int* __restrict__ offs,
    unsigned short* __restrict__ efm, unsigned short* __restrict__ emb,
    int2* __restrict__ nodes, int* __restrict__ rmap,
    const float* __restrict__ outc, float* __restrict__ out) {
  __shared__ float tile[64][65];
  const int bid = blockIdx.x, t = threadIdx.x;
  if (bid < 3072) {
    int i = bid * 256 + t;
    float4 v = ((const float4*)node)[i];
    ushort4 o;
    o.x = f2bf(v.x); o.y = f2bf(v.y); o.z = f2bf(v.z); o.w = f2bf(v.w);
    ((ushort4*)node_bf)[i] = o;
  } else if (bid < 4864) {
    int tau = bid - 3072;
    const float* src; unsigned short* dst; int K, N;
    if (tau < 128)       { src = W_node; dst = WnT; K = 1024; N = 512; }
    else if (tau < 256)  { src = W_edge; dst = WeT; K = 1024; N = 512; tau -= 128; }
    else if (tau < 1408) {
      int hh = (tau - 256) / 384; tau = (tau - 256) % 384;
      src = hh == 0 ? W0a : (hh == 1 ? W0b : W0c);
      dst = W0T + (size_t)hh * 1024 * 1536; K = 1536; N = 1024;
    } else {
      int hh = (tau - 1408) / 128; tau = (tau - 1408) % 128;
      src = hh == 0 ? W1a : (hh == 1 ? W1b : W1c);
      dst = W1T + (size_t)hh * 512 * 1024; K = 1024; N = 512;
    }
    const int ntn = N >> 6;
    const int kb = (tau / ntn) * 64, nb = (tau % ntn) * 64;
    const int tx = t & 15, ty = t >> 4;
#pragma unroll
    for (int i = 0; i < 4; i++) {
      float4 v = *(const float4*)&src[(size_t)(kb + ty + 16 * i) * N + nb + tx * 4];
      tile[ty + 16 * i][tx * 4 + 0] = v.x;
      tile[ty + 16 * i][tx * 4 + 1] = v.y;
      tile[ty + 16 * i][tx * 4 + 2] = v.z;
      tile[ty + 16 * i][tx * 4 + 3] = v.w;
    }
    __syncthreads();
    const int wx = t & 7, wy = t >> 3;
#pragma unroll
    for (int i = 0; i < 2; i++) {
      const int n = wy + 32 * i;
      u16x8 o;
#pragma unroll
      for (int j = 0; j < 8; j++) o[j] = f2bf(tile[wx * 8 + j][n]);
      *(u16x8*)&dst[(size_t)(nb + n) * K + kb + wx * 8] = o;
    }
  } else if (bid < 5632) {
    int e = bid - 4864;
    int h = e >> 8, blk = e & 255;
    const int C = (h == 0) ? 9 : ((h == 1) ? 3 : 5);
    const float* W2 = (h == 0) ? w2a : ((h == 1) ? w2b : w2c);
    const float* b2 = (h == 0) ? b2a : ((h == 1) ? b2b : b2c);
    int idx = blk * 256 + t;
    int n = idx >> 9, k = idx & 511;
    W2T[(size_t)h * 65536 + idx] = (n < C) ? f2bf(W2[(size_t)k * C + n]) : (unsigned short)0;
    if (blk == 0 && t < 128)
      b2pad[h * 128 + t] = (t < C) ? b2[t] : 0.f;
  } else if (bid < 5644) {
    int j = bid - 5632;
    const float* b0 = (j < 4) ? b0a : (j < 8 ? b0b : b0c);
    b0cat[j * 256 + t] = b0[(j & 3) * 256 + t];
  } else if (bid < 5650) {
    int j = bid - 5644;
    const float* b1 = (j < 2) ? b1a : (j < 4 ? b1b : b1c);
    b1cat[j * 256 + t] = b1[(j & 1) * 256 + t];
  } else if (bid < 5654) {
    int idx = (bid - 5650) * 256 + t;
    b_ne[idx] = (idx < 512) ? b_node[idx] : b_edge[idx - 512];
  } else if (bid < 22550) {
    // compact gather: edge features/embeddings + node-pair + row map
    int r = bid - 5654;
    int b = r / PP, p = r - b * PP;
    if (p >= nrels[b]) return;
    const int cr = offs[b] + p;
    int i0 = pairs[r * 2 + 0], i1 = pairs[r * 2 + 1];
    if (t == 0) {
      nodes[cr] = make_int2(b * NNODE + i0, b * NNODE + i1);
      rmap[cr] = r;
    }
    const float4* e01 = (const float4*)(EF + ((size_t)((b * NNODE + i0) * NNODE + i1)) * DEF);
    const float4* e10 = (const float4*)(EF + ((size_t)((b * NNODE + i1) * NNODE + i0)) * DEF);
    float4 a = e01[t], c = e10[t];
    ushort4 o;
    o.x = f2bf(0.5f * (a.x + c.x));
    o.y = f2bf(0.5f * (a.y + c.y));
    o.z = f2bf(0.5f * (a.z + c.z));
    o.w = f2bf(0.5f * (a.w + c.w));
    ((ushort4*)(efm + (size_t)cr * DEF))[t] = o;
    const float2* g01 = (const float2*)(EE + ((size_t)((b * NNODE + i0) * NNODE + i1)) * DD);
    const float2* g10 = (const float2*)(EE + ((size_t)((b * NNODE + i1) * NNODE + i0)) * DD);
    float2 x = g01[t], y = g10[t];
    ushort2 eo;
    eo.x = f2bf(0.25f * (x.x + y.x));
    eo.y = f2bf(0.25f * (x.y + y.y));
    ((ushort2*)(emb + (size_t)cr * DD))[t] = eo;
  } else {
    // fillout: constant rows of d_out
    const int e = (bid - 22550) * 256 + t;
    if (e >= MROWS * 17) return;
    int c;
    if (e < MROWS * 9) c = e % 9;
    else if (e < MROWS * 12) c = 9 + (e - MROWS * 9) % 3;
    else c = 12 + (e - MROWS * 12) % 5;
    out[e] = outc[c];
  }
}

// ---------------- 128-tile MFMA GEMM (m97-family: EXACTLY 32 KB LDS) ---------
// 32768 B -> 5 blocks/CU (33792 capped at 4: r7->r8 occupancy 35.9->27.9).
// EPI: 0 = +bias -> bf16 ; 2 = relu(+bias) -> bf16 ;
//      3 = layer-2 heads fp32, scatter via rmap ; 4 = raw bf16 (no bias) ;
//      5 = L0': relu(bias + acc + npair); npair tile ld=256B with chunk-XOR
//          swizzle (chunk ^= (row>>2)&7) -> conflict-free, no pad ;
//      6 = merged nf|e: head0 +bias->bf16(nf), head1 e-assembly into ci_e.
template <int EPI>
__global__ __launch_bounds__(256) void k_gemm(
    const unsigned short* __restrict__ A, int ldA,
    const unsigned short* __restrict__ BT, int ldB, int K,
    int Ntiles,
    const float* __restrict__ bias,
    unsigned short* __restrict__ outb, int ldo,
    const unsigned short* __restrict__ em,
    const int* __restrict__ Mvp,
    unsigned short* __restrict__ ci,
    int blocksPerHead, long long aHeadOff, long long bHeadOff,
    long long oHeadOff, int biasHeadOff,
    const int2* __restrict__ nodes,
    const unsigned short* __restrict__ nfa,
    const unsigned short* __restrict__ nfb,
    const int* __restrict__ rmap) {
  __shared__ __align__(16) unsigned short sm[16384];  // exactly 32 KB
  char* smc = (char*)sm;
  const int t = threadIdx.x;
  const int l = t & 63, w = t >> 6;
  const int wm = w >> 1, wn = w & 1;
  int bid = blockIdx.x;

  int head = 0;
  unsigned short* outp = outb;
  if constexpr (EPI == 3) {
    head = bid / MTILES;
    bid -= head * MTILES;
    A += (size_t)head * MROWS * DD;
    BT += (size_t)head * 128 * DD;
    bias += head * 128;
  } else {
    if (blocksPerHead > 0) {
      head = bid / blocksPerHead;
      bid -= head * blocksPerHead;
      A += (long long)head * aHeadOff;
      BT += (long long)head * bHeadOff;
      bias += head * biasHeadOff;
      outp = outb + (long long)head * oHeadOff;
    }
  }
  const int tn = bid % Ntiles, tm = bid / Ntiles;

  int Mv = MROWS;
  if (Mvp) Mv = *Mvp;
  if constexpr (EPI == 6) { if (head == 0) Mv = MNODE; }
  if (Mvp) {
    if (tm * 128 >= Mv) return;   // compact early-exit (uniform branch)
  }

  const int lrow = l >> 3;
  const int scol = (l & 7) ^ lrow;       // pre-swizzled source chunk
  const unsigned short* Ap = A + (size_t)(tm * 128 + w * 8 + lrow) * ldA + scol * 8;
  const unsigned short* Bp = BT + (size_t)(tn * 128 + w * 8 + lrow) * ldB + scol * 8;

  f32x4 acc[4][4] = {};
  const int hi = l >> 4, l15 = l & 15, l7 = l & 7;
  const int nk = K >> 6;

  for (int kt = 0; kt < nk; ++kt) {
#pragma unroll
    for (int c = 0; c < 4; ++c) {
      gll16(Ap + (size_t)c * 32 * ldA, smc + c * 4096 + w * 1024);
      gll16(Bp + (size_t)c * 32 * ldB, smc + 16384 + c * 4096 + w * 1024);
    }
    __syncthreads();
#pragma unroll
    for (int kk = 0; kk < 2; ++kk) {
      const int cb = (((kk << 2) + hi) ^ l7) << 4;
      s16x8 af[4], bfr[4];
#pragma unroll
      for (int m = 0; m < 4; m++)
        af[m] = *(const s16x8*)(smc + (wm * 64 + m * 16 + l15) * 128 + cb);
#pragma unroll
      for (int n = 0; n < 4; n++)
        bfr[n] = *(const s16x8*)(smc + 16384 + (wn * 64 + n * 16 + l15) * 128 + cb);
#pragma unroll
      for (int m = 0; m < 4; m++)
#pragma unroll
        for (int n = 0; n < 4; n++)
          asm volatile("v_mfma_f32_16x16x32_bf16 %0, %1, %2, %0"
                       : "+v"(acc[m][n])
                       : "v"(af[m]), "v"(bfr[n]));
    }
    __syncthreads();
    Ap += 64;
    Bp += 64;
  }
  asm volatile("s_nop 7\n\ts_nop 7\n\ts_nop 7" :::);  // MFMA->VALU hazard guard

  if constexpr (EPI == 5) {
    // Stage npair = nfa[i0]+nfb[i1] for the 128x128 tile, coalesced 16B/lane.
    // Layout: row*256B + swizzled 16B chunk (chunk ^= (row>>2)&7): the 4
    // hi-groups (rows +4 apart) land on distinct banks -> conflict-free reads.
    const int se_r = t >> 4;            // 0..15
    const int se_ch = t & 15;           // 16B chunk index 0..15
#pragma unroll
    for (int it = 0; it < 8; ++it) {
      const int rr = se_r + (it << 4);
      const int2 nn = nodes[tm * 128 + rr];   // pad rows zero-initialized
      union { unsigned short s[8]; unsigned long long q[2]; } ov;
      u16x8 va = *(const u16x8*)&nfa[(size_t)nn.x * 3072 + tn * 128 + se_ch * 8];
      u16x8 vb = *(const u16x8*)&nfb[(size_t)nn.y * 3072 + tn * 128 + se_ch * 8];
#pragma unroll
      for (int j = 0; j < 8; ++j)
        ov.s[j] = f2bf(bf2f(va[j]) + bf2f(vb[j]));
      const int sch = se_ch ^ ((rr >> 2) & 7);
      *(unsigned long long*)(smc + rr * 256 + (sch << 4)) = ov.q[0];
      *(unsigned long long*)(smc + rr * 256 + (sch << 4) + 8) = ov.q[1];
    }
    __syncthreads();
  }

  // C/D layout: col = lane&15, row = (lane>>4)*4 + reg
  const int gr_base = tm * 128 + wm * 64 + (hi << 2);
  const int gc_base = tn * 128 + wn * 64 + l15;
  const int lr_base = wm * 64 + (hi << 2);
  const int lc_base = wn * 64 + l15;

  int Cc = 0; size_t obase = 0;
  if constexpr (EPI == 3) {
    Cc = (head == 0) ? 9 : ((head == 1) ? 3 : 5);
    obase = (head == 0) ? 0 : ((head == 1) ? (size_t)MROWS * 9 : (size_t)MROWS * 12);
  }

#pragma unroll
  for (int n = 0; n < 4; n++) {
    const int gc = gc_base + n * 16;
    const float bv = (EPI == 4) ? 0.f : bias[gc];
#pragma unroll
    for (int m = 0; m < 4; m++) {
#pragma unroll
      for (int i = 0; i < 4; i++) {
        const int gr = gr_base + m * 16 + i;
        float v = acc[m][n][i] + bv;
        if constexpr (EPI == 0 || EPI == 4) {
          outp[(size_t)gr * ldo + gc] = f2bf(v);
        } else if constexpr (EPI == 2) {
          outp[(size_t)gr * ldo + gc] = f2bf(v > 0.f ? v : 0.f);
        } else if constexpr (EPI == 5) {
          const int lr = lr_base + m * 16 + i;
          const int lc = lc_base + n * 16;
          const int rch = (lc >> 3) ^ ((lr >> 2) & 7);
          v += bf2f(*(const unsigned short*)(smc + lr * 256 + (rch << 4) + (lc & 7) * 2));
          outp[(size_t)gr * ldo + gc] = f2bf(v > 0.f ? v : 0.f);
        } else if constexpr (EPI == 6) {
          if (head == 0) {
            outp[(size_t)gr * ldo + gc] = f2bf(v);
          } else {
            float e = bf2f(em[(size_t)gr * DD + gc]) + 0.5f * v;
            ci[(size_t)gr * DD + gc] = f2bf(e);
          }
        } else {
          if (gc < Cc && gr < Mv)
            ((float*)outb)[obase + (size_t)rmap[gr] * Cc + gc] = v;
        }
      }
    }
  }
}

// ---------------- launcher ----------------
extern "C" void kernel_launch(void* const* d_in, const int* in_sizes, int n_in,
                              void* d_out, int out_size, void* d_ws, size_t ws_size,
                              hipStream_t stream) {
  const float* node   = (const float*)d_in[0];
  const float* EF     = (const float*)d_in[1];
  const float* EE     = (const float*)d_in[2];
  const int*   pairs  = (const int*)d_in[3];
  const int*   nrels  = (const int*)d_in[4];
  const float* W_node = (const float*)d_in[5];
  const float* b_node = (const float*)d_in[6];
  const float* W_edge = (const float*)d_in[7];
  const float* b_edge = (const float*)d_in[8];
  const float* hW0[3] = {(const float*)d_in[9],  (const float*)d_in[15], (const float*)d_in[21]};
  const float* hb0[3] = {(const float*)d_in[10], (const float*)d_in[16], (const float*)d_in[22]};
  const float* hW1[3] = {(const float*)d_in[11], (const float*)d_in[17], (const float*)d_in[23]};
  const float* hb1[3] = {(const float*)d_in[12], (const float*)d_in[18], (const float*)d_in[24]};
  const float* hW2[3] = {(const float*)d_in[13], (const float*)d_in[19], (const float*)d_in[25]};
  const float* hb2[3] = {(const float*)d_in[14], (const float*)d_in[20], (const float*)d_in[26]};

  char* ws = (char*)d_ws;
  size_t off = 0;
  auto alloc = [&](size_t bytes) {
    char* p = ws + off;
    off += (bytes + 255) & ~(size_t)255;
    return p;
  };
  // --- persistent front ---
  unsigned short* WnT    = (unsigned short*)alloc((size_t)512 * 1024 * 2);
  unsigned short* WeT    = (unsigned short*)alloc((size_t)512 * 1024 * 2);
  unsigned short* W0T    = (unsigned short*)alloc((size_t)3072 * 1536 * 2);
  unsigned short* W1T    = (unsigned short*)alloc((size_t)3 * 512 * 1024 * 2);
  unsigned short* W2T    = (unsigned short*)alloc((size_t)3 * 128 * 512 * 2);
  float*          b2pad  = (float*)alloc((size_t)3 * 128 * 4);
  float*          b0cat  = (float*)alloc((size_t)3072 * 4);
  float*          b1cat  = (float*)alloc((size_t)1536 * 4);
  float*          b_ne   = (float*)alloc((size_t)1024 * 4);
  int2*           nodes  = (int2*)alloc((size_t)MROWS * 8);
  int*            offs   = (int*)alloc((size_t)256 * 4);
  int*            Mv     = (int*)alloc(256);
  int*            rmap   = (int*)alloc((size_t)MROWS * 4);
  float*          outc   = (float*)alloc((size_t)32 * 4);
  float*          h1part = (float*)alloc((size_t)24 * 512 * 4);
  // --- zone A: efm+EMb (dead after e-GEMM) -> reused as nfa/nfb, then h1 ---
  size_t zoneA = off;
  unsigned short* efm = (unsigned short*)alloc((size_t)MROWS * DEF * 2);  // 34.6M
  unsigned short* EMb = (unsigned short*)alloc((size_t)MROWS * DD * 2);   // 17.3M
  // --- zone B: ci_e (dead after L0') ---
  unsigned short* ci_e = (unsigned short*)alloc((size_t)MROWS * DD * 2);  // 17.3M
  // --- zone C: node_bf+nf (dead before L0') -> overlaid by h0big ---
  size_t zoneC = off;
  unsigned short* node_bf = (unsigned short*)alloc((size_t)MNODE * DNF * 2);
  unsigned short* nf      = (unsigned short*)alloc((size_t)MNODE * DD * 2);
  // overlays
  unsigned short* nfa   = (unsigned short*)(ws + zoneA);                 // 18.9M
  unsigned short* nfb   = nfa + (size_t)MNODE * 3072;                    // 18.9M
  unsigned short* h1    = (unsigned short*)(ws + zoneA);                 // 51.9M (after L0')
  unsigned short* h0big = (unsigned short*)(ws + zoneC);                 // 104M

  // 0. scan + PARALLEL h1c partials ; finish (outc)
  k_scan_h1c<<<25, 256, 0, stream>>>(nrels, offs, Mv, nodes,
      hb0[0], hb0[1], hb0[2], hW1[0], hW1[1], hW1[2], h1part);
  k_finish<<<1, 512, 0, stream>>>(h1part, hb1[0], hb1[1], hb1[2],
      hW2[0], hW2[1], hW2[2], hb2[0], hb2[1], hb2[2], outc);
  // 1. prep + compact gather + constant fill (ONE launch, 23672 blocks)
  k_prep_all<<<23672, 256, 0, stream>>>(node, node_bf, W_node, WnT, W_edge, WeT,
      hW0[0], hW0[1], hW0[2], W0T, hW1[0], hW1[1], hW1[2], W1T,
      hW2[0], hW2[1], hW2[2], hb2[0], hb2[1], hb2[2], W2T, b2pad,
      hb0[0], hb0[1], hb0[2], b0cat, hb1[0], hb1[1], hb1[2], b1cat,
      b_node, b_edge, b_ne,
      EF, EE, pairs, nrels, offs, efm, EMb, nodes, rmap,
      outc, (float*)d_out);

  // 2. merged nf|e GEMM (EPI 6): head0 nf = node_bf@WnT^T+b_node (M=3072);
  //    head1 ci_e = 0.25(ee+ee') + 0.5(efm@WeT^T + b_edge)  (M=Mv compact)
  k_gemm<6><<<2 * MTILES * 4, 256, 0, stream>>>(
      node_bf, 1024, WnT, 1024, 1024, 4, b_ne, nf, 512,
      EMb, Mv, ci_e, MTILES * 4,
      (long long)(efm - node_bf), (long long)512 * 1024,
      (long long)(ci_e - nf), 512,
      nullptr, nullptr, nullptr, nullptr);

  // 3. node-side layer-0 partials, ONE fused dispatch (a/b halves):
  //    nfa = nf@W0[0:512,:]^T ; nfb = nf@W0[512:1024,:]^T  (each M=3072,N=3072,K=512)
  k_gemm<4><<<2 * (MNODE / 128) * 24, 256, 0, stream>>>(
      nf, 512, W0T, 1536, 512, 24, nullptr, nfa, 3072,
      nullptr, nullptr, nullptr, (MNODE / 128) * 24,
      0, 512, (long long)MNODE * 3072, 0, nullptr, nullptr, nullptr, nullptr);

  // 4. L0' (compact): h0 = relu(ci_e @ W0[1024:1536,:]^T + b0 + npair)
  k_gemm<5><<<MTILES * 24, 256, 0, stream>>>(
      ci_e, 512, W0T + 1024, 1536, 512, 24, b0cat, h0big, 3072,
      nullptr, Mv, nullptr, 0, 0, 0, 0, 0, nodes, nfa, nfb, nullptr);

  // 5. L1 (compact, fused over heads): h1[h] = relu(h0[:,h*1024:] @ W1[h]^T + b1[h])
  k_gemm<2><<<3 * MTILES * 4, 256, 0, stream>>>(
      h0big, 3072, W1T, 1024, 1024, 4, b1cat, h1, 512,
      nullptr, Mv, nullptr, MTILES * 4,
      1024, (long long)512 * 1024, (long long)MROWS * DD, 512,
      nullptr, nullptr, nullptr, nullptr);

  // 6. L2 (compact): padded GEMM, scatter valid rows into pre-filled d_out
  k_gemm<3><<<3 * MTILES, 256, 0, stream>>>(
      h1, 512, W2T, 512, 512, 1, b2pad, (unsigned short*)d_out, 0,
      nullptr, Mv, nullptr, 0, 0, 0, 0, 0, nullptr, nullptr, nullptr, rmap);
}

// Round 13
// 201.359 us; speedup vs baseline: 2.0818x; 1.0358x over previous
//
#include <hip/hip_runtime.h>
#include <stdint.h>

// Problem constants
#define BB 256
#define NNODE 12
#define PP 66
#define DNF 1024
#define DEF 1024
#define DD 512
#define MROWS (BB*PP)        // 16896
#define MNODE (BB*NNODE)     // 3072
#define MTILES (MROWS/128)   // 132

typedef __attribute__((ext_vector_type(8))) short s16x8;
typedef __attribute__((ext_vector_type(4))) float f32x4;
typedef __attribute__((ext_vector_type(8))) unsigned short u16x8;

__device__ __forceinline__ unsigned short f2bf(float f) {
  union { float f; unsigned u; } v; v.f = f;
  return (unsigned short)((v.u + 0x7FFFu + ((v.u >> 16) & 1u)) >> 16);
}
__device__ __forceinline__ float bf2f(unsigned short h) {
  union { unsigned u; float f; } v; v.u = ((unsigned)h) << 16;
  return v.f;
}

__device__ __forceinline__ void gll16(const void* g, void* l) {
  __builtin_amdgcn_global_load_lds(
      (const __attribute__((address_space(1))) void*)g,
      (__attribute__((address_space(3))) void*)l, 16, 0, 0);
}

// ---------------- k_front: h1c partials + scan + prep (ONE launch) ----------
// [0,24) h1c partial blocks ; [24] prefix scan + Mv + nodes pad-init ;
// [25,3097) conv node->bf16 ; [3097,4889) 64x64 transposes ;
// [4889,5657) W2 pad ; [5657,5669) b0cat ; [5669,5675) b1cat ; [5675,5679) b_ne
__global__ __launch_bounds__(256) void k_front(
    const int* __restrict__ nrels, int* __restrict__ offs,
    int* __restrict__ Mv, int2* __restrict__ nodes,
    float* __restrict__ h1part,
    const float* __restrict__ node, unsigned short* __restrict__ node_bf,
    const float* __restrict__ W_node, unsigned short* __restrict__ WnT,
    const float* __restrict__ W_edge, unsigned short* __restrict__ WeT,
    const float* __restrict__ W0a, const float* __restrict__ W0b,
    const float* __restrict__ W0c, unsigned short* __restrict__ W0T,
    const float* __restrict__ W1a, const float* __restrict__ W1b,
    const float* __restrict__ W1c, unsigned short* __restrict__ W1T,
    const float* __restrict__ w2a, const float* __restrict__ w2b,
    const float* __restrict__ w2c,
    const float* __restrict__ b2a, const float* __restrict__ b2b,
    const float* __restrict__ b2c,
    unsigned short* __restrict__ W2T, float* __restrict__ b2pad,
    const float* __restrict__ b0a, const float* __restrict__ b0b,
    const float* __restrict__ b0c, float* __restrict__ b0cat,
    const float* __restrict__ b1a, const float* __restrict__ b1b,
    const float* __restrict__ b1c, float* __restrict__ b1cat,
    const float* __restrict__ b_node, const float* __restrict__ b_edge,
    float* __restrict__ b_ne) {
  __shared__ float tile[64][65];
  const int bid = blockIdx.x, t = threadIdx.x;
  if (bid < 24) {
    // h1c partials: h = bid/8, k-chunk = bid%8 of 128 rows; cols t, t+256
    const int h = bid >> 3, c = bid & 7;
    const float* b0 = h == 0 ? b0a : (h == 1 ? b0b : b0c);
    const float* W1 = h == 0 ? W1a : (h == 1 ? W1b : W1c);
    const int k0 = c * 128;
    float acc0 = 0.f, acc1 = 0.f;
#pragma unroll 8
    for (int kk = 0; kk < 128; ++kk) {
      const int k = k0 + kk;
      const float bv = fmaxf(b0[k], 0.f);
      acc0 += bv * W1[(size_t)k * 512 + t];
      acc1 += bv * W1[(size_t)k * 512 + t + 256];
    }
    h1part[(size_t)bid * 512 + t] = acc0;
    h1part[(size_t)bid * 512 + t + 256] = acc1;
  } else if (bid == 24) {
    // exclusive prefix scan of num_rels + Mv + compact-nodes pad zero-init
    __shared__ int s[256];
    const int val = nrels[t];
    s[t] = val;
    __syncthreads();
    for (int d = 1; d < 256; d <<= 1) {
      int x = (t >= d) ? s[t - d] : 0;
      __syncthreads();
      s[t] += x;
      __syncthreads();
    }
    offs[t] = s[t] - val;
    __syncthreads();
    const int total = s[255];
    if (t == 0) *Mv = total;
    if (t < 128) {
      int cr = total + t;
      if (cr < MROWS) nodes[cr] = make_int2(0, 0);
    }
  } else if (bid < 3097) {
    int i = (bid - 25) * 256 + t;
    float4 v = ((const float4*)node)[i];
    ushort4 o;
    o.x = f2bf(v.x); o.y = f2bf(v.y); o.z = f2bf(v.z); o.w = f2bf(v.w);
    ((ushort4*)node_bf)[i] = o;
  } else if (bid < 4889) {
    int tau = bid - 3097;
    const float* src; unsigned short* dst; int K, N;
    if (tau < 128)       { src = W_node; dst = WnT; K = 1024; N = 512; }
    else if (tau < 256)  { src = W_edge; dst = WeT; K = 1024; N = 512; tau -= 128; }
    else if (tau < 1408) {
      int hh = (tau - 256) / 384; tau = (tau - 256) % 384;
      src = hh == 0 ? W0a : (hh == 1 ? W0b : W0c);
      dst = W0T + (size_t)hh * 1024 * 1536; K = 1536; N = 1024;
    } else {
      int hh = (tau - 1408) / 128; tau = (tau - 1408) % 128;
      src = hh == 0 ? W1a : (hh == 1 ? W1b : W1c);
      dst = W1T + (size_t)hh * 512 * 1024; K = 1024; N = 512;
    }
    const int ntn = N >> 6;
    const int kb = (tau / ntn) * 64, nb = (tau % ntn) * 64;
    const int tx = t & 15, ty = t >> 4;
#pragma unroll
    for (int i = 0; i < 4; i++) {
      float4 v = *(const float4*)&src[(size_t)(kb + ty + 16 * i) * N + nb + tx * 4];
      tile[ty + 16 * i][tx * 4 + 0] = v.x;
      tile[ty + 16 * i][tx * 4 + 1] = v.y;
      tile[ty + 16 * i][tx * 4 + 2] = v.z;
      tile[ty + 16 * i][tx * 4 + 3] = v.w;
    }
    __syncthreads();
    const int wx = t & 7, wy = t >> 3;
#pragma unroll
    for (int i = 0; i < 2; i++) {
      const int n = wy + 32 * i;
      u16x8 o;
#pragma unroll
      for (int j = 0; j < 8; j++) o[j] = f2bf(tile[wx * 8 + j][n]);
      *(u16x8*)&dst[(size_t)(nb + n) * K + kb + wx * 8] = o;
    }
  } else if (bid < 5657) {
    int e = bid - 4889;
    int h = e >> 8, blk = e & 255;
    const int C = (h == 0) ? 9 : ((h == 1) ? 3 : 5);
    const float* W2 = (h == 0) ? w2a : ((h == 1) ? w2b : w2c);
    const float* b2 = (h == 0) ? b2a : ((h == 1) ? b2b : b2c);
    int idx = blk * 256 + t;
    int n = idx >> 9, k = idx & 511;
    W2T[(size_t)h * 65536 + idx] = (n < C) ? f2bf(W2[(size_t)k * C + n]) : (unsigned short)0;
    if (blk == 0 && t < 128)
      b2pad[h * 128 + t] = (t < C) ? b2[t] : 0.f;
  } else if (bid < 5669) {
    int j = bid - 5657;
    const float* b0 = (j < 4) ? b0a : (j < 8 ? b0b : b0c);
    b0cat[j * 256 + t] = b0[(j & 3) * 256 + t];
  } else if (bid < 5675) {
    int j = bid - 5669;
    const float* b1 = (j < 2) ? b1a : (j < 4 ? b1b : b1c);
    b1cat[j * 256 + t] = b1[(j & 1) * 256 + t];
  } else {
    int idx = (bid - 5675) * 256 + t;
    b_ne[idx] = (idx < 512) ? b_node[idx] : b_edge[idx - 512];
  }
}

// ------- k_gather_fin: compact gather + outc finish (ONE launch) -------------
// [0,16896) compact gather_ef ; [16896] finish: outc = b2 + relu(b1+Σpart)@W2
__global__ __launch_bounds__(256) void k_gather_fin(
    const float* __restrict__ EF, const float* __restrict__ EE,
    const int* __restrict__ pairs, const int* __restrict__ nrels,
    const int* __restrict__ offs,
    unsigned short* __restrict__ efm, unsigned short* __restrict__ emb,
    int2* __restrict__ nodes, int* __restrict__ rmap,
    const float* __restrict__ h1part,
    const float* __restrict__ b1a, const float* __restrict__ b1b,
    const float* __restrict__ b1c,
    const float* __restrict__ w2a, const float* __restrict__ w2b,
    const float* __restrict__ w2c,
    const float* __restrict__ b2a, const float* __restrict__ b2b,
    const float* __restrict__ b2c, float* __restrict__ outc) {
  const int bid = blockIdx.x, t = threadIdx.x;
  if (bid == MROWS) {
    // finish (256 threads: cols t and t+256)
    __shared__ float red[9];
    for (int h = 0; h < 3; ++h) {
      const float* b1 = h == 0 ? b1a : (h == 1 ? b1b : b1c);
      const float* W2 = h == 0 ? w2a : (h == 1 ? w2b : w2c);
      const float* b2 = h == 0 ? b2a : (h == 1 ? b2b : b2c);
      const int C = h == 0 ? 9 : (h == 1 ? 3 : 5);
      const int obase = h == 0 ? 0 : (h == 1 ? 9 : 12);
      if (t < 9) red[t] = 0.f;
      float s0 = b1[t], s1 = b1[t + 256];
#pragma unroll
      for (int cc = 0; cc < 8; ++cc) {
        s0 += h1part[(size_t)(h * 8 + cc) * 512 + t];
        s1 += h1part[(size_t)(h * 8 + cc) * 512 + t + 256];
      }
      const float hv0 = fmaxf(s0, 0.f), hv1 = fmaxf(s1, 0.f);
      __syncthreads();
      float p[9] = {0.f, 0.f, 0.f, 0.f, 0.f, 0.f, 0.f, 0.f, 0.f};
#pragma unroll
      for (int c = 0; c < 9; ++c)
        if (c < C) p[c] = hv0 * W2[(size_t)t * C + c] + hv1 * W2[(size_t)(t + 256) * C + c];
#pragma unroll
      for (int c = 0; c < 9; ++c)
#pragma unroll
        for (int off = 32; off; off >>= 1) p[c] += __shfl_xor(p[c], off);
      if ((t & 63) == 0)
        for (int c = 0; c < C; ++c) atomicAdd(&red[c], p[c]);
      __syncthreads();
      if (t < C) outc[obase + t] = red[t] + b2[t];
      __syncthreads();
    }
    return;
  }
  int r = bid;
  int b = r / PP, p = r - b * PP;
  if (p >= nrels[b]) return;
  const int cr = offs[b] + p;
  int i0 = pairs[r * 2 + 0], i1 = pairs[r * 2 + 1];
  if (t == 0) {
    nodes[cr] = make_int2(b * NNODE + i0, b * NNODE + i1);
    rmap[cr] = r;
  }
  const float4* e01 = (const float4*)(EF + ((size_t)((b * NNODE + i0) * NNODE + i1)) * DEF);
  const float4* e10 = (const float4*)(EF + ((size_t)((b * NNODE + i1) * NNODE + i0)) * DEF);
  float4 a = e01[t], c = e10[t];
  ushort4 o;
  o.x = f2bf(0.5f * (a.x + c.x));
  o.y = f2bf(0.5f * (a.y + c.y));
  o.z = f2bf(0.5f * (a.z + c.z));
  o.w = f2bf(0.5f * (a.w + c.w));
  ((ushort4*)(efm + (size_t)cr * DEF))[t] = o;
  const float2* g01 = (const float2*)(EE + ((size_t)((b * NNODE + i0) * NNODE + i1)) * DD);
  const float2* g10 = (const float2*)(EE + ((size_t)((b * NNODE + i1) * NNODE + i0)) * DD);
  float2 x = g01[t], y = g10[t];
  ushort2 eo;
  eo.x = f2bf(0.25f * (x.x + y.x));
  eo.y = f2bf(0.25f * (x.y + y.y));
  ((ushort2*)(emb + (size_t)cr * DD))[t] = eo;
}

// ---------------- 128-tile MFMA GEMM (m97-family: EXACTLY 32 KB LDS) ---------
// EPI: 0 = +bias -> bf16 ; 2 = relu(+bias) -> bf16 ;
//      3 = layer-2 heads fp32, scatter via rmap ; 4 = raw bf16 (no bias) ;
//      5 = L0': relu(bias + acc + npair); npair LDS tile chunk-XOR swizzled ;
//      6 = merged nf|e (+ trailing fillout blocks: nfa=outc, nfb=d_out).
template <int EPI>
__global__ __launch_bounds__(256) void k_gemm(
    const unsigned short* __restrict__ A, int ldA,
    const unsigned short* __restrict__ BT, int ldB, int K,
    int Ntiles,
    const float* __restrict__ bias,
    unsigned short* __restrict__ outb, int ldo,
    const unsigned short* __restrict__ em,
    const int* __restrict__ Mvp,
    unsigned short* __restrict__ ci,
    int blocksPerHead, long long aHeadOff, long long bHeadOff,
    long long oHeadOff, int biasHeadOff,
    const int2* __restrict__ nodes,
    const unsigned short* __restrict__ nfa,
    const unsigned short* __restrict__ nfb,
    const int* __restrict__ rmap) {
  __shared__ __align__(16) unsigned short sm[16384];  // exactly 32 KB
  char* smc = (char*)sm;
  const int t = threadIdx.x;
  int bid = blockIdx.x;

  if constexpr (EPI == 6) {
    // trailing fillout blocks: constant rows of d_out (nfa=outc, nfb=d_out)
    if (bid >= 2 * blocksPerHead) {
      const float* oc = (const float*)nfa;
      float* out = (float*)nfb;
      const int e = (bid - 2 * blocksPerHead) * 256 + t;
      if (e < MROWS * 17) {
        int c;
        if (e < MROWS * 9) c = e % 9;
        else if (e < MROWS * 12) c = 9 + (e - MROWS * 9) % 3;
        else c = 12 + (e - MROWS * 12) % 5;
        out[e] = oc[c];
      }
      return;
    }
  }

  const int l = t & 63, w = t >> 6;
  const int wm = w >> 1, wn = w & 1;

  int head = 0;
  unsigned short* outp = outb;
  if constexpr (EPI == 3) {
    head = bid / MTILES;
    bid -= head * MTILES;
    A += (size_t)head * MROWS * DD;
    BT += (size_t)head * 128 * DD;
    bias += head * 128;
  } else {
    if (blocksPerHead > 0) {
      head = bid / blocksPerHead;
      bid -= head * blocksPerHead;
      A += (long long)head * aHeadOff;
      BT += (long long)head * bHeadOff;
      bias += head * biasHeadOff;
      outp = outb + (long long)head * oHeadOff;
    }
  }
  const int tn = bid % Ntiles, tm = bid / Ntiles;

  int Mv = MROWS;
  if (Mvp) Mv = *Mvp;
  if constexpr (EPI == 6) { if (head == 0) Mv = MNODE; }
  if (Mvp) {
    if (tm * 128 >= Mv) return;   // compact early-exit (uniform branch)
  }

  const int lrow = l >> 3;
  const int scol = (l & 7) ^ lrow;       // pre-swizzled source chunk
  const unsigned short* Ap = A + (size_t)(tm * 128 + w * 8 + lrow) * ldA + scol * 8;
  const unsigned short* Bp = BT + (size_t)(tn * 128 + w * 8 + lrow) * ldB + scol * 8;

  f32x4 acc[4][4] = {};
  const int hi = l >> 4, l15 = l & 15, l7 = l & 7;
  const int nk = K >> 6;

  for (int kt = 0; kt < nk; ++kt) {
#pragma unroll
    for (int c = 0; c < 4; ++c) {
      gll16(Ap + (size_t)c * 32 * ldA, smc + c * 4096 + w * 1024);
      gll16(Bp + (size_t)c * 32 * ldB, smc + 16384 + c * 4096 + w * 1024);
    }
    __syncthreads();
#pragma unroll
    for (int kk = 0; kk < 2; ++kk) {
      const int cb = (((kk << 2) + hi) ^ l7) << 4;
      s16x8 af[4], bfr[4];
#pragma unroll
      for (int m = 0; m < 4; m++)
        af[m] = *(const s16x8*)(smc + (wm * 64 + m * 16 + l15) * 128 + cb);
#pragma unroll
      for (int n = 0; n < 4; n++)
        bfr[n] = *(const s16x8*)(smc + 16384 + (wn * 64 + n * 16 + l15) * 128 + cb);
#pragma unroll
      for (int m = 0; m < 4; m++)
#pragma unroll
        for (int n = 0; n < 4; n++)
          asm volatile("v_mfma_f32_16x16x32_bf16 %0, %1, %2, %0"
                       : "+v"(acc[m][n])
                       : "v"(af[m]), "v"(bfr[n]));
    }
    __syncthreads();
    Ap += 64;
    Bp += 64;
  }
  asm volatile("s_nop 7\n\ts_nop 7\n\ts_nop 7" :::);  // MFMA->VALU hazard guard

  if constexpr (EPI == 5) {
    // Stage npair = nfa[i0]+nfb[i1] for the 128x128 tile, coalesced 16B/lane.
    // Layout: row*256B, 16B chunk swizzled (chunk ^= (row>>2)&7) -> conflict-free.
    const int se_r = t >> 4;
    const int se_ch = t & 15;
#pragma unroll
    for (int it = 0; it < 8; ++it) {
      const int rr = se_r + (it << 4);
      const int2 nn = nodes[tm * 128 + rr];   // pad rows zero-initialized
      union { unsigned short s[8]; unsigned long long q[2]; } ov;
      u16x8 va = *(const u16x8*)&nfa[(size_t)nn.x * 3072 + tn * 128 + se_ch * 8];
      u16x8 vb = *(const u16x8*)&nfb[(size_t)nn.y * 3072 + tn * 128 + se_ch * 8];
#pragma unroll
      for (int j = 0; j < 8; ++j)
        ov.s[j] = f2bf(bf2f(va[j]) + bf2f(vb[j]));
      const int sch = se_ch ^ ((rr >> 2) & 7);
      *(unsigned long long*)(smc + rr * 256 + (sch << 4)) = ov.q[0];
      *(unsigned long long*)(smc + rr * 256 + (sch << 4) + 8) = ov.q[1];
    }
    __syncthreads();
  }

  // C/D layout: col = lane&15, row = (lane>>4)*4 + reg
  const int gr_base = tm * 128 + wm * 64 + (hi << 2);
  const int gc_base = tn * 128 + wn * 64 + l15;
  const int lr_base = wm * 64 + (hi << 2);
  const int lc_base = wn * 64 + l15;

  int Cc = 0; size_t obase = 0;
  if constexpr (EPI == 3) {
    Cc = (head == 0) ? 9 : ((head == 1) ? 3 : 5);
    obase = (head == 0) ? 0 : ((head == 1) ? (size_t)MROWS * 9 : (size_t)MROWS * 12);
  }

#pragma unroll
  for (int n = 0; n < 4; n++) {
    const int gc = gc_base + n * 16;
    const float bv = (EPI == 4) ? 0.f : bias[gc];
#pragma unroll
    for (int m = 0; m < 4; m++) {
#pragma unroll
      for (int i = 0; i < 4; i++) {
        const int gr = gr_base + m * 16 + i;
        float v = acc[m][n][i] + bv;
        if constexpr (EPI == 0 || EPI == 4) {
          outp[(size_t)gr * ldo + gc] = f2bf(v);
        } else if constexpr (EPI == 2) {
          outp[(size_t)gr * ldo + gc] = f2bf(v > 0.f ? v : 0.f);
        } else if constexpr (EPI == 5) {
          const int lr = lr_base + m * 16 + i;
          const int lc = lc_base + n * 16;
          const int rch = (lc >> 3) ^ ((lr >> 2) & 7);
          v += bf2f(*(const unsigned short*)(smc + lr * 256 + (rch << 4) + (lc & 7) * 2));
          outp[(size_t)gr * ldo + gc] = f2bf(v > 0.f ? v : 0.f);
        } else if constexpr (EPI == 6) {
          if (head == 0) {
            outp[(size_t)gr * ldo + gc] = f2bf(v);
          } else {
            float e = bf2f(em[(size_t)gr * DD + gc]) + 0.5f * v;
            ci[(size_t)gr * DD + gc] = f2bf(e);
          }
        } else {
          if (gc < Cc && gr < Mv)
            ((float*)outb)[obase + (size_t)rmap[gr] * Cc + gc] = v;
        }
      }
    }
  }
}

// ---------------- launcher ----------------
extern "C" void kernel_launch(void* const* d_in, const int* in_sizes, int n_in,
                              void* d_out, int out_size, void* d_ws, size_t ws_size,
                              hipStream_t stream) {
  const float* node   = (const float*)d_in[0];
  const float* EF     = (const float*)d_in[1];
  const float* EE     = (const float*)d_in[2];
  const int*   pairs  = (const int*)d_in[3];
  const int*   nrels  = (const int*)d_in[4];
  const float* W_node = (const float*)d_in[5];
  const float* b_node = (const float*)d_in[6];
  const float* W_edge = (const float*)d_in[7];
  const float* b_edge = (const float*)d_in[8];
  const float* hW0[3] = {(const float*)d_in[9],  (const float*)d_in[15], (const float*)d_in[21]};
  const float* hb0[3] = {(const float*)d_in[10], (const float*)d_in[16], (const float*)d_in[22]};
  const float* hW1[3] = {(const float*)d_in[11], (const float*)d_in[17], (const float*)d_in[23]};
  const float* hb1[3] = {(const float*)d_in[12], (const float*)d_in[18], (const float*)d_in[24]};
  const float* hW2[3] = {(const float*)d_in[13], (const float*)d_in[19], (const float*)d_in[25]};
  const float* hb2[3] = {(const float*)d_in[14], (const float*)d_in[20], (const float*)d_in[26]};

  char* ws = (char*)d_ws;
  size_t off = 0;
  auto alloc = [&](size_t bytes) {
    char* p = ws + off;
    off += (bytes + 255) & ~(size_t)255;
    return p;
  };
  // --- persistent front ---
  unsigned short* WnT    = (unsigned short*)alloc((size_t)512 * 1024 * 2);
  unsigned short* WeT    = (unsigned short*)alloc((size_t)512 * 1024 * 2);
  unsigned short* W0T    = (unsigned short*)alloc((size_t)3072 * 1536 * 2);
  unsigned short* W1T    = (unsigned short*)alloc((size_t)3 * 512 * 1024 * 2);
  unsigned short* W2T    = (unsigned short*)alloc((size_t)3 * 128 * 512 * 2);
  float*          b2pad  = (float*)alloc((size_t)3 * 128 * 4);
  float*          b0cat  = (float*)alloc((size_t)3072 * 4);
  float*          b1cat  = (float*)alloc((size_t)1536 * 4);
  float*          b_ne   = (float*)alloc((size_t)1024 * 4);
  int2*           nodes  = (int2*)alloc((size_t)MROWS * 8);
  int*            offs   = (int*)alloc((size_t)256 * 4);
  int*            Mv     = (int*)alloc(256);
  int*            rmap   = (int*)alloc((size_t)MROWS * 4);
  float*          outc   = (float*)alloc((size_t)32 * 4);
  float*          h1part = (float*)alloc((size_t)24 * 512 * 4);
  // --- zone A: efm+EMb (dead after e-GEMM) -> reused as nfa/nfb, then h1 ---
  size_t zoneA = off;
  unsigned short* efm = (unsigned short*)alloc((size_t)MROWS * DEF * 2);  // 34.6M
  unsigned short* EMb = (unsigned short*)alloc((size_t)MROWS * DD * 2);   // 17.3M
  // --- zone B: ci_e (dead after L0') ---
  unsigned short* ci_e = (unsigned short*)alloc((size_t)MROWS * DD * 2);  // 17.3M
  // --- zone C: node_bf+nf (dead before L0') -> overlaid by h0big ---
  size_t zoneC = off;
  unsigned short* node_bf = (unsigned short*)alloc((size_t)MNODE * DNF * 2);
  unsigned short* nf      = (unsigned short*)alloc((size_t)MNODE * DD * 2);
  // overlays
  unsigned short* nfa   = (unsigned short*)(ws + zoneA);                 // 18.9M
  unsigned short* nfb   = nfa + (size_t)MNODE * 3072;                    // 18.9M
  unsigned short* h1    = (unsigned short*)(ws + zoneA);                 // 51.9M (after L0')
  unsigned short* h0big = (unsigned short*)(ws + zoneC);                 // 104M

  // 1. front: h1c partials + scan + conv + transposes + pads (ONE launch)
  k_front<<<5679, 256, 0, stream>>>(nrels, offs, Mv, nodes, h1part,
      node, node_bf, W_node, WnT, W_edge, WeT,
      hW0[0], hW0[1], hW0[2], W0T, hW1[0], hW1[1], hW1[2], W1T,
      hW2[0], hW2[1], hW2[2], hb2[0], hb2[1], hb2[2], W2T, b2pad,
      hb0[0], hb0[1], hb0[2], b0cat, hb1[0], hb1[1], hb1[2], b1cat,
      b_node, b_edge, b_ne);
  // 2. compact gather + outc finish (ONE launch)
  k_gather_fin<<<MROWS + 1, 256, 0, stream>>>(EF, EE, pairs, nrels, offs,
      efm, EMb, nodes, rmap, h1part,
      hb1[0], hb1[1], hb1[2], hW2[0], hW2[1], hW2[2],
      hb2[0], hb2[1], hb2[2], outc);

  // 3. merged nf|e GEMM + trailing fillout blocks
  k_gemm<6><<<2 * MTILES * 4 + (MROWS * 17 + 255) / 256, 256, 0, stream>>>(
      node_bf, 1024, WnT, 1024, 1024, 4, b_ne, nf, 512,
      EMb, Mv, ci_e, MTILES * 4,
      (long long)(efm - node_bf), (long long)512 * 1024,
      (long long)(ci_e - nf), 512,
      nullptr, (const unsigned short*)outc, (const unsigned short*)d_out, nullptr);

  // 4. node-side layer-0 partials (a/b halves fused):
  k_gemm<4><<<2 * (MNODE / 128) * 24, 256, 0, stream>>>(
      nf, 512, W0T, 1536, 512, 24, nullptr, nfa, 3072,
      nullptr, nullptr, nullptr, (MNODE / 128) * 24,
      0, 512, (long long)MNODE * 3072, 0, nullptr, nullptr, nullptr, nullptr);

  // 5. L0' (compact): h0 = relu(ci_e @ W0[1024:1536,:]^T + b0 + npair)
  k_gemm<5><<<MTILES * 24, 256, 0, stream>>>(
      ci_e, 512, W0T + 1024, 1536, 512, 24, b0cat, h0big, 3072,
      nullptr, Mv, nullptr, 0, 0, 0, 0, 0, nodes, nfa, nfb, nullptr);

  // 6. L1 (compact, fused over heads)
  k_gemm<2><<<3 * MTILES * 4, 256, 0, stream>>>(
      h0big, 3072, W1T, 1024, 1024, 4, b1cat, h1, 512,
      nullptr, Mv, nullptr, MTILES * 4,
      1024, (long long)512 * 1024, (long long)MROWS * DD, 512,
      nullptr, nullptr, nullptr, nullptr);

  // 7. L2 (compact): padded GEMM, scatter valid rows into pre-filled d_out
  k_gemm<3><<<3 * MTILES, 256, 0, stream>>>(
      h1, 512, W2T, 512, 512, 1, b2pad, (unsigned short*)d_out, 0,
      nullptr, Mv, nullptr, 0, 0, 0, 0, 0, nullptr, nullptr, nullptr, rmap);
}

// Round 15
// 198.836 us; speedup vs baseline: 2.1082x; 1.0127x over previous
//
#include <hip/hip_runtime.h>
#include <stdint.h>

// Problem constants
#define BB 256
#define NNODE 12
#define PP 66
#define DNF 1024
#define DEF 1024
#define DD 512
#define MROWS (BB*PP)        // 16896
#define MNODE (BB*NNODE)     // 3072
#define MTILES (MROWS/128)   // 132

typedef __attribute__((ext_vector_type(8))) short s16x8;
typedef __attribute__((ext_vector_type(4))) float f32x4;
typedef __attribute__((ext_vector_type(8))) unsigned short u16x8;

__device__ __forceinline__ unsigned short f2bf(float f) {
  union { float f; unsigned u; } v; v.f = f;
  return (unsigned short)((v.u + 0x7FFFu + ((v.u >> 16) & 1u)) >> 16);
}
__device__ __forceinline__ float bf2f(unsigned short h) {
  union { unsigned u; float f; } v; v.u = ((unsigned)h) << 16;
  return v.f;
}

__device__ __forceinline__ void gll16(const void* g, void* l) {
  __builtin_amdgcn_global_load_lds(
      (const __attribute__((address_space(1))) void*)g,
      (__attribute__((address_space(3))) void*)l, 16, 0, 0);
}

// ---------------- k_front: h1c partials + scan + prep (ONE launch) ----------
__global__ __launch_bounds__(256) void k_front(
    const int* __restrict__ nrels, int* __restrict__ offs,
    int* __restrict__ Mv, int2* __restrict__ nodes,
    float* __restrict__ h1part,
    const float* __restrict__ node, unsigned short* __restrict__ node_bf,
    const float* __restrict__ W_node, unsigned short* __restrict__ WnT,
    const float* __restrict__ W_edge, unsigned short* __restrict__ WeT,
    const float* __restrict__ W0a, const float* __restrict__ W0b,
    const float* __restrict__ W0c, unsigned short* __restrict__ W0T,
    const float* __restrict__ W1a, const float* __restrict__ W1b,
    const float* __restrict__ W1c, unsigned short* __restrict__ W1T,
    const float* __restrict__ w2a, const float* __restrict__ w2b,
    const float* __restrict__ w2c,
    const float* __restrict__ b2a, const float* __restrict__ b2b,
    const float* __restrict__ b2c,
    unsigned short* __restrict__ W2T, float* __restrict__ b2pad,
    const float* __restrict__ b0a, const float* __restrict__ b0b,
    const float* __restrict__ b0c, float* __restrict__ b0cat,
    const float* __restrict__ b1a, const float* __restrict__ b1b,
    const float* __restrict__ b1c, float* __restrict__ b1cat,
    const float* __restrict__ b_node, const float* __restrict__ b_edge,
    float* __restrict__ b_ne) {
  __shared__ float tile[64][65];
  const int bid = blockIdx.x, t = threadIdx.x;
  if (bid < 24) {
    const int h = bid >> 3, c = bid & 7;
    const float* b0 = h == 0 ? b0a : (h == 1 ? b0b : b0c);
    const float* W1 = h == 0 ? W1a : (h == 1 ? W1b : W1c);
    const int k0 = c * 128;
    float acc0 = 0.f, acc1 = 0.f;
#pragma unroll 8
    for (int kk = 0; kk < 128; ++kk) {
      const int k = k0 + kk;
      const float bv = fmaxf(b0[k], 0.f);
      acc0 += bv * W1[(size_t)k * 512 + t];
      acc1 += bv * W1[(size_t)k * 512 + t + 256];
    }
    h1part[(size_t)bid * 512 + t] = acc0;
    h1part[(size_t)bid * 512 + t + 256] = acc1;
  } else if (bid == 24) {
    __shared__ int s[256];
    const int val = nrels[t];
    s[t] = val;
    __syncthreads();
    for (int d = 1; d < 256; d <<= 1) {
      int x = (t >= d) ? s[t - d] : 0;
      __syncthreads();
      s[t] += x;
      __syncthreads();
    }
    offs[t] = s[t] - val;
    __syncthreads();
    const int total = s[255];
    if (t == 0) *Mv = total;
    if (t < 128) {
      int cr = total + t;
      if (cr < MROWS) nodes[cr] = make_int2(0, 0);
    }
  } else if (bid < 3097) {
    int i = (bid - 25) * 256 + t;
    float4 v = ((const float4*)node)[i];
    ushort4 o;
    o.x = f2bf(v.x); o.y = f2bf(v.y); o.z = f2bf(v.z); o.w = f2bf(v.w);
    ((ushort4*)node_bf)[i] = o;
  } else if (bid < 4889) {
    int tau = bid - 3097;
    const float* src; unsigned short* dst; int K, N;
    if (tau < 128)       { src = W_node; dst = WnT; K = 1024; N = 512; }
    else if (tau < 256)  { src = W_edge; dst = WeT; K = 1024; N = 512; tau -= 128; }
    else if (tau < 1408) {
      int hh = (tau - 256) / 384; tau = (tau - 256) % 384;
      src = hh == 0 ? W0a : (hh == 1 ? W0b : W0c);
      dst = W0T + (size_t)hh * 1024 * 1536; K = 1536; N = 1024;
    } else {
      int hh = (tau - 1408) / 128; tau = (tau - 1408) % 128;
      src = hh == 0 ? W1a : (hh == 1 ? W1b : W1c);
      dst = W1T + (size_t)hh * 512 * 1024; K = 1024; N = 512;
    }
    const int ntn = N >> 6;
    const int kb = (tau / ntn) * 64, nb = (tau % ntn) * 64;
    const int tx = t & 15, ty = t >> 4;
#pragma unroll
    for (int i = 0; i < 4; i++) {
      float4 v = *(const float4*)&src[(size_t)(kb + ty + 16 * i) * N + nb + tx * 4];
      tile[ty + 16 * i][tx * 4 + 0] = v.x;
      tile[ty + 16 * i][tx * 4 + 1] = v.y;
      tile[ty + 16 * i][tx * 4 + 2] = v.z;
      tile[ty + 16 * i][tx * 4 + 3] = v.w;
    }
    __syncthreads();
    const int wx = t & 7, wy = t >> 3;
#pragma unroll
    for (int i = 0; i < 2; i++) {
      const int n = wy + 32 * i;
      u16x8 o;
#pragma unroll
      for (int j = 0; j < 8; j++) o[j] = f2bf(tile[wx * 8 + j][n]);
      *(u16x8*)&dst[(size_t)(nb + n) * K + kb + wx * 8] = o;
    }
  } else if (bid < 5657) {
    int e = bid - 4889;
    int h = e >> 8, blk = e & 255;
    const int C = (h == 0) ? 9 : ((h == 1) ? 3 : 5);
    const float* W2 = (h == 0) ? w2a : ((h == 1) ? w2b : w2c);
    const float* b2 = (h == 0) ? b2a : ((h == 1) ? b2b : b2c);
    int idx = blk * 256 + t;
    int n = idx >> 9, k = idx & 511;
    W2T[(size_t)h * 65536 + idx] = (n < C) ? f2bf(W2[(size_t)k * C + n]) : (unsigned short)0;
    if (blk == 0 && t < 128)
      b2pad[h * 128 + t] = (t < C) ? b2[t] : 0.f;
  } else if (bid < 5669) {
    int j = bid - 5657;
    const float* b0 = (j < 4) ? b0a : (j < 8 ? b0b : b0c);
    b0cat[j * 256 + t] = b0[(j & 3) * 256 + t];
  } else if (bid < 5675) {
    int j = bid - 5669;
    const float* b1 = (j < 2) ? b1a : (j < 4 ? b1b : b1c);
    b1cat[j * 256 + t] = b1[(j & 1) * 256 + t];
  } else {
    int idx = (bid - 5675) * 256 + t;
    b_ne[idx] = (idx < 512) ? b_node[idx] : b_edge[idx - 512];
  }
}

// ---------------- shared GEMM body (m97-family, EXACTLY 32 KB LDS) ----------
// EPI: 0 = +bias -> bf16 ; 1 = e-assembly into ci_e (compact) ;
//      2 = relu(+bias) -> bf16 ; 3 = layer-2 heads fp32, scatter via rmap ;
//      4 = raw bf16 ; 5 = L0': relu(bias + acc + npair), chunk-XOR LDS stage.
template <int EPI>
__device__ __forceinline__ void gemm_body(
    unsigned short* sm,
    const unsigned short* __restrict__ A, int ldA,
    const unsigned short* __restrict__ BT, int ldB, int K,
    int Ntiles,
    const float* __restrict__ bias,
    unsigned short* __restrict__ outb, int ldo,
    const unsigned short* __restrict__ em,
    const int* __restrict__ Mvp,
    unsigned short* __restrict__ ci,
    int blocksPerHead, long long aHeadOff, long long bHeadOff,
    long long oHeadOff, int biasHeadOff,
    const int2* __restrict__ nodes,
    const unsigned short* __restrict__ nfa,
    const unsigned short* __restrict__ nfb,
    const int* __restrict__ rmap, int bid) {
  char* smc = (char*)sm;
  const int t = threadIdx.x;
  const int l = t & 63, w = t >> 6;
  const int wm = w >> 1, wn = w & 1;

  int head = 0;
  unsigned short* outp = outb;
  if constexpr (EPI == 3) {
    head = bid / MTILES;
    bid -= head * MTILES;
    A += (size_t)head * MROWS * DD;
    BT += (size_t)head * 128 * DD;
    bias += head * 128;
  } else {
    if (blocksPerHead > 0) {
      head = bid / blocksPerHead;
      bid -= head * blocksPerHead;
      A += (long long)head * aHeadOff;
      BT += (long long)head * bHeadOff;
      bias += head * biasHeadOff;
      outp = outb + (long long)head * oHeadOff;
    }
  }
  const int tn = bid % Ntiles, tm = bid / Ntiles;

  int Mv = MROWS;
  if (Mvp) {
    Mv = *Mvp;
    if (tm * 128 >= Mv) return;   // compact early-exit (uniform branch)
  }

  const int lrow = l >> 3;
  const int scol = (l & 7) ^ lrow;       // pre-swizzled source chunk
  const unsigned short* Ap = A + (size_t)(tm * 128 + w * 8 + lrow) * ldA + scol * 8;
  const unsigned short* Bp = BT + (size_t)(tn * 128 + w * 8 + lrow) * ldB + scol * 8;

  f32x4 acc[4][4] = {};
  const int hi = l >> 4, l15 = l & 15, l7 = l & 7;
  const int nk = K >> 6;

  for (int kt = 0; kt < nk; ++kt) {
#pragma unroll
    for (int c = 0; c < 4; ++c) {
      gll16(Ap + (size_t)c * 32 * ldA, smc + c * 4096 + w * 1024);
      gll16(Bp + (size_t)c * 32 * ldB, smc + 16384 + c * 4096 + w * 1024);
    }
    __syncthreads();
#pragma unroll
    for (int kk = 0; kk < 2; ++kk) {
      const int cb = (((kk << 2) + hi) ^ l7) << 4;
      s16x8 af[4], bfr[4];
#pragma unroll
      for (int m = 0; m < 4; m++)
        af[m] = *(const s16x8*)(smc + (wm * 64 + m * 16 + l15) * 128 + cb);
#pragma unroll
      for (int n = 0; n < 4; n++)
        bfr[n] = *(const s16x8*)(smc + 16384 + (wn * 64 + n * 16 + l15) * 128 + cb);
#pragma unroll
      for (int m = 0; m < 4; m++)
#pragma unroll
        for (int n = 0; n < 4; n++)
          asm volatile("v_mfma_f32_16x16x32_bf16 %0, %1, %2, %0"
                       : "+v"(acc[m][n])
                       : "v"(af[m]), "v"(bfr[n]));
    }
    __syncthreads();
    Ap += 64;
    Bp += 64;
  }
  asm volatile("s_nop 7\n\ts_nop 7\n\ts_nop 7" :::);  // MFMA->VALU hazard guard

  if constexpr (EPI == 5) {
    // Stage npair = nfa[i0]+nfb[i1], coalesced 16B/lane; chunk-XOR swizzle.
    const int se_r = t >> 4;
    const int se_ch = t & 15;
#pragma unroll
    for (int it = 0; it < 8; ++it) {
      const int rr = se_r + (it << 4);
      const int2 nn = nodes[tm * 128 + rr];   // pad rows zero-initialized
      union { unsigned short s[8]; unsigned long long q[2]; } ov;
      u16x8 va = *(const u16x8*)&nfa[(size_t)nn.x * 3072 + tn * 128 + se_ch * 8];
      u16x8 vb = *(const u16x8*)&nfb[(size_t)nn.y * 3072 + tn * 128 + se_ch * 8];
#pragma unroll
      for (int j = 0; j < 8; ++j)
        ov.s[j] = f2bf(bf2f(va[j]) + bf2f(vb[j]));
      const int sch = se_ch ^ ((rr >> 2) & 7);
      *(unsigned long long*)(smc + rr * 256 + (sch << 4)) = ov.q[0];
      *(unsigned long long*)(smc + rr * 256 + (sch << 4) + 8) = ov.q[1];
    }
    __syncthreads();
  }

  // C/D layout: col = lane&15, row = (lane>>4)*4 + reg
  const int gr_base = tm * 128 + wm * 64 + (hi << 2);
  const int gc_base = tn * 128 + wn * 64 + l15;
  const int lr_base = wm * 64 + (hi << 2);
  const int lc_base = wn * 64 + l15;

  int Cc = 0; size_t obase = 0;
  if constexpr (EPI == 3) {
    Cc = (head == 0) ? 9 : ((head == 1) ? 3 : 5);
    obase = (head == 0) ? 0 : ((head == 1) ? (size_t)MROWS * 9 : (size_t)MROWS * 12);
  }

#pragma unroll
  for (int n = 0; n < 4; n++) {
    const int gc = gc_base + n * 16;
    const float bv = (EPI == 4) ? 0.f : bias[gc];
#pragma unroll
    for (int m = 0; m < 4; m++) {
#pragma unroll
      for (int i = 0; i < 4; i++) {
        const int gr = gr_base + m * 16 + i;
        float v = acc[m][n][i] + bv;
        if constexpr (EPI == 0 || EPI == 4) {
          outp[(size_t)gr * ldo + gc] = f2bf(v);
        } else if constexpr (EPI == 1) {
          float e = bf2f(em[(size_t)gr * DD + gc]) + 0.5f * v;
          ci[(size_t)gr * DD + gc] = f2bf(e);
        } else if constexpr (EPI == 2) {
          outp[(size_t)gr * ldo + gc] = f2bf(v > 0.f ? v : 0.f);
        } else if constexpr (EPI == 5) {
          const int lr = lr_base + m * 16 + i;
          const int lc = lc_base + n * 16;
          const int rch = (lc >> 3) ^ ((lr >> 2) & 7);
          v += bf2f(*(const unsigned short*)(smc + lr * 256 + (rch << 4) + (lc & 7) * 2));
          outp[(size_t)gr * ldo + gc] = f2bf(v > 0.f ? v : 0.f);
        } else {
          if (gc < Cc && gr < Mv)
            ((float*)outb)[obase + (size_t)rmap[gr] * Cc + gc] = v;
        }
      }
    }
  }
}

// ---- k_gather_nf: compact gather + outc finish + nf GEMM (ONE launch) ------
// All segment read/write sets disjoint: gather writes efm/EMb/nodes/rmap;
// finish writes outc; nf GEMM reads node_bf/WnT, writes nf.
__global__ __launch_bounds__(256) void k_gather_nf(
    const float* __restrict__ EF, const float* __restrict__ EE,
    const int* __restrict__ pairs, const int* __restrict__ nrels,
    const int* __restrict__ offs,
    unsigned short* __restrict__ efm, unsigned short* __restrict__ emb,
    int2* __restrict__ nodes, int* __restrict__ rmap,
    const float* __restrict__ h1part,
    const float* __restrict__ b1a, const float* __restrict__ b1b,
    const float* __restrict__ b1c,
    const float* __restrict__ w2a, const float* __restrict__ w2b,
    const float* __restrict__ w2c,
    const float* __restrict__ b2a, const float* __restrict__ b2b,
    const float* __restrict__ b2c, float* __restrict__ outc,
    const unsigned short* __restrict__ node_bf,
    const unsigned short* __restrict__ WnT,
    const float* __restrict__ b_node, unsigned short* __restrict__ nf) {
  __shared__ __align__(16) unsigned short sm[16384];
  const int bid = blockIdx.x, t = threadIdx.x;
  if (bid > MROWS) {
    // nf = node_bf @ WnT^T + b_node  (M=3072, N=512, K=1024; 96 blocks)
    gemm_body<0>(sm, node_bf, 1024, WnT, 1024, 1024, 4, b_node, nf, 512,
                 nullptr, nullptr, nullptr, 0, 0, 0, 0, 0,
                 nullptr, nullptr, nullptr, nullptr, bid - MROWS - 1);
    return;
  }
  if (bid == MROWS) {
    float* red = (float*)sm;
    for (int h = 0; h < 3; ++h) {
      const float* b1 = h == 0 ? b1a : (h == 1 ? b1b : b1c);
      const float* W2 = h == 0 ? w2a : (h == 1 ? w2b : w2c);
      const float* b2 = h == 0 ? b2a : (h == 1 ? b2b : b2c);
      const int C = h == 0 ? 9 : (h == 1 ? 3 : 5);
      const int obase = h == 0 ? 0 : (h == 1 ? 9 : 12);
      if (t < 9) red[t] = 0.f;
      float s0 = b1[t], s1 = b1[t + 256];
#pragma unroll
      for (int cc = 0; cc < 8; ++cc) {
        s0 += h1part[(size_t)(h * 8 + cc) * 512 + t];
        s1 += h1part[(size_t)(h * 8 + cc) * 512 + t + 256];
      }
      const float hv0 = fmaxf(s0, 0.f), hv1 = fmaxf(s1, 0.f);
      __syncthreads();
      float p[9] = {0.f, 0.f, 0.f, 0.f, 0.f, 0.f, 0.f, 0.f, 0.f};
#pragma unroll
      for (int c = 0; c < 9; ++c)
        if (c < C) p[c] = hv0 * W2[(size_t)t * C + c] + hv1 * W2[(size_t)(t + 256) * C + c];
#pragma unroll
      for (int c = 0; c < 9; ++c)
#pragma unroll
        for (int off = 32; off; off >>= 1) p[c] += __shfl_xor(p[c], off);
      if ((t & 63) == 0)
        for (int c = 0; c < C; ++c) atomicAdd(&red[c], p[c]);
      __syncthreads();
      if (t < C) outc[obase + t] = red[t] + b2[t];
      __syncthreads();
    }
    return;
  }
  int r = bid;
  int b = r / PP, p = r - b * PP;
  if (p >= nrels[b]) return;
  const int cr = offs[b] + p;
  int i0 = pairs[r * 2 + 0], i1 = pairs[r * 2 + 1];
  if (t == 0) {
    nodes[cr] = make_int2(b * NNODE + i0, b * NNODE + i1);
    rmap[cr] = r;
  }
  const float4* e01 = (const float4*)(EF + ((size_t)((b * NNODE + i0) * NNODE + i1)) * DEF);
  const float4* e10 = (const float4*)(EF + ((size_t)((b * NNODE + i1) * NNODE + i0)) * DEF);
  float4 a = e01[t], c = e10[t];
  ushort4 o;
  o.x = f2bf(0.5f * (a.x + c.x));
  o.y = f2bf(0.5f * (a.y + c.y));
  o.z = f2bf(0.5f * (a.z + c.z));
  o.w = f2bf(0.5f * (a.w + c.w));
  ((ushort4*)(efm + (size_t)cr * DEF))[t] = o;
  const float2* g01 = (const float2*)(EE + ((size_t)((b * NNODE + i0) * NNODE + i1)) * DD);
  const float2* g10 = (const float2*)(EE + ((size_t)((b * NNODE + i1) * NNODE + i0)) * DD);
  float2 x = g01[t], y = g10[t];
  ushort2 eo;
  eo.x = f2bf(0.25f * (x.x + y.x));
  eo.y = f2bf(0.25f * (x.y + y.y));
  ((ushort2*)(emb + (size_t)cr * DD))[t] = eo;
}

// ---- k_mid: e-GEMM + nfa/nfb GEMM + fillout (ONE launch) --------------------
// RACE-FREE iff nfa/nfb are DISJOINT from efm/EMb (r14 bug: they overlaid).
// [0,528) e-assembly EPI1 ; [528,1680) nfa/nfb EPI4 ; [1680,2802) fillout.
__global__ __launch_bounds__(256) void k_mid(
    const unsigned short* __restrict__ efm, const unsigned short* __restrict__ WeT,
    const float* __restrict__ b_edge,
    const unsigned short* __restrict__ EMb, const int* __restrict__ Mvp,
    unsigned short* __restrict__ ci_e,
    const unsigned short* __restrict__ nf, const unsigned short* __restrict__ W0T,
    unsigned short* __restrict__ nfa,
    const float* __restrict__ outc, float* __restrict__ out) {
  __shared__ __align__(16) unsigned short sm[16384];
  const int bid = blockIdx.x, t = threadIdx.x;
  if (bid < 528) {
    // ci_e = 0.25(ee+ee') + 0.5(efm@WeT^T + b_edge)  (M=Mv compact, N=512, K=1024)
    gemm_body<1>(sm, efm, 1024, WeT, 1024, 1024, 4, b_edge, nullptr, 0,
                 EMb, Mvp, ci_e, 0, 0, 0, 0, 0,
                 nullptr, nullptr, nullptr, nullptr, bid);
  } else if (bid < 1680) {
    // nfa = nf@W0[0:512]^T ; nfb = nf@W0[512:1024]^T (each M=3072,N=3072,K=512)
    gemm_body<4>(sm, nf, 512, W0T, 1536, 512, 24, nullptr, nfa, 3072,
                 nullptr, nullptr, nullptr, 576,
                 0, 512, (long long)MNODE * 3072, 0,
                 nullptr, nullptr, nullptr, nullptr, bid - 528);
  } else {
    const int e = (bid - 1680) * 256 + t;
    if (e < MROWS * 17) {
      int c;
      if (e < MROWS * 9) c = e % 9;
      else if (e < MROWS * 12) c = 9 + (e - MROWS * 9) % 3;
      else c = 12 + (e - MROWS * 12) % 5;
      out[e] = outc[c];
    }
  }
}

// ---------------- plain GEMM wrapper (L0', L1, L2) ---------------------------
template <int EPI>
__global__ __launch_bounds__(256) void k_gemm(
    const unsigned short* __restrict__ A, int ldA,
    const unsigned short* __restrict__ BT, int ldB, int K,
    int Ntiles,
    const float* __restrict__ bias,
    unsigned short* __restrict__ outb, int ldo,
    const unsigned short* __restrict__ em,
    const int* __restrict__ Mvp,
    unsigned short* __restrict__ ci,
    int blocksPerHead, long long aHeadOff, long long bHeadOff,
    long long oHeadOff, int biasHeadOff,
    const int2* __restrict__ nodes,
    const unsigned short* __restrict__ nfa,
    const unsigned short* __restrict__ nfb,
    const int* __restrict__ rmap) {
  __shared__ __align__(16) unsigned short sm[16384];
  gemm_body<EPI>(sm, A, ldA, BT, ldB, K, Ntiles, bias, outb, ldo, em, Mvp, ci,
                 blocksPerHead, aHeadOff, bHeadOff, oHeadOff, biasHeadOff,
                 nodes, nfa, nfb, rmap, blockIdx.x);
}

// ---------------- launcher ----------------
extern "C" void kernel_launch(void* const* d_in, const int* in_sizes, int n_in,
                              void* d_out, int out_size, void* d_ws, size_t ws_size,
                              hipStream_t stream) {
  const float* node   = (const float*)d_in[0];
  const float* EF     = (const float*)d_in[1];
  const float* EE     = (const float*)d_in[2];
  const int*   pairs  = (const int*)d_in[3];
  const int*   nrels  = (const int*)d_in[4];
  const float* W_node = (const float*)d_in[5];
  const float* b_node = (const float*)d_in[6];
  const float* W_edge = (const float*)d_in[7];
  const float* b_edge = (const float*)d_in[8];
  const float* hW0[3] = {(const float*)d_in[9],  (const float*)d_in[15], (const float*)d_in[21]};
  const float* hb0[3] = {(const float*)d_in[10], (const float*)d_in[16], (const float*)d_in[22]};
  const float* hW1[3] = {(const float*)d_in[11], (const float*)d_in[17], (const float*)d_in[23]};
  const float* hb1[3] = {(const float*)d_in[12], (const float*)d_in[18], (const float*)d_in[24]};
  const float* hW2[3] = {(const float*)d_in[13], (const float*)d_in[19], (const float*)d_in[25]};
  const float* hb2[3] = {(const float*)d_in[14], (const float*)d_in[20], (const float*)d_in[26]};

  char* ws = (char*)d_ws;
  size_t off = 0;
  auto alloc = [&](size_t bytes) {
    char* p = ws + off;
    off += (bytes + 255) & ~(size_t)255;
    return p;
  };
  // --- persistent front (~15.5 MB) ---
  unsigned short* WnT    = (unsigned short*)alloc((size_t)512 * 1024 * 2);
  unsigned short* WeT    = (unsigned short*)alloc((size_t)512 * 1024 * 2);
  unsigned short* W0T    = (unsigned short*)alloc((size_t)3072 * 1536 * 2);
  unsigned short* W1T    = (unsigned short*)alloc((size_t)3 * 512 * 1024 * 2);
  unsigned short* W2T    = (unsigned short*)alloc((size_t)3 * 128 * 512 * 2);
  float*          b2pad  = (float*)alloc((size_t)3 * 128 * 4);
  float*          b0cat  = (float*)alloc((size_t)3072 * 4);
  float*          b1cat  = (float*)alloc((size_t)1536 * 4);
  float*          b_ne   = (float*)alloc((size_t)1024 * 4);
  int2*           nodes  = (int2*)alloc((size_t)MROWS * 8);
  int*            offs   = (int*)alloc((size_t)256 * 4);
  int*            Mv     = (int*)alloc(256);
  int*            rmap   = (int*)alloc((size_t)MROWS * 4);
  float*          outc   = (float*)alloc((size_t)32 * 4);
  float*          h1part = (float*)alloc((size_t)24 * 512 * 4);
  // --- zone B: [ci_e | nfa | nfb] (55.1 MB). DISJOINT from efm/EMb so k_mid's
  //     concurrent e-GEMM reads + nfa/nfb writes cannot alias (r14 bug fix).
  //     All three dead after L0' -> h1 (51.9 MB) overlays zone B.
  size_t zoneB = off;
  unsigned short* ci_e = (unsigned short*)alloc((size_t)MROWS * DD * 2);    // 17.3M
  unsigned short* nfa  = (unsigned short*)alloc((size_t)MNODE * 3072 * 2);  // 18.9M
  unsigned short* nfb  = (unsigned short*)alloc((size_t)MNODE * 3072 * 2);  // 18.9M
  // --- zone C: [node_bf | nf | efm | EMb] (61.3 MB). All dead after k_mid ->
  //     h0big (103.8 MB) overlays zone C and extends 42.5 MB into fresh space.
  size_t zoneC = off;
  unsigned short* node_bf = (unsigned short*)alloc((size_t)MNODE * DNF * 2); // 6.3M
  unsigned short* nf      = (unsigned short*)alloc((size_t)MNODE * DD * 2);  // 3.1M
  unsigned short* efm     = (unsigned short*)alloc((size_t)MROWS * DEF * 2); // 34.6M
  unsigned short* EMb     = (unsigned short*)alloc((size_t)MROWS * DD * 2);  // 17.3M
  // overlays (verified: h1 end = zoneB+51.9M < zoneC; h0big disjoint from zone B)
  unsigned short* h1    = (unsigned short*)(ws + zoneB);
  unsigned short* h0big = (unsigned short*)(ws + zoneC);

  // 1. front: h1c partials + scan + conv + transposes + pads
  k_front<<<5679, 256, 0, stream>>>(nrels, offs, Mv, nodes, h1part,
      node, node_bf, W_node, WnT, W_edge, WeT,
      hW0[0], hW0[1], hW0[2], W0T, hW1[0], hW1[1], hW1[2], W1T,
      hW2[0], hW2[1], hW2[2], hb2[0], hb2[1], hb2[2], W2T, b2pad,
      hb0[0], hb0[1], hb0[2], b0cat, hb1[0], hb1[1], hb1[2], b1cat,
      b_node, b_edge, b_ne);

  // 2. gather + finish + nf GEMM (nf's MFMA hides under the HBM-bound gather)
  k_gather_nf<<<MROWS + 1 + (MNODE / 128) * 4, 256, 0, stream>>>(
      EF, EE, pairs, nrels, offs, efm, EMb, nodes, rmap, h1part,
      hb1[0], hb1[1], hb1[2], hW2[0], hW2[1], hW2[2],
      hb2[0], hb2[1], hb2[2], outc,
      node_bf, WnT, b_ne, nf);

  // 3. mid: e-GEMM + nfa/nfb + fillout (race-free with the new layout)
  k_mid<<<1680 + (MROWS * 17 + 255) / 256, 256, 0, stream>>>(
      efm, WeT, b_ne + 512, EMb, Mv, ci_e,
      nf, W0T, nfa, outc, (float*)d_out);

  // 4. L0' (compact): h0 = relu(ci_e @ W0[1024:1536,:]^T + b0 + npair)
  k_gemm<5><<<MTILES * 24, 256, 0, stream>>>(
      ci_e, 512, W0T + 1024, 1536, 512, 24, b0cat, h0big, 3072,
      nullptr, Mv, nullptr, 0, 0, 0, 0, 0, nodes, nfa, nfb, nullptr);

  // 5. L1 (compact, fused over heads)
  k_gemm<2><<<3 * MTILES * 4, 256, 0, stream>>>(
      h0big, 3072, W1T, 1024, 1024, 4, b1cat, h1, 512,
      nullptr, Mv, nullptr, MTILES * 4,
      1024, (long long)512 * 1024, (long long)MROWS * DD, 512,
      nullptr, nullptr, nullptr, nullptr);

  // 6. L2 (compact): padded GEMM, scatter valid rows into pre-filled d_out
  k_gemm<3><<<3 * MTILES, 256, 0, stream>>>(
      h1, 512, W2T, 512, 512, 1, b2pad, (unsigned short*)d_out, 0,
      nullptr, Mv, nullptr, 0, 0, 0, 0, 0, nullptr, nullptr, nullptr, rmap);
}